// Round 1
// baseline (2960.726 us; speedup 1.0000x reference)
//
#include <hip/hip_runtime.h>
#include <math.h>

// ---------------------------------------------------------------------------
// EfficientFaceTransformer forward, fp32 baseline.
// Layouts: all activations channel-first [b][c][p], p = 28*28 = 784.
// ---------------------------------------------------------------------------

#define NPIX 784
#define CDIM 512
#define NHEAD 8
#define HDIM 64
#define C3 1536
#define H3DIM 682

// ---- workspace float offsets --------------------------------------------
#define OFF_A   ((size_t)0)           // 16*512*784   (xa -> xn2 -> x3)
#define OFF_B   ((size_t)6422528)     // 16*1536*784  (qkv -> cat -> h_e)
#define OFF_C   ((size_t)25690112)    // 16*512*784   (o -> gtmp)
#define OFF_D   ((size_t)32112640)    // 16*512*784   (x2)
#define OFF_PL  ((size_t)38535168)    // 16*512 pooled
#define OFF_AD  ((size_t)38543360)    // 16*1024 adapt out
#define OFF_R   ((size_t)38559744)    // 16*3 router

// ---------------------------------------------------------------------------
// pooled[b,c] = mean_p x[b,c,p]
__global__ __launch_bounds__(64) void pool_mean_k(const float* __restrict__ x,
                                                  float* __restrict__ pooled) {
  int c = blockIdx.x, b = blockIdx.y;
  const float* row = x + ((size_t)b * CDIM + c) * NPIX;
  float s = 0.f;
  for (int i = threadIdx.x; i < NPIX; i += 64) s += row[i];
  #pragma unroll
  for (int off = 32; off; off >>= 1) s += __shfl_down(s, off);
  if (threadIdx.x == 0) pooled[b * CDIM + c] = s * (1.f / NPIX);
}

// ---------------------------------------------------------------------------
// h = relu(pooled @ a1w.T + a1b) [128]; ad = h @ a2w.T + a2b [1024]
__global__ __launch_bounds__(256) void adapt_mlp_k(const float* __restrict__ pooled,
                                                   const float* __restrict__ a1w,
                                                   const float* __restrict__ a1b,
                                                   const float* __restrict__ a2w,
                                                   const float* __restrict__ a2b,
                                                   float* __restrict__ ad) {
  int b = blockIdx.x, tid = threadIdx.x;
  __shared__ float pl[CDIM];
  __shared__ float hh[128];
  for (int i = tid; i < CDIM; i += 256) pl[i] = pooled[b * CDIM + i];
  __syncthreads();
  if (tid < 128) {
    const float* w = a1w + (size_t)tid * CDIM;
    float a = a1b[tid];
    for (int k = 0; k < CDIM; ++k) a += w[k] * pl[k];
    hh[tid] = fmaxf(a, 0.f);
  }
  __syncthreads();
  for (int o = tid; o < 1024; o += 256) {
    const float* w = a2w + (size_t)o * 128;
    float a = a2b[o];
    for (int k = 0; k < 128; ++k) a += w[k] * hh[k];
    ad[b * 1024 + o] = a;
  }
}

// ---------------------------------------------------------------------------
// adaptive LN: per pixel, normalize over channels.
// out[b,c,p] = w[c]*(1+aw[b,c]) * (x-u)*rstd + (bias[c] + ab[b,c])
__global__ __launch_bounds__(256) void ln_apply_k(const float* __restrict__ x,
                                                  const float* __restrict__ w,
                                                  const float* __restrict__ bias,
                                                  const float* __restrict__ ad,
                                                  float* __restrict__ out) {
  int b = blockIdx.y;
  int p0 = blockIdx.x * 32;
  int tid = threadIdx.x;
  int px = tid & 31, cg = tid >> 5;           // 32 pixels x 8 channel groups
  int p = p0 + px;
  bool valid = p < NPIX;
  const float* xb = x + (size_t)b * CDIM * NPIX;
  float s = 0.f, s2 = 0.f;
  if (valid) {
    for (int c = cg * 64; c < cg * 64 + 64; ++c) {
      float v = xb[(size_t)c * NPIX + p];
      s += v; s2 += v * v;
    }
  }
  __shared__ float rs[8][32], rq[8][32];
  __shared__ float us[32], vs[32];
  rs[cg][px] = s; rq[cg][px] = s2;
  __syncthreads();
  if (tid < 32) {
    float ts = 0.f, ts2 = 0.f;
    #pragma unroll
    for (int g = 0; g < 8; ++g) { ts += rs[g][tid]; ts2 += rq[g][tid]; }
    float u = ts * (1.f / CDIM);
    float var = ts2 * (1.f / CDIM) - u * u;
    us[tid] = u;
    vs[tid] = rsqrtf(var + 1e-6f);
  }
  __syncthreads();
  if (valid) {
    float u = us[px], rst = vs[px];
    const float* aw = ad + (size_t)b * 1024;
    const float* ab = aw + CDIM;
    float* ob = out + (size_t)b * CDIM * NPIX;
    for (int c = cg * 64; c < cg * 64 + 64; ++c) {
      float v = xb[(size_t)c * NPIX + p];
      float xn = (v - u) * rst;
      ob[(size_t)c * NPIX + p] = w[c] * (1.f + aw[c]) * xn + (bias[c] + ab[c]);
    }
  }
}

// ---------------------------------------------------------------------------
// Generic GEMM, channel-first activations.
// C[b,n,m] = EPI( sum_k A[b,k,m]*Bw[n,k] + bias[n] ), M = 784 fixed.
// EPI: 0 none, 1 relu, 2 gelu(exact), 3 C *= sigmoid(v), 4 C = resid + sc*v
template <int EPI>
__global__ __launch_bounds__(256) void gemm_k(const float* __restrict__ A,
                                              const float* __restrict__ Bw,
                                              const float* __restrict__ bias,
                                              const float* __restrict__ resid,
                                              const float* __restrict__ scales,
                                              float* __restrict__ C,
                                              int K, int N) {
  const int M = NPIX;
  int b = blockIdx.z;
  const float* Ab = A + (size_t)b * K * M;
  float* Cb = C + (size_t)b * N * M;
  const float* Rb = resid ? resid + (size_t)b * N * M : nullptr;
  int m0 = blockIdx.x * 128, n0 = blockIdx.y * 64;
  __shared__ float As[16][132];
  __shared__ float Bs[16][68];
  int tid = threadIdx.x;
  int tx = tid & 15, ty = tid >> 4;
  float acc[8][4];
  #pragma unroll
  for (int i = 0; i < 8; ++i)
    #pragma unroll
    for (int j = 0; j < 4; ++j) acc[i][j] = 0.f;

  const bool kvec = (K & 3) == 0;
  for (int k0 = 0; k0 < K; k0 += 16) {
    {  // A tile 16k x 128m
      int mm = (tid & 31) * 4;
      int kkb = tid >> 5;
      #pragma unroll
      for (int ph = 0; ph < 2; ++ph) {
        int kk = kkb + ph * 8;
        int gk = k0 + kk, gm = m0 + mm;
        float4 v = {0.f, 0.f, 0.f, 0.f};
        if (gk < K) {
          if (gm + 3 < M) {
            v = *(const float4*)(Ab + (size_t)gk * M + gm);
          } else {
            float tv[4];
            #pragma unroll
            for (int q = 0; q < 4; ++q)
              tv[q] = (gm + q < M) ? Ab[(size_t)gk * M + gm + q] : 0.f;
            v = {tv[0], tv[1], tv[2], tv[3]};
          }
        }
        *(float4*)&As[kk][mm] = v;
      }
    }
    {  // B tile 64n x 16k
      int nn = tid >> 2, kk = (tid & 3) * 4;
      int gn = n0 + nn, gk = k0 + kk;
      float4 v = {0.f, 0.f, 0.f, 0.f};
      if (gn < N) {
        if (kvec && gk + 3 < K) {
          v = *(const float4*)(Bw + (size_t)gn * K + gk);
        } else {
          float tv[4];
          #pragma unroll
          for (int q = 0; q < 4; ++q)
            tv[q] = (gk + q < K) ? Bw[(size_t)gn * K + gk + q] : 0.f;
          v = {tv[0], tv[1], tv[2], tv[3]};
        }
      }
      Bs[kk][nn] = v.x; Bs[kk + 1][nn] = v.y;
      Bs[kk + 2][nn] = v.z; Bs[kk + 3][nn] = v.w;
    }
    __syncthreads();
    #pragma unroll
    for (int kk = 0; kk < 16; ++kk) {
      float4 a0 = *(const float4*)&As[kk][tx * 8];
      float4 a1 = *(const float4*)&As[kk][tx * 8 + 4];
      float4 bv = *(const float4*)&Bs[kk][ty * 4];
      float av[8] = {a0.x, a0.y, a0.z, a0.w, a1.x, a1.y, a1.z, a1.w};
      float bb[4] = {bv.x, bv.y, bv.z, bv.w};
      #pragma unroll
      for (int i = 0; i < 8; ++i)
        #pragma unroll
        for (int j = 0; j < 4; ++j) acc[i][j] += av[i] * bb[j];
    }
    __syncthreads();
  }

  float sc = 1.f;
  if (EPI == 4 && scales) sc = scales[(size_t)b * 3];
  int mbase = m0 + tx * 8;
  bool fullM = (mbase + 7 < M);
  #pragma unroll
  for (int j = 0; j < 4; ++j) {
    int n = n0 + ty * 4 + j;
    if (n >= N) continue;
    float bi = bias[n];
    size_t rowoff = (size_t)n * M + mbase;
    if (fullM) {
      float vv[8];
      #pragma unroll
      for (int i = 0; i < 8; ++i) {
        float v = acc[i][j] + bi;
        if (EPI == 1) v = fmaxf(v, 0.f);
        else if (EPI == 2) v = 0.5f * v * (1.f + erff(v * 0.70710678118654752f));
        else if (EPI == 3) v = 1.f / (1.f + __expf(-v));
        vv[i] = v;
      }
      if (EPI == 3) {
        float4 c0 = *(const float4*)(Cb + rowoff);
        float4 c1 = *(const float4*)(Cb + rowoff + 4);
        vv[0] *= c0.x; vv[1] *= c0.y; vv[2] *= c0.z; vv[3] *= c0.w;
        vv[4] *= c1.x; vv[5] *= c1.y; vv[6] *= c1.z; vv[7] *= c1.w;
      } else if (EPI == 4) {
        float4 r0 = *(const float4*)(Rb + rowoff);
        float4 r1 = *(const float4*)(Rb + rowoff + 4);
        vv[0] = r0.x + sc * vv[0]; vv[1] = r0.y + sc * vv[1];
        vv[2] = r0.z + sc * vv[2]; vv[3] = r0.w + sc * vv[3];
        vv[4] = r1.x + sc * vv[4]; vv[5] = r1.y + sc * vv[5];
        vv[6] = r1.z + sc * vv[6]; vv[7] = r1.w + sc * vv[7];
      }
      float4 o0 = {vv[0], vv[1], vv[2], vv[3]};
      float4 o1 = {vv[4], vv[5], vv[6], vv[7]};
      *(float4*)(Cb + rowoff) = o0;
      *(float4*)(Cb + rowoff + 4) = o1;
    } else {
      #pragma unroll
      for (int i = 0; i < 8; ++i) {
        int m = mbase + i;
        if (m >= M) break;
        float v = acc[i][j] + bi;
        if (EPI == 1) v = fmaxf(v, 0.f);
        else if (EPI == 2) v = 0.5f * v * (1.f + erff(v * 0.70710678118654752f));
        else if (EPI == 3) v = (1.f / (1.f + __expf(-v))) * Cb[(size_t)n * M + m];
        else if (EPI == 4) v = Rb[(size_t)n * M + m] + sc * v;
        Cb[(size_t)n * M + m] = v;
      }
    }
  }
}

// ---------------------------------------------------------------------------
// Attention: per (b, h, 16-row tile). Scores + struct_prior + rpb + face mask
// + softmax + P@V, output to obuf[b, h*64+d, n] (channel-first).
__device__ __forceinline__ int sidx(int m, int r) {
  // S row m holds 16 r-values; float4 groups swizzled by (m>>1)&3 for banks
  return m * 16 + ((((r >> 2) ^ ((m >> 1) & 3)) << 2) | (r & 3));
}

__global__ __launch_bounds__(256) void attn_k(const float* __restrict__ qkv,
                                              const float* __restrict__ sp,
                                              const float* __restrict__ rpb,
                                              const float* __restrict__ fp,
                                              float* __restrict__ obuf) {
  const int n0 = blockIdx.x * 16;
  const int h = blockIdx.y, b = blockIdx.z;
  const float* qb = qkv + ((size_t)b * C3 + h * HDIM) * NPIX;
  const float* kb = qkv + ((size_t)b * C3 + CDIM + h * HDIM) * NPIX;
  const float* vb = qkv + ((size_t)b * C3 + 2 * CDIM + h * HDIM) * NPIX;
  const float* spb = sp + (size_t)h * NPIX * NPIX;
  const float* fpb = fp + (size_t)b * NPIX * NPIX;

  __shared__ float S[NPIX * 16];   // scores, then P (swizzled [m][16])
  __shared__ float kvb[64 * 36];   // q_s [d][16] (phase1) / v_s [mm][68] / sst
  __shared__ float invs[16];

  int t = threadIdx.x;

  // load q tile [64 d][16 r]
  for (int i = t; i < 1024; i += 256) kvb[i] = qb[(size_t)(i >> 4) * NPIX + n0 + (i & 15)];
  __syncthreads();

  // ---- phase 1: scores for m in {t, t+256, t+512, t+768} ----
  float acc[4][16];
  #pragma unroll
  for (int mi = 0; mi < 4; ++mi)
    #pragma unroll
    for (int r = 0; r < 16; ++r) acc[mi][r] = 0.f;
  bool has4 = (t < 16);
  for (int d = 0; d < 64; ++d) {
    const float* krow = kb + (size_t)d * NPIX;
    float kd0 = krow[t];
    float kd1 = krow[t + 256];
    float kd2 = krow[t + 512];
    float kd3 = has4 ? krow[t + 768] : 0.f;
    const float* qr = &kvb[d * 16];
    #pragma unroll
    for (int rq = 0; rq < 4; ++rq) {
      float4 q4 = *(const float4*)(qr + rq * 4);
      acc[0][rq * 4 + 0] += q4.x * kd0; acc[0][rq * 4 + 1] += q4.y * kd0;
      acc[0][rq * 4 + 2] += q4.z * kd0; acc[0][rq * 4 + 3] += q4.w * kd0;
      acc[1][rq * 4 + 0] += q4.x * kd1; acc[1][rq * 4 + 1] += q4.y * kd1;
      acc[1][rq * 4 + 2] += q4.z * kd1; acc[1][rq * 4 + 3] += q4.w * kd1;
      acc[2][rq * 4 + 0] += q4.x * kd2; acc[2][rq * 4 + 1] += q4.y * kd2;
      acc[2][rq * 4 + 2] += q4.z * kd2; acc[2][rq * 4 + 3] += q4.w * kd2;
      acc[3][rq * 4 + 0] += q4.x * kd3; acc[3][rq * 4 + 1] += q4.y * kd3;
      acc[3][rq * 4 + 2] += q4.z * kd3; acc[3][rq * 4 + 3] += q4.w * kd3;
    }
  }
  #pragma unroll
  for (int mi = 0; mi < 4; ++mi) {
    int m = t + mi * 256;
    if (m >= NPIX) break;
    int i2 = m / 28, j2 = m - i2 * 28;
    #pragma unroll
    for (int rq = 0; rq < 4; ++rq) {
      float4 sv;
      float* pv = (float*)&sv;
      #pragma unroll
      for (int rr = 0; rr < 4; ++rr) {
        int r = rq * 4 + rr;
        int n = n0 + r;
        int i1 = n / 28, j1 = n - i1 * 28;
        int rpi = (i1 - i2 + 27) * 55 + (j1 - j2 + 27);
        float val = acc[mi][r] * 0.125f + spb[(size_t)n * NPIX + m] + rpb[rpi * 8 + h];
        val *= fpb[(size_t)n * NPIX + m];
        pv[rr] = val;
      }
      *(float4*)&S[sidx(m, rq * 4)] = sv;
    }
  }
  __syncthreads();

  // ---- phase 2: softmax per row (16 threads per row) ----
  {
    int r = t >> 4, li = t & 15;
    float mx = -1e30f;
    for (int m = li; m < NPIX; m += 16) mx = fmaxf(mx, S[sidx(m, r)]);
    #pragma unroll
    for (int off = 1; off < 16; off <<= 1) mx = fmaxf(mx, __shfl_xor(mx, off));
    float sum = 0.f;
    for (int m = li; m < NPIX; m += 16) {
      float e = __expf(S[sidx(m, r)] - mx);
      S[sidx(m, r)] = e;
      sum += e;
    }
    #pragma unroll
    for (int off = 1; off < 16; off <<= 1) sum += __shfl_xor(sum, off);
    if (li == 0) invs[r] = 1.f / sum;
  }

  // ---- phase 3: O = P @ V.  wave w handles rows w*4..w*4+3 ----
  int w = t >> 6, mq = (t >> 4) & 3, li = t & 15;
  float o[4][4];
  #pragma unroll
  for (int rr = 0; rr < 4; ++rr)
    #pragma unroll
    for (int j = 0; j < 4; ++j) o[rr][j] = 0.f;

  for (int mt = 0; mt < NPIX; mt += 32) {
    int clen = min(32, NPIX - mt);
    __syncthreads();
    if (clen == 32) {
      for (int idx = t; idx < 32 * 64; idx += 256) {
        int mm = idx & 31, d = idx >> 5;
        kvb[mm * 68 + d] = vb[(size_t)d * NPIX + mt + mm];
      }
    } else {
      for (int idx = t; idx < 16 * 64; idx += 256) {
        int mm = idx & 15, d = idx >> 4;
        kvb[mm * 68 + d] = vb[(size_t)d * NPIX + mt + mm];
      }
    }
    __syncthreads();
    for (int mmit = 0; mmit < clen; mmit += 4) {
      int mm = mmit + mq;
      float4 v4 = *(const float4*)&kvb[mm * 68 + li * 4];
      float4 p4 = *(const float4*)&S[sidx(mt + mm, w * 4)];
      o[0][0] += p4.x * v4.x; o[0][1] += p4.x * v4.y; o[0][2] += p4.x * v4.z; o[0][3] += p4.x * v4.w;
      o[1][0] += p4.y * v4.x; o[1][1] += p4.y * v4.y; o[1][2] += p4.y * v4.z; o[1][3] += p4.y * v4.w;
      o[2][0] += p4.z * v4.x; o[2][1] += p4.z * v4.y; o[2][2] += p4.z * v4.z; o[2][3] += p4.z * v4.w;
      o[3][0] += p4.w * v4.x; o[3][1] += p4.w * v4.y; o[3][2] += p4.w * v4.z; o[3][3] += p4.w * v4.w;
    }
  }
  // reduce over mq (lane bits 4,5)
  #pragma unroll
  for (int rr = 0; rr < 4; ++rr)
    #pragma unroll
    for (int j = 0; j < 4; ++j) {
      float v = o[rr][j];
      v += __shfl_xor(v, 16);
      v += __shfl_xor(v, 32);
      o[rr][j] = v;
    }
  __syncthreads();
  if (mq == 0) {
    #pragma unroll
    for (int rr = 0; rr < 4; ++rr)
      #pragma unroll
      for (int j = 0; j < 4; ++j)
        kvb[(li * 4 + j) * 17 + w * 4 + rr] = o[rr][j];
  }
  __syncthreads();
  float* ob = obuf + (size_t)b * CDIM * NPIX;
  {
    int rr = t & 15;
    float inv = invs[rr];
    for (int dd = t >> 4; dd < 64; dd += 16)
      ob[(size_t)(h * HDIM + dd) * NPIX + n0 + rr] = kvb[dd * 17 + rr] * inv;
  }
}

// ---------------------------------------------------------------------------
// fused depthwise 3x3 / 5x5 / 7x7 -> cat[b, {c, 512+c, 1024+c}, p]
__global__ __launch_bounds__(256) void dwconv3_k(const float* __restrict__ xn2,
                                                 const float* __restrict__ ew, const float* __restrict__ eb,
                                                 const float* __restrict__ nw, const float* __restrict__ nb,
                                                 const float* __restrict__ mw, const float* __restrict__ mb,
                                                 float* __restrict__ cat) {
  int c = blockIdx.x, b = blockIdx.y;
  const float* xp = xn2 + ((size_t)b * CDIM + c) * NPIX;
  __shared__ float S[NPIX];
  __shared__ float W[83];
  int tid = threadIdx.x;
  for (int i = tid; i < NPIX; i += 256) S[i] = xp[i];
  if (tid < 83) {
    W[tid] = tid < 9 ? ew[(size_t)c * 9 + tid]
           : tid < 34 ? nw[(size_t)c * 25 + tid - 9]
                      : mw[(size_t)c * 49 + tid - 34];
  }
  __syncthreads();
  float be = eb[c], bn = nb[c], bm = mb[c];
  float* c0 = cat + ((size_t)b * C3 + c) * NPIX;
  float* c1 = cat + ((size_t)b * C3 + CDIM + c) * NPIX;
  float* c2 = cat + ((size_t)b * C3 + 2 * CDIM + c) * NPIX;
  for (int p = tid; p < NPIX; p += 256) {
    int y = p / 28, x = p - y * 28;
    float a0 = 0.f, a1 = 0.f, a2 = 0.f;
    #pragma unroll
    for (int dy = -3; dy <= 3; ++dy) {
      int yy = y + dy;
      if (yy < 0 || yy >= 28) continue;
      #pragma unroll
      for (int dx = -3; dx <= 3; ++dx) {
        int xx = x + dx;
        if (xx < 0 || xx >= 28) continue;
        float v = S[yy * 28 + xx];
        a2 += v * W[34 + (dy + 3) * 7 + (dx + 3)];
        if (dy >= -2 && dy <= 2 && dx >= -2 && dx <= 2)
          a1 += v * W[9 + (dy + 2) * 5 + (dx + 2)];
        if (dy >= -1 && dy <= 1 && dx >= -1 && dx <= 1)
          a0 += v * W[(dy + 1) * 3 + (dx + 1)];
      }
    }
    c0[p] = a0 + be;
    c1[p] = a1 + bn;
    c2[p] = a2 + bm;
  }
}

// ---------------------------------------------------------------------------
// router: r[b] = softmax(pooled3 @ rw.T + rb) over 3 experts
__global__ __launch_bounds__(64) void router_k(const float* __restrict__ pooled,
                                               const float* __restrict__ rw,
                                               const float* __restrict__ rb,
                                               float* __restrict__ r) {
  int b = blockIdx.x, lane = threadIdx.x;
  float a0 = 0.f, a1 = 0.f, a2 = 0.f;
  for (int k = lane; k < CDIM; k += 64) {
    float p = pooled[b * CDIM + k];
    a0 += rw[k] * p;
    a1 += rw[CDIM + k] * p;
    a2 += rw[2 * CDIM + k] * p;
  }
  #pragma unroll
  for (int off = 32; off; off >>= 1) {
    a0 += __shfl_down(a0, off);
    a1 += __shfl_down(a1, off);
    a2 += __shfl_down(a2, off);
  }
  if (lane == 0) {
    float l0 = a0 + rb[0], l1 = a1 + rb[1], l2 = a2 + rb[2];
    float mx = fmaxf(l0, fmaxf(l1, l2));
    float e0 = __expf(l0 - mx), e1 = __expf(l1 - mx), e2 = __expf(l2 - mx);
    float inv = 1.f / (e0 + e1 + e2);
    r[b * 3 + 0] = e0 * inv;
    r[b * 3 + 1] = e1 * inv;
    r[b * 3 + 2] = e2 * inv;
  }
}

// ---------------------------------------------------------------------------
extern "C" void kernel_launch(void* const* d_in, const int* in_sizes, int n_in,
                              void* d_out, int out_size, void* d_ws, size_t ws_size,
                              hipStream_t stream) {
  (void)in_sizes; (void)n_in; (void)out_size; (void)ws_size;
  const float* x         = (const float*)d_in[0];
  const float* fpri      = (const float*)d_in[1];
  const float* n1_w      = (const float*)d_in[2];
  const float* n1_b      = (const float*)d_in[3];
  const float* n1_a1w    = (const float*)d_in[4];
  const float* n1_a1b    = (const float*)d_in[5];
  const float* n1_a2w    = (const float*)d_in[6];
  const float* n1_a2b    = (const float*)d_in[7];
  const float* n2_w      = (const float*)d_in[8];
  const float* n2_b      = (const float*)d_in[9];
  const float* n2_a1w    = (const float*)d_in[10];
  const float* n2_a1b    = (const float*)d_in[11];
  const float* n2_a2w    = (const float*)d_in[12];
  const float* n2_a2b    = (const float*)d_in[13];
  const float* qkv_w     = (const float*)d_in[14];
  const float* qkv_b     = (const float*)d_in[15];
  const float* rpb_table = (const float*)d_in[16];
  const float* sprior    = (const float*)d_in[17];
  const float* proj_w    = (const float*)d_in[18];
  const float* proj_b    = (const float*)d_in[19];
  const float* eye_w     = (const float*)d_in[20];
  const float* eye_b     = (const float*)d_in[21];
  const float* nose_w    = (const float*)d_in[22];
  const float* nose_b    = (const float*)d_in[23];
  const float* mouth_w   = (const float*)d_in[24];
  const float* mouth_b   = (const float*)d_in[25];
  const float* fusion_w  = (const float*)d_in[26];
  const float* fusion_b  = (const float*)d_in[27];
  const float* gate1_w   = (const float*)d_in[28];
  const float* gate1_b   = (const float*)d_in[29];
  const float* gate2_w   = (const float*)d_in[30];
  const float* gate2_b   = (const float*)d_in[31];
  const float* e1w[3] = {(const float*)d_in[32], (const float*)d_in[36], (const float*)d_in[40]};
  const float* e1b[3] = {(const float*)d_in[33], (const float*)d_in[37], (const float*)d_in[41]};
  const float* e2w[3] = {(const float*)d_in[34], (const float*)d_in[38], (const float*)d_in[42]};
  const float* e2b[3] = {(const float*)d_in[35], (const float*)d_in[39], (const float*)d_in[43]};
  const float* router_w  = (const float*)d_in[44];
  const float* router_b  = (const float*)d_in[45];

  float* ws   = (float*)d_ws;
  float* bufA = ws + OFF_A;   // xa -> xn2 -> x3
  float* bufB = ws + OFF_B;   // qkv -> cat -> expert hidden
  float* bufC = ws + OFF_C;   // attn out -> gate hidden
  float* bufD = ws + OFF_D;   // x2
  float* pld  = ws + OFF_PL;
  float* adb  = ws + OFF_AD;
  float* rbuf = ws + OFF_R;
  float* outp = (float*)d_out;

  // --- LN1 ---
  pool_mean_k<<<dim3(CDIM, 16), 64, 0, stream>>>(x, pld);
  adapt_mlp_k<<<16, 256, 0, stream>>>(pld, n1_a1w, n1_a1b, n1_a2w, n1_a2b, adb);
  ln_apply_k<<<dim3(25, 16), 256, 0, stream>>>(x, n1_w, n1_b, adb, bufA);
  // --- attention ---
  gemm_k<0><<<dim3(7, 24, 16), 256, 0, stream>>>(bufA, qkv_w, qkv_b, nullptr, nullptr, bufB, 512, 1536);
  attn_k<<<dim3(49, 8, 16), 256, 0, stream>>>(bufB, sprior, rpb_table, fpri, bufC);
  gemm_k<4><<<dim3(7, 8, 16), 256, 0, stream>>>(bufC, proj_w, proj_b, x, nullptr, bufD, 512, 512);
  // --- LN2 ---
  pool_mean_k<<<dim3(CDIM, 16), 64, 0, stream>>>(bufD, pld);
  adapt_mlp_k<<<16, 256, 0, stream>>>(pld, n2_a1w, n2_a1b, n2_a2w, n2_a2b, adb);
  ln_apply_k<<<dim3(25, 16), 256, 0, stream>>>(bufD, n2_w, n2_b, adb, bufA);
  // --- token mixer ---
  dwconv3_k<<<dim3(CDIM, 16), 256, 0, stream>>>(bufA, eye_w, eye_b, nose_w, nose_b, mouth_w, mouth_b, bufB);
  gemm_k<1><<<dim3(7, 2, 16), 256, 0, stream>>>(bufA, gate1_w, gate1_b, nullptr, nullptr, bufC, 512, 128);
  gemm_k<3><<<dim3(7, 24, 16), 256, 0, stream>>>(bufC, gate2_w, gate2_b, nullptr, nullptr, bufB, 128, 1536);
  gemm_k<4><<<dim3(7, 8, 16), 256, 0, stream>>>(bufB, fusion_w, fusion_b, bufD, nullptr, bufA, 1536, 512);
  // --- MoE ---
  pool_mean_k<<<dim3(CDIM, 16), 64, 0, stream>>>(bufA, pld);
  router_k<<<16, 64, 0, stream>>>(pld, router_w, router_b, rbuf);
  for (int e = 0; e < 3; ++e) {
    gemm_k<2><<<dim3(7, 11, 16), 256, 0, stream>>>(bufA, e1w[e], e1b[e], nullptr, nullptr, bufB, 512, H3DIM);
    gemm_k<4><<<dim3(7, 8, 16), 256, 0, stream>>>(bufB, e2w[e], e2b[e], (e == 0) ? bufA : outp, rbuf + e, outp, H3DIM, 512);
  }
}

// Round 2
// 2315.787 us; speedup vs baseline: 1.2785x; 1.2785x over previous
//
#include <hip/hip_runtime.h>
#include <math.h>

// ---------------------------------------------------------------------------
// EfficientFaceTransformer forward.
// Round 2: bf16 MFMA flash-attention (swapped-QK^T, online softmax, no barriers).
// Layouts: all fp32 activations channel-first [b][c][p], p = 28*28 = 784.
// ---------------------------------------------------------------------------

#define NPIX 784
#define CDIM 512
#define NHEAD 8
#define HDIM 64
#define C3 1536
#define H3DIM 682

typedef unsigned short ushort;
typedef float f32x4 __attribute__((ext_vector_type(4)));
typedef __bf16 bf16x8 __attribute__((ext_vector_type(8)));

// ---- workspace float offsets --------------------------------------------
#define OFF_A   ((size_t)0)           // 16*512*784   (xa -> QKbf -> xn2 -> x3)
#define OFF_B   ((size_t)6422528)     // 16*1536*784  (qkv -> cat -> h_e)
#define OFF_C   ((size_t)25690112)    // 16*512*784   (attn o -> gtmp)
#define OFF_D   ((size_t)32112640)    // 16*512*784   (Vbf -> x2)
#define OFF_PL  ((size_t)38535168)    // 16*512 pooled
#define OFF_AD  ((size_t)38543360)    // 16*1024 adapt out
#define OFF_R   ((size_t)38559744)    // 16*3 router

__device__ __forceinline__ ushort f2bf(float f) {
  unsigned u = __builtin_bit_cast(unsigned, f);
  unsigned r = (u + 0x7fffu + ((u >> 16) & 1u)) >> 16;
  return (ushort)r;
}
__device__ __forceinline__ unsigned pack2bf(float lo, float hi) {
  return (unsigned)f2bf(lo) | ((unsigned)f2bf(hi) << 16);
}

// ---------------------------------------------------------------------------
// pooled[b,c] = mean_p x[b,c,p]
__global__ __launch_bounds__(64) void pool_mean_k(const float* __restrict__ x,
                                                  float* __restrict__ pooled) {
  int c = blockIdx.x, b = blockIdx.y;
  const float* row = x + ((size_t)b * CDIM + c) * NPIX;
  float s = 0.f;
  for (int i = threadIdx.x; i < NPIX; i += 64) s += row[i];
  #pragma unroll
  for (int off = 32; off; off >>= 1) s += __shfl_down(s, off);
  if (threadIdx.x == 0) pooled[b * CDIM + c] = s * (1.f / NPIX);
}

// ---------------------------------------------------------------------------
// h = relu(pooled @ a1w.T + a1b) [128]; ad = h @ a2w.T + a2b [1024]
__global__ __launch_bounds__(256) void adapt_mlp_k(const float* __restrict__ pooled,
                                                   const float* __restrict__ a1w,
                                                   const float* __restrict__ a1b,
                                                   const float* __restrict__ a2w,
                                                   const float* __restrict__ a2b,
                                                   float* __restrict__ ad) {
  int b = blockIdx.x, tid = threadIdx.x;
  __shared__ float pl[CDIM];
  __shared__ float hh[128];
  for (int i = tid; i < CDIM; i += 256) pl[i] = pooled[b * CDIM + i];
  __syncthreads();
  if (tid < 128) {
    const float* w = a1w + (size_t)tid * CDIM;
    float a = a1b[tid];
    for (int k = 0; k < CDIM; ++k) a += w[k] * pl[k];
    hh[tid] = fmaxf(a, 0.f);
  }
  __syncthreads();
  for (int o = tid; o < 1024; o += 256) {
    const float* w = a2w + (size_t)o * 128;
    float a = a2b[o];
    for (int k = 0; k < 128; ++k) a += w[k] * hh[k];
    ad[b * 1024 + o] = a;
  }
}

// ---------------------------------------------------------------------------
// adaptive LN
__global__ __launch_bounds__(256) void ln_apply_k(const float* __restrict__ x,
                                                  const float* __restrict__ w,
                                                  const float* __restrict__ bias,
                                                  const float* __restrict__ ad,
                                                  float* __restrict__ out) {
  int b = blockIdx.y;
  int p0 = blockIdx.x * 32;
  int tid = threadIdx.x;
  int px = tid & 31, cg = tid >> 5;
  int p = p0 + px;
  bool valid = p < NPIX;
  const float* xb = x + (size_t)b * CDIM * NPIX;
  float s = 0.f, s2 = 0.f;
  if (valid) {
    for (int c = cg * 64; c < cg * 64 + 64; ++c) {
      float v = xb[(size_t)c * NPIX + p];
      s += v; s2 += v * v;
    }
  }
  __shared__ float rs[8][32], rq[8][32];
  __shared__ float us[32], vs[32];
  rs[cg][px] = s; rq[cg][px] = s2;
  __syncthreads();
  if (tid < 32) {
    float ts = 0.f, ts2 = 0.f;
    #pragma unroll
    for (int g = 0; g < 8; ++g) { ts += rs[g][tid]; ts2 += rq[g][tid]; }
    float u = ts * (1.f / CDIM);
    float var = ts2 * (1.f / CDIM) - u * u;
    us[tid] = u;
    vs[tid] = rsqrtf(var + 1e-6f);
  }
  __syncthreads();
  if (valid) {
    float u = us[px], rst = vs[px];
    const float* aw = ad + (size_t)b * 1024;
    const float* ab = aw + CDIM;
    float* ob = out + (size_t)b * CDIM * NPIX;
    for (int c = cg * 64; c < cg * 64 + 64; ++c) {
      float v = xb[(size_t)c * NPIX + p];
      float xn = (v - u) * rst;
      ob[(size_t)c * NPIX + p] = w[c] * (1.f + aw[c]) * xn + (bias[c] + ab[c]);
    }
  }
}

// ---------------------------------------------------------------------------
// Generic fp32 GEMM (unchanged this round).
template <int EPI>
__global__ __launch_bounds__(256) void gemm_k(const float* __restrict__ A,
                                              const float* __restrict__ Bw,
                                              const float* __restrict__ bias,
                                              const float* __restrict__ resid,
                                              const float* __restrict__ scales,
                                              float* __restrict__ C,
                                              int K, int N) {
  const int M = NPIX;
  int b = blockIdx.z;
  const float* Ab = A + (size_t)b * K * M;
  float* Cb = C + (size_t)b * N * M;
  const float* Rb = resid ? resid + (size_t)b * N * M : nullptr;
  int m0 = blockIdx.x * 128, n0 = blockIdx.y * 64;
  __shared__ float As[16][132];
  __shared__ float Bs[16][68];
  int tid = threadIdx.x;
  int tx = tid & 15, ty = tid >> 4;
  float acc[8][4];
  #pragma unroll
  for (int i = 0; i < 8; ++i)
    #pragma unroll
    for (int j = 0; j < 4; ++j) acc[i][j] = 0.f;

  const bool kvec = (K & 3) == 0;
  for (int k0 = 0; k0 < K; k0 += 16) {
    {
      int mm = (tid & 31) * 4;
      int kkb = tid >> 5;
      #pragma unroll
      for (int ph = 0; ph < 2; ++ph) {
        int kk = kkb + ph * 8;
        int gk = k0 + kk, gm = m0 + mm;
        float4 v = {0.f, 0.f, 0.f, 0.f};
        if (gk < K) {
          if (gm + 3 < M) {
            v = *(const float4*)(Ab + (size_t)gk * M + gm);
          } else {
            float tv[4];
            #pragma unroll
            for (int q = 0; q < 4; ++q)
              tv[q] = (gm + q < M) ? Ab[(size_t)gk * M + gm + q] : 0.f;
            v = {tv[0], tv[1], tv[2], tv[3]};
          }
        }
        *(float4*)&As[kk][mm] = v;
      }
    }
    {
      int nn = tid >> 2, kk = (tid & 3) * 4;
      int gn = n0 + nn, gk = k0 + kk;
      float4 v = {0.f, 0.f, 0.f, 0.f};
      if (gn < N) {
        if (kvec && gk + 3 < K) {
          v = *(const float4*)(Bw + (size_t)gn * K + gk);
        } else {
          float tv[4];
          #pragma unroll
          for (int q = 0; q < 4; ++q)
            tv[q] = (gk + q < K) ? Bw[(size_t)gn * K + gk + q] : 0.f;
          v = {tv[0], tv[1], tv[2], tv[3]};
        }
      }
      Bs[kk][nn] = v.x; Bs[kk + 1][nn] = v.y;
      Bs[kk + 2][nn] = v.z; Bs[kk + 3][nn] = v.w;
    }
    __syncthreads();
    #pragma unroll
    for (int kk = 0; kk < 16; ++kk) {
      float4 a0 = *(const float4*)&As[kk][tx * 8];
      float4 a1 = *(const float4*)&As[kk][tx * 8 + 4];
      float4 bv = *(const float4*)&Bs[kk][ty * 4];
      float av[8] = {a0.x, a0.y, a0.z, a0.w, a1.x, a1.y, a1.z, a1.w};
      float bb[4] = {bv.x, bv.y, bv.z, bv.w};
      #pragma unroll
      for (int i = 0; i < 8; ++i)
        #pragma unroll
        for (int j = 0; j < 4; ++j) acc[i][j] += av[i] * bb[j];
    }
    __syncthreads();
  }

  float sc = 1.f;
  if (EPI == 4 && scales) sc = scales[(size_t)b * 3];
  int mbase = m0 + tx * 8;
  bool fullM = (mbase + 7 < M);
  #pragma unroll
  for (int j = 0; j < 4; ++j) {
    int n = n0 + ty * 4 + j;
    if (n >= N) continue;
    float bi = bias[n];
    size_t rowoff = (size_t)n * M + mbase;
    if (fullM) {
      float vv[8];
      #pragma unroll
      for (int i = 0; i < 8; ++i) {
        float v = acc[i][j] + bi;
        if (EPI == 1) v = fmaxf(v, 0.f);
        else if (EPI == 2) v = 0.5f * v * (1.f + erff(v * 0.70710678118654752f));
        else if (EPI == 3) v = 1.f / (1.f + __expf(-v));
        vv[i] = v;
      }
      if (EPI == 3) {
        float4 c0 = *(const float4*)(Cb + rowoff);
        float4 c1 = *(const float4*)(Cb + rowoff + 4);
        vv[0] *= c0.x; vv[1] *= c0.y; vv[2] *= c0.z; vv[3] *= c0.w;
        vv[4] *= c1.x; vv[5] *= c1.y; vv[6] *= c1.z; vv[7] *= c1.w;
      } else if (EPI == 4) {
        float4 r0 = *(const float4*)(Rb + rowoff);
        float4 r1 = *(const float4*)(Rb + rowoff + 4);
        vv[0] = r0.x + sc * vv[0]; vv[1] = r0.y + sc * vv[1];
        vv[2] = r0.z + sc * vv[2]; vv[3] = r0.w + sc * vv[3];
        vv[4] = r1.x + sc * vv[4]; vv[5] = r1.y + sc * vv[5];
        vv[6] = r1.z + sc * vv[6]; vv[7] = r1.w + sc * vv[7];
      }
      float4 o0 = {vv[0], vv[1], vv[2], vv[3]};
      float4 o1 = {vv[4], vv[5], vv[6], vv[7]};
      *(float4*)(Cb + rowoff) = o0;
      *(float4*)(Cb + rowoff + 4) = o1;
    } else {
      #pragma unroll
      for (int i = 0; i < 8; ++i) {
        int m = mbase + i;
        if (m >= M) break;
        float v = acc[i][j] + bi;
        if (EPI == 1) v = fmaxf(v, 0.f);
        else if (EPI == 2) v = 0.5f * v * (1.f + erff(v * 0.70710678118654752f));
        else if (EPI == 3) v = (1.f / (1.f + __expf(-v))) * Cb[(size_t)n * M + m];
        else if (EPI == 4) v = Rb[(size_t)n * M + m] + sc * v;
        Cb[(size_t)n * M + m] = v;
      }
    }
  }
}

// ---------------------------------------------------------------------------
// qkv fp32 [b][c][n] -> QKbf [b][hs][n][64] bf16 (hs = 0..7 Q heads, 8..15 K heads)
__global__ __launch_bounds__(256) void qk_cvt_k(const float* __restrict__ qkv,
                                                ushort* __restrict__ out) {
  int nt = blockIdx.x, hs = blockIdx.y, b = blockIdx.z;
  int n0 = nt * 64;
  int t = threadIdx.x;
  const float* src = qkv + ((size_t)b * C3 + hs * 64) * NPIX;
  ushort* dst = out + ((size_t)(b * 16 + hs) * NPIX) * 64;
  __shared__ ushort T[64][72];
  for (int idx = t; idx < 4096; idx += 256) {
    int d = idx >> 6, nn = idx & 63;
    int n = n0 + nn;
    T[nn][d] = (n < NPIX) ? f2bf(src[(size_t)d * NPIX + n]) : (ushort)0;
  }
  __syncthreads();
  for (int idx = t; idx < 512; idx += 256) {
    int nn = idx >> 3, ch = idx & 7;
    int n = n0 + nn;
    if (n < NPIX) {
      uint4 v = *(const uint4*)&T[nn][ch * 8];
      *(uint4*)(dst + ((size_t)n << 6) + ch * 8) = v;
    }
  }
}

// v part: pure element-wise cast, same [c][n] layout. grid (392, 16)
__global__ __launch_bounds__(256) void v_cvt_k(const float* __restrict__ qkv,
                                               ushort* __restrict__ out) {
  int b = blockIdx.y;
  int idx = blockIdx.x * 256 + threadIdx.x;   // float4 index, 100352 per b
  if (idx >= 100352) return;
  const float4 v = *((const float4*)(qkv + ((size_t)b * C3 + 1024) * NPIX) + idx);
  ushort4 o;
  o.x = f2bf(v.x); o.y = f2bf(v.y); o.z = f2bf(v.z); o.w = f2bf(v.w);
  *((ushort4*)(out + (size_t)b * CDIM * NPIX) + idx) = o;
}

// ---------------------------------------------------------------------------
// MFMA flash attention.
// Per wave: 16 query rows. S^T = mfma(K_tile, Q_tile) so softmax over m is
// in-register (3 maxes + shfl_xor 16/32); P^T (C-layout) -> PV B-operand via
// a wave-private LDS bounce; O accumulated as O^T (coalesced [d][n] store).
__global__ __launch_bounds__(256) void attn_mfma_k(const ushort* __restrict__ qkbf,
                                                   const ushort* __restrict__ vbf,
                                                   const float* __restrict__ sp,
                                                   const float* __restrict__ rpb,
                                                   const float* __restrict__ fp,
                                                   float* __restrict__ obuf) {
  const int qt = blockIdx.x, h = blockIdx.y, b = blockIdx.z;
  const int w = threadIdx.x >> 6, lane = threadIdx.x & 63;
  const int g = lane >> 4, c = lane & 15;
  const int n0 = qt * 64 + w * 16;
  if (n0 + 16 > NPIX) return;          // tail q-tile: only wave 0 active
  const int q = n0 + c;

  __shared__ __align__(16) unsigned bounce[4][392];
  unsigned* bw = bounce[w];

  // persistent Q fragments (B-operand: col=q, k=d)
  const ushort* qptr = qkbf + (((size_t)(b * 16 + h) * NPIX + q) << 6) + g * 8;
  const bf16x8 qf0 = *(const bf16x8*)qptr;
  const bf16x8 qf1 = *(const bf16x8*)(qptr + 32);

  const ushort* kbase = qkbf + (((size_t)(b * 16 + 8 + h) * NPIX) << 6);
  const ushort* vbase = vbf + (((size_t)b * CDIM + h * HDIM)) * NPIX;
  const float* spq = sp + ((size_t)h * NPIX + q) * NPIX;
  const float* fpq = fp + ((size_t)b * NPIX + q) * NPIX;
  const int i1 = q / 28, j1 = q - (q / 28) * 28;

  f32x4 ot0 = {0.f, 0.f, 0.f, 0.f}, ot1 = ot0, ot2 = ot0, ot3 = ot0;
  float M = -1e30f, L = 0.f;

  for (int ms = 0; ms < 25; ++ms) {
    const int m0 = ms * 32;
    const bool full = (ms < 24);

    // ---- S^T tiles via MFMA (A = K rows, B = Q) ----
    f32x4 s0 = {0.f, 0.f, 0.f, 0.f}, s1 = s0;
    {
      const ushort* kp = kbase + (((size_t)(m0 + c)) << 6) + g * 8;
      bf16x8 ka0 = *(const bf16x8*)kp;
      bf16x8 ka1 = *(const bf16x8*)(kp + 32);
      s0 = __builtin_amdgcn_mfma_f32_16x16x32_bf16(ka0, qf0, s0, 0, 0, 0);
      s0 = __builtin_amdgcn_mfma_f32_16x16x32_bf16(ka1, qf1, s0, 0, 0, 0);
      if (full) {
        const ushort* kp1 = kp + (16 << 6);
        bf16x8 kb0 = *(const bf16x8*)kp1;
        bf16x8 kb1 = *(const bf16x8*)(kp1 + 32);
        s1 = __builtin_amdgcn_mfma_f32_16x16x32_bf16(kb0, qf0, s1, 0, 0, 0);
        s1 = __builtin_amdgcn_mfma_f32_16x16x32_bf16(kb1, qf1, s1, 0, 0, 0);
      }
    }

    // ---- biases: (s*0.125 + struct_prior + rpb) * face_prior ----
    float v0[4], v1[4];
    {
      const int mb0 = m0 + g * 4;
      float4 sp4 = *(const float4*)(spq + mb0);
      float4 fp4 = *(const float4*)(fpq + mb0);
      const float spv[4] = {sp4.x, sp4.y, sp4.z, sp4.w};
      const float fpv[4] = {fp4.x, fp4.y, fp4.z, fp4.w};
      #pragma unroll
      for (int j = 0; j < 4; ++j) {
        int m = mb0 + j;
        int i2 = m / 28, j2 = m - i2 * 28;
        float rv = rpb[(size_t)((i1 - i2 + 27) * 55 + (j1 - j2 + 27)) * NHEAD + h];
        v0[j] = (s0[j] * 0.125f + spv[j] + rv) * fpv[j];
      }
    }
    if (full) {
      const int mb1 = m0 + 16 + g * 4;
      float4 sp4 = *(const float4*)(spq + mb1);
      float4 fp4 = *(const float4*)(fpq + mb1);
      const float spv[4] = {sp4.x, sp4.y, sp4.z, sp4.w};
      const float fpv[4] = {fp4.x, fp4.y, fp4.z, fp4.w};
      #pragma unroll
      for (int j = 0; j < 4; ++j) {
        int m = mb1 + j;
        int i2 = m / 28, j2 = m - i2 * 28;
        float rv = rpb[(size_t)((i1 - i2 + 27) * 55 + (j1 - j2 + 27)) * NHEAD + h];
        v1[j] = (s1[j] * 0.125f + spv[j] + rv) * fpv[j];
      }
    }

    // ---- online softmax update (reduction over m = regs + lane-groups) ----
    float tm = fmaxf(fmaxf(v0[0], v0[1]), fmaxf(v0[2], v0[3]));
    if (full) tm = fmaxf(tm, fmaxf(fmaxf(v1[0], v1[1]), fmaxf(v1[2], v1[3])));
    tm = fmaxf(tm, __shfl_xor(tm, 16));
    tm = fmaxf(tm, __shfl_xor(tm, 32));
    const float nM = fmaxf(M, tm);
    const float fac = __expf(M - nM);
    float p0[4], p1[4];
    float ps = 0.f;
    #pragma unroll
    for (int j = 0; j < 4; ++j) { p0[j] = __expf(v0[j] - nM); ps += p0[j]; }
    if (full) {
      #pragma unroll
      for (int j = 0; j < 4; ++j) { p1[j] = __expf(v1[j] - nM); ps += p1[j]; }
    }
    ps += __shfl_xor(ps, 16);
    ps += __shfl_xor(ps, 32);
    L = L * fac + ps;
    M = nM;
    #pragma unroll
    for (int j = 0; j < 4; ++j) { ot0[j] *= fac; ot1[j] *= fac; ot2[j] *= fac; ot3[j] *= fac; }

    // ---- P^T -> PV B-operand via wave-private LDS bounce ----
    {
      uint2 wlo, whi;
      wlo.x = pack2bf(p0[0], p0[1]);
      wlo.y = pack2bf(p0[2], p0[3]);
      whi.x = full ? pack2bf(p1[0], p1[1]) : 0u;
      whi.y = full ? pack2bf(p1[2], p1[3]) : 0u;
      *(uint2*)&bw[lane * 6] = wlo;
      *(uint2*)&bw[lane * 6 + 2] = whi;
    }
    const int f = g >> 1;
    const int slo = 32 * (g & 1) + c;
    uint2 blo = *(const uint2*)&bw[slo * 6 + f * 2];
    uint2 bhi = *(const uint2*)&bw[(slo + 16) * 6 + f * 2];
    uint4 bb;
    bb.x = blo.x; bb.y = blo.y; bb.z = bhi.x; bb.w = bhi.y;
    const bf16x8 pfrag = __builtin_bit_cast(bf16x8, bb);

    // ---- PV: O^T[f4] += mfma(V^T tile, P^T) ----
    {
      const ushort* vp = vbase + (size_t)c * NPIX + m0 + g * 8;
      bf16x8 vf0 = *(const bf16x8*)(vp);
      bf16x8 vf1 = *(const bf16x8*)(vp + (size_t)16 * NPIX);
      bf16x8 vf2 = *(const bf16x8*)(vp + (size_t)32 * NPIX);
      bf16x8 vf3 = *(const bf16x8*)(vp + (size_t)48 * NPIX);
      ot0 = __builtin_amdgcn_mfma_f32_16x16x32_bf16(vf0, pfrag, ot0, 0, 0, 0);
      ot1 = __builtin_amdgcn_mfma_f32_16x16x32_bf16(vf1, pfrag, ot1, 0, 0, 0);
      ot2 = __builtin_amdgcn_mfma_f32_16x16x32_bf16(vf2, pfrag, ot2, 0, 0, 0);
      ot3 = __builtin_amdgcn_mfma_f32_16x16x32_bf16(vf3, pfrag, ot3, 0, 0, 0);
    }
  }

  const float invL = 1.f / L;
  float* ob = obuf + ((size_t)b * CDIM + h * HDIM) * NPIX + n0 + c;
  #pragma unroll
  for (int j = 0; j < 4; ++j) {
    ob[(size_t)(0  + g * 4 + j) * NPIX] = ot0[j] * invL;
    ob[(size_t)(16 + g * 4 + j) * NPIX] = ot1[j] * invL;
    ob[(size_t)(32 + g * 4 + j) * NPIX] = ot2[j] * invL;
    ob[(size_t)(48 + g * 4 + j) * NPIX] = ot3[j] * invL;
  }
}

// ---------------------------------------------------------------------------
// fused depthwise 3x3 / 5x5 / 7x7 -> cat[b, {c, 512+c, 1024+c}, p]
__global__ __launch_bounds__(256) void dwconv3_k(const float* __restrict__ xn2,
                                                 const float* __restrict__ ew, const float* __restrict__ eb,
                                                 const float* __restrict__ nw, const float* __restrict__ nb,
                                                 const float* __restrict__ mw, const float* __restrict__ mb,
                                                 float* __restrict__ cat) {
  int c = blockIdx.x, b = blockIdx.y;
  const float* xp = xn2 + ((size_t)b * CDIM + c) * NPIX;
  __shared__ float S[NPIX];
  __shared__ float W[83];
  int tid = threadIdx.x;
  for (int i = tid; i < NPIX; i += 256) S[i] = xp[i];
  if (tid < 83) {
    W[tid] = tid < 9 ? ew[(size_t)c * 9 + tid]
           : tid < 34 ? nw[(size_t)c * 25 + tid - 9]
                      : mw[(size_t)c * 49 + tid - 34];
  }
  __syncthreads();
  float be = eb[c], bn = nb[c], bm = mb[c];
  float* c0 = cat + ((size_t)b * C3 + c) * NPIX;
  float* c1 = cat + ((size_t)b * C3 + CDIM + c) * NPIX;
  float* c2 = cat + ((size_t)b * C3 + 2 * CDIM + c) * NPIX;
  for (int p = tid; p < NPIX; p += 256) {
    int y = p / 28, x = p - y * 28;
    float a0 = 0.f, a1 = 0.f, a2 = 0.f;
    #pragma unroll
    for (int dy = -3; dy <= 3; ++dy) {
      int yy = y + dy;
      if (yy < 0 || yy >= 28) continue;
      #pragma unroll
      for (int dx = -3; dx <= 3; ++dx) {
        int xx = x + dx;
        if (xx < 0 || xx >= 28) continue;
        float v = S[yy * 28 + xx];
        a2 += v * W[34 + (dy + 3) * 7 + (dx + 3)];
        if (dy >= -2 && dy <= 2 && dx >= -2 && dx <= 2)
          a1 += v * W[9 + (dy + 2) * 5 + (dx + 2)];
        if (dy >= -1 && dy <= 1 && dx >= -1 && dx <= 1)
          a0 += v * W[(dy + 1) * 3 + (dx + 1)];
      }
    }
    c0[p] = a0 + be;
    c1[p] = a1 + bn;
    c2[p] = a2 + bm;
  }
}

// ---------------------------------------------------------------------------
__global__ __launch_bounds__(64) void router_k(const float* __restrict__ pooled,
                                               const float* __restrict__ rw,
                                               const float* __restrict__ rb,
                                               float* __restrict__ r) {
  int b = blockIdx.x, lane = threadIdx.x;
  float a0 = 0.f, a1 = 0.f, a2 = 0.f;
  for (int k = lane; k < CDIM; k += 64) {
    float p = pooled[b * CDIM + k];
    a0 += rw[k] * p;
    a1 += rw[CDIM + k] * p;
    a2 += rw[2 * CDIM + k] * p;
  }
  #pragma unroll
  for (int off = 32; off; off >>= 1) {
    a0 += __shfl_down(a0, off);
    a1 += __shfl_down(a1, off);
    a2 += __shfl_down(a2, off);
  }
  if (lane == 0) {
    float l0 = a0 + rb[0], l1 = a1 + rb[1], l2 = a2 + rb[2];
    float mx = fmaxf(l0, fmaxf(l1, l2));
    float e0 = __expf(l0 - mx), e1 = __expf(l1 - mx), e2 = __expf(l2 - mx);
    float inv = 1.f / (e0 + e1 + e2);
    r[b * 3 + 0] = e0 * inv;
    r[b * 3 + 1] = e1 * inv;
    r[b * 3 + 2] = e2 * inv;
  }
}

// ---------------------------------------------------------------------------
extern "C" void kernel_launch(void* const* d_in, const int* in_sizes, int n_in,
                              void* d_out, int out_size, void* d_ws, size_t ws_size,
                              hipStream_t stream) {
  (void)in_sizes; (void)n_in; (void)out_size; (void)ws_size;
  const float* x         = (const float*)d_in[0];
  const float* fpri      = (const float*)d_in[1];
  const float* n1_w      = (const float*)d_in[2];
  const float* n1_b      = (const float*)d_in[3];
  const float* n1_a1w    = (const float*)d_in[4];
  const float* n1_a1b    = (const float*)d_in[5];
  const float* n1_a2w    = (const float*)d_in[6];
  const float* n1_a2b    = (const float*)d_in[7];
  const float* n2_w      = (const float*)d_in[8];
  const float* n2_b      = (const float*)d_in[9];
  const float* n2_a1w    = (const float*)d_in[10];
  const float* n2_a1b    = (const float*)d_in[11];
  const float* n2_a2w    = (const float*)d_in[12];
  const float* n2_a2b    = (const float*)d_in[13];
  const float* qkv_w     = (const float*)d_in[14];
  const float* qkv_b     = (const float*)d_in[15];
  const float* rpb_table = (const float*)d_in[16];
  const float* sprior    = (const float*)d_in[17];
  const float* proj_w    = (const float*)d_in[18];
  const float* proj_b    = (const float*)d_in[19];
  const float* eye_w     = (const float*)d_in[20];
  const float* eye_b     = (const float*)d_in[21];
  const float* nose_w    = (const float*)d_in[22];
  const float* nose_b    = (const float*)d_in[23];
  const float* mouth_w   = (const float*)d_in[24];
  const float* mouth_b   = (const float*)d_in[25];
  const float* fusion_w  = (const float*)d_in[26];
  const float* fusion_b  = (const float*)d_in[27];
  const float* gate1_w   = (const float*)d_in[28];
  const float* gate1_b   = (const float*)d_in[29];
  const float* gate2_w   = (const float*)d_in[30];
  const float* gate2_b   = (const float*)d_in[31];
  const float* e1w[3] = {(const float*)d_in[32], (const float*)d_in[36], (const float*)d_in[40]};
  const float* e1b[3] = {(const float*)d_in[33], (const float*)d_in[37], (const float*)d_in[41]};
  const float* e2w[3] = {(const float*)d_in[34], (const float*)d_in[38], (const float*)d_in[42]};
  const float* e2b[3] = {(const float*)d_in[35], (const float*)d_in[39], (const float*)d_in[43]};
  const float* router_w  = (const float*)d_in[44];
  const float* router_b  = (const float*)d_in[45];

  float* ws   = (float*)d_ws;
  float* bufA = ws + OFF_A;   // xa -> QKbf -> xn2 -> x3
  float* bufB = ws + OFF_B;   // qkv -> cat -> expert hidden
  float* bufC = ws + OFF_C;   // attn out -> gate hidden
  float* bufD = ws + OFF_D;   // Vbf -> x2
  float* pld  = ws + OFF_PL;
  float* adb  = ws + OFF_AD;
  float* rbuf = ws + OFF_R;
  float* outp = (float*)d_out;

  ushort* qkbf = (ushort*)bufA;   // 25.7 MB, exactly bufA (xa dead after qkv gemm)
  ushort* vbf  = (ushort*)bufD;   // 12.8 MB, bufD free until proj writes it

  // --- LN1 ---
  pool_mean_k<<<dim3(CDIM, 16), 64, 0, stream>>>(x, pld);
  adapt_mlp_k<<<16, 256, 0, stream>>>(pld, n1_a1w, n1_a1b, n1_a2w, n1_a2b, adb);
  ln_apply_k<<<dim3(25, 16), 256, 0, stream>>>(x, n1_w, n1_b, adb, bufA);
  // --- attention ---
  gemm_k<0><<<dim3(7, 24, 16), 256, 0, stream>>>(bufA, qkv_w, qkv_b, nullptr, nullptr, bufB, 512, 1536);
  qk_cvt_k<<<dim3(13, 16, 16), 256, 0, stream>>>(bufB, qkbf);
  v_cvt_k<<<dim3(392, 16), 256, 0, stream>>>(bufB, vbf);
  attn_mfma_k<<<dim3(13, 8, 16), 256, 0, stream>>>(qkbf, vbf, sprior, rpb_table, fpri, bufC);
  gemm_k<4><<<dim3(7, 8, 16), 256, 0, stream>>>(bufC, proj_w, proj_b, x, nullptr, bufD, 512, 512);
  // --- LN2 ---
  pool_mean_k<<<dim3(CDIM, 16), 64, 0, stream>>>(bufD, pld);
  adapt_mlp_k<<<16, 256, 0, stream>>>(pld, n2_a1w, n2_a1b, n2_a2w, n2_a2b, adb);
  ln_apply_k<<<dim3(25, 16), 256, 0, stream>>>(bufD, n2_w, n2_b, adb, bufA);
  // --- token mixer ---
  dwconv3_k<<<dim3(CDIM, 16), 256, 0, stream>>>(bufA, eye_w, eye_b, nose_w, nose_b, mouth_w, mouth_b, bufB);
  gemm_k<1><<<dim3(7, 2, 16), 256, 0, stream>>>(bufA, gate1_w, gate1_b, nullptr, nullptr, bufC, 512, 128);
  gemm_k<3><<<dim3(7, 24, 16), 256, 0, stream>>>(bufC, gate2_w, gate2_b, nullptr, nullptr, bufB, 128, 1536);
  gemm_k<4><<<dim3(7, 8, 16), 256, 0, stream>>>(bufB, fusion_w, fusion_b, bufD, nullptr, bufA, 1536, 512);
  // --- MoE ---
  pool_mean_k<<<dim3(CDIM, 16), 64, 0, stream>>>(bufA, pld);
  router_k<<<16, 64, 0, stream>>>(pld, router_w, router_b, rbuf);
  for (int e = 0; e < 3; ++e) {
    gemm_k<2><<<dim3(7, 11, 16), 256, 0, stream>>>(bufA, e1w[e], e1b[e], nullptr, nullptr, bufB, 512, H3DIM);
    gemm_k<4><<<dim3(7, 8, 16), 256, 0, stream>>>(bufB, e2w[e], e2b[e], (e == 0) ? bufA : outp, rbuf + e, outp, H3DIM, 512);
  }
}

// Round 3
// 1246.951 us; speedup vs baseline: 2.3744x; 1.8572x over previous
//
#include <hip/hip_runtime.h>
#include <math.h>

// ---------------------------------------------------------------------------
// EfficientFaceTransformer forward — round 3: everything matmul on bf16 MFMA.
// Canonical layouts: act bf16 pixel-major [b][p][k]; weights bf16 [n][k];
// f32 residual spine channel-major [b][c][p].
// ---------------------------------------------------------------------------

#define NPIX 784
#define CDIM 512
#define NHEAD 8
#define C3 1536

typedef unsigned int uint;
typedef unsigned short ushort;
typedef float f32x4 __attribute__((ext_vector_type(4)));
typedef __bf16 bf16x8 __attribute__((ext_vector_type(8)));

// ---- workspace float offsets ----------------------------------------------
#define OFF_XPM ((size_t)0)          // pm bf16 act 16x784x512 (xa / xn2)
#define OFF_W   ((size_t)3211264)    // all bf16 weights
#define OFF_R2  ((size_t)5324288)    // qkvbf -> catpm/fin -> he
#define OFF_VBF ((size_t)14958080)   // vbf -> x3bf
#define OFF_OBF ((size_t)18169344)   // obf -> g1bf
#define OFF_X2  ((size_t)21380608)   // x2 f32 ch-major
#define OFF_X3  ((size_t)27803136)   // x3 f32 ch-major
#define OFF_PL  ((size_t)34225664)
#define OFF_AD  ((size_t)34233856)
#define OFF_RB  ((size_t)34250240)
#define OFF_US  ((size_t)34250288)
#define OFF_RS  ((size_t)34262832)

// weight sub-offsets (ushort units)
#define WOFF_QKV 0
#define WOFF_PROJ 786432
#define WOFF_G1  1048576
#define WOFF_G2  1114112
#define WOFF_FUS 1310720
#define WOFF_E1  2097152   /* + e*349184, packed [682][512] */
#define WOFF_E2  3144704   /* + e*360448, padded [512][704] */

__device__ __forceinline__ ushort f2bf(float f) {
  unsigned u = __builtin_bit_cast(unsigned, f);
  unsigned r = (u + 0x7fffu + ((u >> 16) & 1u)) >> 16;
  return (ushort)r;
}
__device__ __forceinline__ unsigned pack2bf(float lo, float hi) {
  return (unsigned)f2bf(lo) | ((unsigned)f2bf(hi) << 16);
}
__device__ __forceinline__ float bf2f(ushort u) {
  unsigned x = ((unsigned)u) << 16;
  return __builtin_bit_cast(float, x);
}

// ---------------------------------------------------------------------------
__global__ __launch_bounds__(64) void pool_mean_k(const float* __restrict__ x,
                                                  float* __restrict__ pooled) {
  int c = blockIdx.x, b = blockIdx.y;
  const float* row = x + ((size_t)b * CDIM + c) * NPIX;
  float s = 0.f;
  for (int i = threadIdx.x; i < NPIX; i += 64) s += row[i];
  #pragma unroll
  for (int off = 32; off; off >>= 1) s += __shfl_down(s, off);
  if (threadIdx.x == 0) pooled[b * CDIM + c] = s * (1.f / NPIX);
}

// ---------------------------------------------------------------------------
__global__ __launch_bounds__(256) void adapt_mlp_k(const float* __restrict__ pooled,
                                                   const float* __restrict__ a1w,
                                                   const float* __restrict__ a1b,
                                                   const float* __restrict__ a2w,
                                                   const float* __restrict__ a2b,
                                                   float* __restrict__ ad) {
  int b = blockIdx.x, tid = threadIdx.x;
  __shared__ float pl[CDIM];
  __shared__ float hh[128];
  for (int i = tid; i < CDIM; i += 256) pl[i] = pooled[b * CDIM + i];
  __syncthreads();
  if (tid < 128) {
    const float* w = a1w + (size_t)tid * CDIM;
    float a = a1b[tid];
    for (int k = 0; k < CDIM; ++k) a += w[k] * pl[k];
    hh[tid] = fmaxf(a, 0.f);
  }
  __syncthreads();
  for (int o = tid; o < 1024; o += 256) {
    const float* w = a2w + (size_t)o * 128;
    float a = a2b[o];
    for (int k = 0; k < 128; ++k) a += w[k] * hh[k];
    ad[b * 1024 + o] = a;
  }
}

// ---------------------------------------------------------------------------
// adaptive LN: read f32 ch-major, write bf16 pixel-major [b][p][512].
// STATS: also store per-pixel mean / rstd for the fused dwconv.
template <int STATS>
__global__ __launch_bounds__(256) void ln_pm_k(const float* __restrict__ x,
                                               const float* __restrict__ w,
                                               const float* __restrict__ bias,
                                               const float* __restrict__ ad,
                                               ushort* __restrict__ out,
                                               float* __restrict__ ust,
                                               float* __restrict__ rstp) {
  int b = blockIdx.y;
  int p0 = blockIdx.x * 32;
  int tid = threadIdx.x;
  int px = tid & 31, cg = tid >> 5;
  int p = p0 + px;
  bool valid = p < NPIX;
  const float* xb = x + (size_t)b * CDIM * NPIX;
  float s = 0.f, s2 = 0.f;
  if (valid) {
    for (int c = cg * 64; c < cg * 64 + 64; ++c) {
      float v = xb[(size_t)c * NPIX + p];
      s += v; s2 += v * v;
    }
  }
  __shared__ float rs[8][32], rq[8][32], us[32], vs[32];
  rs[cg][px] = s; rq[cg][px] = s2;
  __syncthreads();
  if (tid < 32) {
    float ts = 0.f, ts2 = 0.f;
    #pragma unroll
    for (int g = 0; g < 8; ++g) { ts += rs[g][tid]; ts2 += rq[g][tid]; }
    float u = ts * (1.f / CDIM);
    float var = ts2 * (1.f / CDIM) - u * u;
    float rv = rsqrtf(var + 1e-6f);
    us[tid] = u; vs[tid] = rv;
    if (STATS && p0 + tid < NPIX) {
      ust[(size_t)b * NPIX + p0 + tid] = u;
      rstp[(size_t)b * NPIX + p0 + tid] = rv;
    }
  }
  __syncthreads();
  if (valid) {
    float u = us[px], rv = vs[px];
    const float* aw = ad + (size_t)b * 1024;
    const float* ab = aw + CDIM;
    ushort* ob = out + ((size_t)(b * NPIX + p)) * CDIM + cg * 64;
    for (int cb = 0; cb < 64; cb += 8) {
      int c = cg * 64 + cb;
      float vv[8];
      #pragma unroll
      for (int q = 0; q < 8; ++q) {
        float v = xb[(size_t)(c + q) * NPIX + p];
        vv[q] = w[c + q] * (1.f + aw[c + q]) * ((v - u) * rv) + (bias[c + q] + ab[c + q]);
      }
      uint4 o = {pack2bf(vv[0], vv[1]), pack2bf(vv[2], vv[3]),
                 pack2bf(vv[4], vv[5]), pack2bf(vv[6], vv[7])};
      *(uint4*)(ob + cb) = o;
    }
  }
}

// ---------------------------------------------------------------------------
// weight convert fp32 -> bf16 (with optional K padding), 11 segments.
struct CvtDesc {
  const float* s[11];
  ushort* d[11];
  int rows[11], sk[11], dk[11];
};
__global__ __launch_bounds__(256) void cvt_w_k(CvtDesc D) {
  int seg = blockIdx.y;
  int sk = D.sk[seg], dk = D.dk[seg];
  int total = D.rows[seg] * dk;
  const float* s = D.s[seg];
  ushort* d = D.d[seg];
  for (int i = blockIdx.x * 256 + threadIdx.x; i < total; i += gridDim.x * 256) {
    int r = i / dk, cc = i - r * dk;
    d[i] = (cc < sk) ? f2bf(s[(size_t)r * sk + cc]) : (ushort)0;
  }
}

// ---------------------------------------------------------------------------
// Universal MFMA GEMM.  X pm bf16 [b][784][Ks], W bf16 [n][Ks].
// ORIENT 0: out pm bf16 [b][784][Nstore]; EPI 0 none, 1 relu, 2 gelu,
//           3 sigmoid * in-place.
// ORIENT 1: out ch f32 [b][512][784]; out = resid + sc*(acc + bias).
template <int ORIENT, int EPI>
__global__ __launch_bounds__(256) void mgemm_k(const ushort* __restrict__ X,
                                               const ushort* __restrict__ Wt,
                                               const float* __restrict__ bias,
                                               const float* __restrict__ resid,
                                               const float* __restrict__ scales,
                                               void* __restrict__ OutV,
                                               int Ks, int Nreal, int Nstore) {
  const int b = blockIdx.z;
  const int m0 = blockIdx.x * 112;
  const int n0 = blockIdx.y * 128;
  const int t = threadIdx.x;
  const int w = t >> 6, lane = t & 63, c = lane & 15, g = lane >> 4;
  __shared__ ushort Xs[7168];   // [112][64] swizzled
  __shared__ ushort Ws[8192];   // [128][64] swizzled
  f32x4 acc[7][2];
  #pragma unroll
  for (int mi = 0; mi < 7; ++mi)
    #pragma unroll
    for (int ni = 0; ni < 2; ++ni) acc[mi][ni] = (f32x4){0.f, 0.f, 0.f, 0.f};

  const ushort* Xb = X + (size_t)b * NPIX * Ks;
  for (int k0 = 0; k0 < Ks; k0 += 64) {
    for (int i = t; i < 896; i += 256) {
      int m = i >> 3, kg = i & 7;
      uint4 v = *(const uint4*)(Xb + (size_t)(m0 + m) * Ks + k0 + kg * 8);
      *(uint4*)&Xs[m * 64 + ((kg ^ (m & 7)) << 3)] = v;
    }
    for (int i = t; i < 1024; i += 256) {
      int n = i >> 3, kg = i & 7;
      uint4 v = {0u, 0u, 0u, 0u};
      if (n0 + n < Nreal) v = *(const uint4*)(Wt + (size_t)(n0 + n) * Ks + k0 + kg * 8);
      *(uint4*)&Ws[n * 64 + ((kg ^ (n & 7)) << 3)] = v;
    }
    __syncthreads();
    #pragma unroll
    for (int kc = 0; kc < 2; ++kc) {
      bf16x8 xf[7], wf[2];
      #pragma unroll
      for (int mi = 0; mi < 7; ++mi) {
        int m = mi * 16 + c;
        xf[mi] = *(const bf16x8*)&Xs[m * 64 + (((kc * 4 + g) ^ (m & 7)) << 3)];
      }
      #pragma unroll
      for (int ni = 0; ni < 2; ++ni) {
        int n = w * 32 + ni * 16 + c;
        wf[ni] = *(const bf16x8*)&Ws[n * 64 + (((kc * 4 + g) ^ (n & 7)) << 3)];
      }
      #pragma unroll
      for (int mi = 0; mi < 7; ++mi)
        #pragma unroll
        for (int ni = 0; ni < 2; ++ni)
          acc[mi][ni] = (ORIENT == 0)
            ? __builtin_amdgcn_mfma_f32_16x16x32_bf16(wf[ni], xf[mi], acc[mi][ni], 0, 0, 0)
            : __builtin_amdgcn_mfma_f32_16x16x32_bf16(xf[mi], wf[ni], acc[mi][ni], 0, 0, 0);
    }
    __syncthreads();
  }

  if (ORIENT == 0) {
    ushort* Ob = (ushort*)OutV + (size_t)b * NPIX * Nstore;
    const int nbq = n0 + w * 32;
    float bi[2][4];
    #pragma unroll
    for (int ni = 0; ni < 2; ++ni)
      #pragma unroll
      for (int j = 0; j < 4; ++j) {
        int n = nbq + ni * 16 + g * 4 + j;
        bi[ni][j] = (n < Nreal) ? bias[n] : 0.f;
      }
    #pragma unroll
    for (int mi = 0; mi < 7; ++mi) {
      int m = m0 + mi * 16 + c;
      #pragma unroll
      for (int ni = 0; ni < 2; ++ni) {
        int nb = nbq + ni * 16 + g * 4;
        if (nb >= Nstore) continue;
        float v[4];
        #pragma unroll
        for (int j = 0; j < 4; ++j) v[j] = acc[mi][ni][j] + bi[ni][j];
        if (EPI == 1) {
          #pragma unroll
          for (int j = 0; j < 4; ++j) v[j] = fmaxf(v[j], 0.f);
        } else if (EPI == 2) {
          #pragma unroll
          for (int j = 0; j < 4; ++j)
            v[j] = 0.5f * v[j] * (1.f + erff(v[j] * 0.70710678118654752f));
        } else if (EPI == 3) {
          uint2 cm = *(const uint2*)&Ob[(size_t)m * Nstore + nb];
          float cf[4] = {bf2f((ushort)(cm.x & 0xffffu)), bf2f((ushort)(cm.x >> 16)),
                         bf2f((ushort)(cm.y & 0xffffu)), bf2f((ushort)(cm.y >> 16))};
          #pragma unroll
          for (int j = 0; j < 4; ++j)
            v[j] = (1.f / (1.f + __expf(-v[j]))) * cf[j];
        }
        uint2 o = {pack2bf(v[0], v[1]), pack2bf(v[2], v[3])};
        *(uint2*)&Ob[(size_t)m * Nstore + nb] = o;
      }
    }
  } else {
    float* Ob = (float*)OutV + (size_t)b * CDIM * NPIX;
    const float* Rb = resid + (size_t)b * CDIM * NPIX;
    float sc = scales ? scales[b * 3] : 1.f;
    #pragma unroll
    for (int ni = 0; ni < 2; ++ni) {
      int n = n0 + w * 32 + ni * 16 + c;
      float bv = bias[n];
      #pragma unroll
      for (int mi = 0; mi < 7; ++mi) {
        int m = m0 + mi * 16 + g * 4;
        size_t off = (size_t)n * NPIX + m;
        float4 r = *(const float4*)&Rb[off];
        f32x4 a = acc[mi][ni];
        float4 o = {r.x + sc * (a[0] + bv), r.y + sc * (a[1] + bv),
                    r.z + sc * (a[2] + bv), r.w + sc * (a[3] + bv)};
        *(float4*)&Ob[off] = o;
      }
    }
  }
}

// ---------------------------------------------------------------------------
// transpose V out of qkvbf:  [b][p][1024+c] bf16 -> vbf [b][c][784] bf16
__global__ __launch_bounds__(256) void vtr_k(const ushort* __restrict__ qkvbf,
                                             ushort* __restrict__ vbf) {
  const int p0 = blockIdx.x * 64, c0 = blockIdx.y * 64, b = blockIdx.z;
  __shared__ ushort T[64][72];
  for (int idx = threadIdx.x; idx < 512; idx += 256) {
    int pl = idx >> 3, cq = idx & 7;
    int p = p0 + pl;
    uint4 v = {0u, 0u, 0u, 0u};
    if (p < NPIX)
      v = *(const uint4*)(qkvbf + (size_t)(b * NPIX + p) * C3 + 1024 + c0 + cq * 8);
    *(uint4*)&T[pl][cq * 8] = v;
  }
  __syncthreads();
  for (int idx = threadIdx.x; idx < 512; idx += 256) {
    int cl = idx >> 3, pq = idx & 7;
    if (p0 + pq * 8 < NPIX) {
      ushort tmp[8];
      #pragma unroll
      for (int i = 0; i < 8; ++i) tmp[i] = T[pq * 8 + i][cl];
      *(uint4*)(vbf + ((size_t)(b * CDIM + c0 + cl)) * NPIX + p0 + pq * 8) =
          *(const uint4*)&tmp[0];
    }
  }
}

// f32 ch-major -> bf16 pixel-major (x3 -> x3bf)
__global__ __launch_bounds__(256) void tr_cvt_k(const float* __restrict__ src,
                                                ushort* __restrict__ dst) {
  const int p0 = blockIdx.x * 64, c0 = blockIdx.y * 64, b = blockIdx.z;
  __shared__ ushort T[64][72];
  const float* sb = src + (size_t)b * CDIM * NPIX;
  for (int idx = threadIdx.x; idx < 4096; idx += 256) {
    int ci = idx >> 6, pj = idx & 63;
    int p = p0 + pj;
    T[pj][ci] = (p < NPIX) ? f2bf(sb[(size_t)(c0 + ci) * NPIX + p]) : (ushort)0;
  }
  __syncthreads();
  for (int idx = threadIdx.x; idx < 512; idx += 256) {
    int pj = idx >> 3, cq = idx & 7;
    int p = p0 + pj;
    if (p < NPIX) {
      uint4 v = *(const uint4*)&T[pj][cq * 8];
      *(uint4*)(dst + ((size_t)(b * NPIX + p)) * CDIM + c0 + cq * 8) = v;
    }
  }
}

// ---------------------------------------------------------------------------
// MFMA flash attention (swapped QK^T, online softmax, wave-autonomous).
__global__ __launch_bounds__(256) void attn_mfma_k(const ushort* __restrict__ qkvbf,
                                                   const ushort* __restrict__ vbf,
                                                   const float* __restrict__ sp,
                                                   const float* __restrict__ rpb,
                                                   const float* __restrict__ fp,
                                                   ushort* __restrict__ obf) {
  const int qt = blockIdx.x, h = blockIdx.y, b = blockIdx.z;
  const int w = threadIdx.x >> 6, lane = threadIdx.x & 63;
  const int g = lane >> 4, c = lane & 15;
  const int n0 = qt * 64 + w * 16;
  if (n0 + 16 > NPIX) return;
  const int q = n0 + c;

  __shared__ uint BL[4][580];
  uint* bw = BL[w];

  const ushort* qptr = qkvbf + (size_t)(b * NPIX + q) * C3 + h * 64 + g * 8;
  const bf16x8 qf0 = *(const bf16x8*)qptr;
  const bf16x8 qf1 = *(const bf16x8*)(qptr + 32);

  const ushort* kbase = qkvbf + (size_t)b * NPIX * C3 + 512 + h * 64 + g * 8;
  const ushort* vbase = vbf + ((size_t)b * CDIM + h * 64) * NPIX;
  const float* spq = sp + ((size_t)h * NPIX + q) * NPIX;
  const float* fpq = fp + ((size_t)b * NPIX + q) * NPIX;
  const int i1 = q / 28, j1 = q - (q / 28) * 28;

  f32x4 ot0 = {0.f, 0.f, 0.f, 0.f}, ot1 = ot0, ot2 = ot0, ot3 = ot0;
  float M = -1e30f, L = 0.f;

  for (int ms = 0; ms < 25; ++ms) {
    const int m0 = ms * 32;
    const bool full = (ms < 24);

    f32x4 s0 = {0.f, 0.f, 0.f, 0.f}, s1 = s0;
    {
      const ushort* kp = kbase + (size_t)(m0 + c) * C3;
      bf16x8 ka0 = *(const bf16x8*)kp;
      bf16x8 ka1 = *(const bf16x8*)(kp + 32);
      s0 = __builtin_amdgcn_mfma_f32_16x16x32_bf16(ka0, qf0, s0, 0, 0, 0);
      s0 = __builtin_amdgcn_mfma_f32_16x16x32_bf16(ka1, qf1, s0, 0, 0, 0);
      if (full) {
        const ushort* kp1 = kp + (size_t)16 * C3;
        bf16x8 kb0 = *(const bf16x8*)kp1;
        bf16x8 kb1 = *(const bf16x8*)(kp1 + 32);
        s1 = __builtin_amdgcn_mfma_f32_16x16x32_bf16(kb0, qf0, s1, 0, 0, 0);
        s1 = __builtin_amdgcn_mfma_f32_16x16x32_bf16(kb1, qf1, s1, 0, 0, 0);
      }
    }

    float v0[4], v1[4];
    {
      const int mb0 = m0 + g * 4;
      float4 sp4 = *(const float4*)(spq + mb0);
      float4 fp4 = *(const float4*)(fpq + mb0);
      const float spv[4] = {sp4.x, sp4.y, sp4.z, sp4.w};
      const float fpv[4] = {fp4.x, fp4.y, fp4.z, fp4.w};
      #pragma unroll
      for (int j = 0; j < 4; ++j) {
        int m = mb0 + j;
        int i2 = m / 28, j2 = m - i2 * 28;
        float rv = rpb[(size_t)((i1 - i2 + 27) * 55 + (j1 - j2 + 27)) * NHEAD + h];
        v0[j] = (s0[j] * 0.125f + spv[j] + rv) * fpv[j];
      }
    }
    if (full) {
      const int mb1 = m0 + 16 + g * 4;
      float4 sp4 = *(const float4*)(spq + mb1);
      float4 fp4 = *(const float4*)(fpq + mb1);
      const float spv[4] = {sp4.x, sp4.y, sp4.z, sp4.w};
      const float fpv[4] = {fp4.x, fp4.y, fp4.z, fp4.w};
      #pragma unroll
      for (int j = 0; j < 4; ++j) {
        int m = mb1 + j;
        int i2 = m / 28, j2 = m - i2 * 28;
        float rv = rpb[(size_t)((i1 - i2 + 27) * 55 + (j1 - j2 + 27)) * NHEAD + h];
        v1[j] = (s1[j] * 0.125f + spv[j] + rv) * fpv[j];
      }
    }

    float tm = fmaxf(fmaxf(v0[0], v0[1]), fmaxf(v0[2], v0[3]));
    if (full) tm = fmaxf(tm, fmaxf(fmaxf(v1[0], v1[1]), fmaxf(v1[2], v1[3])));
    tm = fmaxf(tm, __shfl_xor(tm, 16));
    tm = fmaxf(tm, __shfl_xor(tm, 32));
    const float nM = fmaxf(M, tm);
    const float fac = __expf(M - nM);
    float p0v[4], p1v[4];
    float ps = 0.f;
    #pragma unroll
    for (int j = 0; j < 4; ++j) { p0v[j] = __expf(v0[j] - nM); ps += p0v[j]; }
    if (full) {
      #pragma unroll
      for (int j = 0; j < 4; ++j) { p1v[j] = __expf(v1[j] - nM); ps += p1v[j]; }
    }
    ps += __shfl_xor(ps, 16);
    ps += __shfl_xor(ps, 32);
    L = L * fac + ps;
    M = nM;
    #pragma unroll
    for (int j = 0; j < 4; ++j) { ot0[j] *= fac; ot1[j] *= fac; ot2[j] *= fac; ot3[j] *= fac; }

    {
      uint2 wlo, whi;
      wlo.x = pack2bf(p0v[0], p0v[1]);
      wlo.y = pack2bf(p0v[2], p0v[3]);
      whi.x = full ? pack2bf(p1v[0], p1v[1]) : 0u;
      whi.y = full ? pack2bf(p1v[2], p1v[3]) : 0u;
      *(uint2*)&bw[lane * 6] = wlo;
      *(uint2*)&bw[lane * 6 + 2] = whi;
    }
    const int f = g >> 1;
    const int slo = 32 * (g & 1) + c;
    uint2 blo = *(const uint2*)&bw[slo * 6 + f * 2];
    uint2 bhi = *(const uint2*)&bw[(slo + 16) * 6 + f * 2];
    uint4 bb;
    bb.x = blo.x; bb.y = blo.y; bb.z = bhi.x; bb.w = bhi.y;
    const bf16x8 pfrag = __builtin_bit_cast(bf16x8, bb);

    {
      const ushort* vp = vbase + (size_t)c * NPIX + m0 + g * 8;
      bf16x8 vf0 = *(const bf16x8*)(vp);
      bf16x8 vf1 = *(const bf16x8*)(vp + (size_t)16 * NPIX);
      bf16x8 vf2 = *(const bf16x8*)(vp + (size_t)32 * NPIX);
      bf16x8 vf3 = *(const bf16x8*)(vp + (size_t)48 * NPIX);
      ot0 = __builtin_amdgcn_mfma_f32_16x16x32_bf16(vf0, pfrag, ot0, 0, 0, 0);
      ot1 = __builtin_amdgcn_mfma_f32_16x16x32_bf16(vf1, pfrag, ot1, 0, 0, 0);
      ot2 = __builtin_amdgcn_mfma_f32_16x16x32_bf16(vf2, pfrag, ot2, 0, 0, 0);
      ot3 = __builtin_amdgcn_mfma_f32_16x16x32_bf16(vf3, pfrag, ot3, 0, 0, 0);
    }
  }

  const float invL = 1.f / L;
  bw[c * 36 + 0 * 8 + g * 2 + 0] = pack2bf(ot0[0] * invL, ot0[1] * invL);
  bw[c * 36 + 0 * 8 + g * 2 + 1] = pack2bf(ot0[2] * invL, ot0[3] * invL);
  bw[c * 36 + 1 * 8 + g * 2 + 0] = pack2bf(ot1[0] * invL, ot1[1] * invL);
  bw[c * 36 + 1 * 8 + g * 2 + 1] = pack2bf(ot1[2] * invL, ot1[3] * invL);
  bw[c * 36 + 2 * 8 + g * 2 + 0] = pack2bf(ot2[0] * invL, ot2[1] * invL);
  bw[c * 36 + 2 * 8 + g * 2 + 1] = pack2bf(ot2[2] * invL, ot2[3] * invL);
  bw[c * 36 + 3 * 8 + g * 2 + 0] = pack2bf(ot3[0] * invL, ot3[1] * invL);
  bw[c * 36 + 3 * 8 + g * 2 + 1] = pack2bf(ot3[2] * invL, ot3[3] * invL);
  {
    int q2 = lane & 15, gg = lane >> 4;
    uint4 lo = *(const uint4*)&bw[q2 * 36 + gg * 8];
    uint4 hi = *(const uint4*)&bw[q2 * 36 + gg * 8 + 4];
    ushort* dst = obf + (size_t)(b * NPIX + n0 + q2) * CDIM + h * 64 + gg * 16;
    *(uint4*)dst = lo;
    *(uint4*)(dst + 8) = hi;
  }
}

// ---------------------------------------------------------------------------
// fused LN2 + depthwise 3x3/5x5/7x7 -> cat pm bf16 [b][p][3*512]
__global__ __launch_bounds__(256) void dwln_k(const float* __restrict__ x2,
    const float* __restrict__ ust, const float* __restrict__ rst,
    const float* __restrict__ ad, const float* __restrict__ n2w,
    const float* __restrict__ n2b,
    const float* __restrict__ ew, const float* __restrict__ eb,
    const float* __restrict__ nw, const float* __restrict__ nb,
    const float* __restrict__ mw, const float* __restrict__ mb,
    ushort* __restrict__ cat) {
  const int cg = blockIdx.x, b = blockIdx.y;
  const int c0 = cg * 16;
  const int t = threadIdx.x;
  __shared__ ushort Sn[16][800];
  __shared__ float uS[NPIX], rS[NPIX];
  __shared__ float Wl[16][83];
  __shared__ float Bl[16][3];
  __shared__ float LWs[16], LBs[16];
  for (int i = t; i < NPIX; i += 256) {
    uS[i] = ust[(size_t)b * NPIX + i];
    rS[i] = rst[(size_t)b * NPIX + i];
  }
  for (int i = t; i < 16 * 83; i += 256) {
    int ci = i / 83, k = i - ci * 83;
    int cc = c0 + ci;
    Wl[ci][k] = (k < 9) ? ew[cc * 9 + k]
              : (k < 34) ? nw[cc * 25 + k - 9] : mw[cc * 49 + k - 34];
  }
  for (int i = t; i < 48; i += 256) {
    int ci = i / 3, kk = i - ci * 3;
    Bl[ci][kk] = (kk == 0 ? eb : kk == 1 ? nb : mb)[c0 + ci];
  }
  if (t < 16) {
    int cc = c0 + t;
    float aw = ad[b * 1024 + cc], ab = ad[b * 1024 + 512 + cc];
    LWs[t] = n2w[cc] * (1.f + aw);
    LBs[t] = n2b[cc] + ab;
  }
  __syncthreads();
  for (int ci = 0; ci < 16; ++ci) {
    float lw = LWs[ci], lb = LBs[ci];
    const float* xp = x2 + ((size_t)(b * CDIM + c0 + ci)) * NPIX;
    for (int p = t; p < NPIX; p += 256)
      Sn[ci][p] = f2bf(lw * (xp[p] - uS[p]) * rS[p] + lb);
  }
  __syncthreads();
  for (int p = t; p < NPIX; p += 256) {
    int y = p / 28, xx = p - y * 28;
    ushort* ob = cat + ((size_t)(b * NPIX + p)) * C3 + c0;
    #pragma unroll
    for (int cv = 0; cv < 3; ++cv) {
      const int R = cv + 1;
      const int wb = (cv == 0) ? 0 : (cv == 1) ? 9 : 34;
      const int Wd = 2 * R + 1;
      float a[16];
      #pragma unroll
      for (int ci = 0; ci < 16; ++ci) a[ci] = Bl[ci][cv];
      for (int dy = -R; dy <= R; ++dy) {
        int yy = y + dy;
        if (yy < 0 || yy >= 28) continue;
        for (int dx = -R; dx <= R; ++dx) {
          int xc = xx + dx;
          if (xc < 0 || xc >= 28) continue;
          int pp = yy * 28 + xc;
          int wk = wb + (dy + R) * Wd + (dx + R);
          #pragma unroll
          for (int ci = 0; ci < 16; ++ci) a[ci] += bf2f(Sn[ci][pp]) * Wl[ci][wk];
        }
      }
      uint4 o0 = {pack2bf(a[0], a[1]), pack2bf(a[2], a[3]),
                  pack2bf(a[4], a[5]), pack2bf(a[6], a[7])};
      uint4 o1 = {pack2bf(a[8], a[9]), pack2bf(a[10], a[11]),
                  pack2bf(a[12], a[13]), pack2bf(a[14], a[15])};
      *(uint4*)(ob + cv * 512) = o0;
      *(uint4*)(ob + cv * 512 + 8) = o1;
    }
  }
}

// ---------------------------------------------------------------------------
__global__ __launch_bounds__(64) void router_k(const float* __restrict__ pooled,
                                               const float* __restrict__ rw,
                                               const float* __restrict__ rb,
                                               float* __restrict__ r) {
  int b = blockIdx.x, lane = threadIdx.x;
  float a0 = 0.f, a1 = 0.f, a2 = 0.f;
  for (int k = lane; k < CDIM; k += 64) {
    float p = pooled[b * CDIM + k];
    a0 += rw[k] * p;
    a1 += rw[CDIM + k] * p;
    a2 += rw[2 * CDIM + k] * p;
  }
  #pragma unroll
  for (int off = 32; off; off >>= 1) {
    a0 += __shfl_down(a0, off);
    a1 += __shfl_down(a1, off);
    a2 += __shfl_down(a2, off);
  }
  if (lane == 0) {
    float l0 = a0 + rb[0], l1 = a1 + rb[1], l2 = a2 + rb[2];
    float mx = fmaxf(l0, fmaxf(l1, l2));
    float e0 = __expf(l0 - mx), e1 = __expf(l1 - mx), e2 = __expf(l2 - mx);
    float inv = 1.f / (e0 + e1 + e2);
    r[b * 3 + 0] = e0 * inv;
    r[b * 3 + 1] = e1 * inv;
    r[b * 3 + 2] = e2 * inv;
  }
}

// ---------------------------------------------------------------------------
extern "C" void kernel_launch(void* const* d_in, const int* in_sizes, int n_in,
                              void* d_out, int out_size, void* d_ws, size_t ws_size,
                              hipStream_t stream) {
  (void)in_sizes; (void)n_in; (void)out_size; (void)ws_size;
  const float* x         = (const float*)d_in[0];
  const float* fpri      = (const float*)d_in[1];
  const float* n1_w      = (const float*)d_in[2];
  const float* n1_b      = (const float*)d_in[3];
  const float* n1_a1w    = (const float*)d_in[4];
  const float* n1_a1b    = (const float*)d_in[5];
  const float* n1_a2w    = (const float*)d_in[6];
  const float* n1_a2b    = (const float*)d_in[7];
  const float* n2_w      = (const float*)d_in[8];
  const float* n2_b      = (const float*)d_in[9];
  const float* n2_a1w    = (const float*)d_in[10];
  const float* n2_a1b    = (const float*)d_in[11];
  const float* n2_a2w    = (const float*)d_in[12];
  const float* n2_a2b    = (const float*)d_in[13];
  const float* qkv_w     = (const float*)d_in[14];
  const float* qkv_b     = (const float*)d_in[15];
  const float* rpb_table = (const float*)d_in[16];
  const float* sprior    = (const float*)d_in[17];
  const float* proj_w    = (const float*)d_in[18];
  const float* proj_b    = (const float*)d_in[19];
  const float* eye_w     = (const float*)d_in[20];
  const float* eye_b     = (const float*)d_in[21];
  const float* nose_w    = (const float*)d_in[22];
  const float* nose_b    = (const float*)d_in[23];
  const float* mouth_w   = (const float*)d_in[24];
  const float* mouth_b   = (const float*)d_in[25];
  const float* fusion_w  = (const float*)d_in[26];
  const float* fusion_b  = (const float*)d_in[27];
  const float* gate1_w   = (const float*)d_in[28];
  const float* gate1_b   = (const float*)d_in[29];
  const float* gate2_w   = (const float*)d_in[30];
  const float* gate2_b   = (const float*)d_in[31];
  const float* e1w[3] = {(const float*)d_in[32], (const float*)d_in[36], (const float*)d_in[40]};
  const float* e1b[3] = {(const float*)d_in[33], (const float*)d_in[37], (const float*)d_in[41]};
  const float* e2w[3] = {(const float*)d_in[34], (const float*)d_in[38], (const float*)d_in[42]};
  const float* e2b[3] = {(const float*)d_in[35], (const float*)d_in[39], (const float*)d_in[43]};
  const float* router_w  = (const float*)d_in[44];
  const float* router_b  = (const float*)d_in[45];

  float* ws    = (float*)d_ws;
  ushort* xpm  = (ushort*)(ws + OFF_XPM);
  ushort* wb   = (ushort*)(ws + OFF_W);
  ushort* r2u  = (ushort*)(ws + OFF_R2);   // qkvbf -> catpm -> he
  ushort* vbf  = (ushort*)(ws + OFF_VBF);  // vbf -> x3bf
  ushort* obf  = (ushort*)(ws + OFF_OBF);  // obf -> g1bf
  float* x2    = ws + OFF_X2;
  float* x3    = ws + OFF_X3;
  float* pld   = ws + OFF_PL;
  float* adb   = ws + OFF_AD;
  float* rbuf  = ws + OFF_RB;
  float* ust   = ws + OFF_US;
  float* rst   = ws + OFF_RS;
  float* outp  = (float*)d_out;

  ushort* qkvw = wb + WOFF_QKV;
  ushort* projw = wb + WOFF_PROJ;
  ushort* g1w  = wb + WOFF_G1;
  ushort* g2w  = wb + WOFF_G2;
  ushort* fusw = wb + WOFF_FUS;

  // --- weight conversion (all fp32 -> bf16, e2 K-padded 682->704) ---
  CvtDesc D;
  D.s[0] = qkv_w;    D.d[0] = qkvw;  D.rows[0] = 1536; D.sk[0] = 512;  D.dk[0] = 512;
  D.s[1] = proj_w;   D.d[1] = projw; D.rows[1] = 512;  D.sk[1] = 512;  D.dk[1] = 512;
  D.s[2] = gate1_w;  D.d[2] = g1w;   D.rows[2] = 128;  D.sk[2] = 512;  D.dk[2] = 512;
  D.s[3] = gate2_w;  D.d[3] = g2w;   D.rows[3] = 1536; D.sk[3] = 128;  D.dk[3] = 128;
  D.s[4] = fusion_w; D.d[4] = fusw;  D.rows[4] = 512;  D.sk[4] = 1536; D.dk[4] = 1536;
  for (int e = 0; e < 3; ++e) {
    D.s[5 + e] = e1w[e]; D.d[5 + e] = wb + WOFF_E1 + e * 349184;
    D.rows[5 + e] = 682; D.sk[5 + e] = 512; D.dk[5 + e] = 512;
    D.s[8 + e] = e2w[e]; D.d[8 + e] = wb + WOFF_E2 + e * 360448;
    D.rows[8 + e] = 512; D.sk[8 + e] = 682; D.dk[8 + e] = 704;
  }
  cvt_w_k<<<dim3(512, 11), 256, 0, stream>>>(D);

  // --- LN1 ---
  pool_mean_k<<<dim3(CDIM, 16), 64, 0, stream>>>(x, pld);
  adapt_mlp_k<<<16, 256, 0, stream>>>(pld, n1_a1w, n1_a1b, n1_a2w, n1_a2b, adb);
  ln_pm_k<0><<<dim3(25, 16), 256, 0, stream>>>(x, n1_w, n1_b, adb, xpm, nullptr, nullptr);

  // --- attention ---
  mgemm_k<0, 0><<<dim3(7, 12, 16), 256, 0, stream>>>(xpm, qkvw, qkv_b, nullptr, nullptr,
                                                     r2u, 512, 1536, 1536);
  vtr_k<<<dim3(13, 8, 16), 256, 0, stream>>>(r2u, vbf);
  attn_mfma_k<<<dim3(13, 8, 16), 256, 0, stream>>>(r2u, vbf, sprior, rpb_table, fpri, obf);
  mgemm_k<1, 4><<<dim3(7, 4, 16), 256, 0, stream>>>(obf, projw, proj_b, x, nullptr,
                                                    x2, 512, 512, 512);

  // --- LN2 + token mixer ---
  pool_mean_k<<<dim3(CDIM, 16), 64, 0, stream>>>(x2, pld);
  adapt_mlp_k<<<16, 256, 0, stream>>>(pld, n2_a1w, n2_a1b, n2_a2w, n2_a2b, adb);
  ln_pm_k<1><<<dim3(25, 16), 256, 0, stream>>>(x2, n2_w, n2_b, adb, xpm, ust, rst);
  dwln_k<<<dim3(32, 16), 256, 0, stream>>>(x2, ust, rst, adb, n2_w, n2_b,
                                           eye_w, eye_b, nose_w, nose_b, mouth_w, mouth_b,
                                           r2u);
  mgemm_k<0, 1><<<dim3(7, 1, 16), 256, 0, stream>>>(xpm, g1w, gate1_b, nullptr, nullptr,
                                                    obf, 512, 128, 128);
  mgemm_k<0, 3><<<dim3(7, 12, 16), 256, 0, stream>>>(obf, g2w, gate2_b, nullptr, nullptr,
                                                     r2u, 128, 1536, 1536);
  mgemm_k<1, 4><<<dim3(7, 4, 16), 256, 0, stream>>>(r2u, fusw, fusion_b, x2, nullptr,
                                                    x3, 1536, 512, 512);

  // --- MoE ---
  tr_cvt_k<<<dim3(13, 8, 16), 256, 0, stream>>>(x3, vbf);
  pool_mean_k<<<dim3(CDIM, 16), 64, 0, stream>>>(x3, pld);
  router_k<<<16, 64, 0, stream>>>(pld, router_w, router_b, rbuf);
  for (int e = 0; e < 3; ++e) {
    mgemm_k<0, 2><<<dim3(7, 6, 16), 256, 0, stream>>>(vbf, wb + WOFF_E1 + e * 349184,
                                                      e1b[e], nullptr, nullptr,
                                                      r2u, 512, 682, 704);
    mgemm_k<1, 4><<<dim3(7, 4, 16), 256, 0, stream>>>(r2u, wb + WOFF_E2 + e * 360448,
                                                      e2b[e], (e == 0) ? x3 : outp,
                                                      rbuf + e, outp, 704, 512, 512);
  }
}

// Round 4
// 1101.634 us; speedup vs baseline: 2.6876x; 1.1319x over previous
//
#include <hip/hip_runtime.h>
#include <math.h>

// ---------------------------------------------------------------------------
// EfficientFaceTransformer forward — round 4: attention latency fixes.
// bf16 pre-folded biases (sp+rpb, fp), 32 q-rows per wave (2 chunks, shared
// K/V fragments), direct epilogue stores.
// ---------------------------------------------------------------------------

#define NPIX 784
#define CDIM 512
#define NHEAD 8
#define C3 1536

typedef unsigned int uint;
typedef unsigned short ushort;
typedef float f32x4 __attribute__((ext_vector_type(4)));
typedef __bf16 bf16x8 __attribute__((ext_vector_type(8)));

// ---- workspace float offsets ----------------------------------------------
#define OFF_XPM ((size_t)0)          // pm bf16 act 16x784x512 (xa / xn2)
#define OFF_W   ((size_t)3211264)    // all bf16 weights
#define OFF_R2  ((size_t)5324288)    // qkvbf -> catpm/fin -> he
#define OFF_VBF ((size_t)14958080)   // vbf -> x3bf
#define OFF_OBF ((size_t)18169344)   // obf -> g1bf
#define OFF_X2  ((size_t)21380608)   // fp_bf (attn) -> x2 f32 ch-major
#define OFF_X3  ((size_t)27803136)   // sprpb_bf (attn) -> x3 f32 ch-major
#define OFF_PL  ((size_t)34225664)
#define OFF_AD  ((size_t)34233856)
#define OFF_RB  ((size_t)34250240)
#define OFF_US  ((size_t)34250288)
#define OFF_RS  ((size_t)34262832)

// weight sub-offsets (ushort units)
#define WOFF_QKV 0
#define WOFF_PROJ 786432
#define WOFF_G1  1048576
#define WOFF_G2  1114112
#define WOFF_FUS 1310720
#define WOFF_E1  2097152   /* + e*349184, packed [682][512] */
#define WOFF_E2  3144704   /* + e*360448, padded [512][704] */

__device__ __forceinline__ ushort f2bf(float f) {
  unsigned u = __builtin_bit_cast(unsigned, f);
  unsigned r = (u + 0x7fffu + ((u >> 16) & 1u)) >> 16;
  return (ushort)r;
}
__device__ __forceinline__ unsigned pack2bf(float lo, float hi) {
  return (unsigned)f2bf(lo) | ((unsigned)f2bf(hi) << 16);
}
__device__ __forceinline__ float bf2f(ushort u) {
  unsigned x = ((unsigned)u) << 16;
  return __builtin_bit_cast(float, x);
}
__device__ __forceinline__ void unpack4bf(uint2 v, float* o) {
  o[0] = bf2f((ushort)(v.x & 0xffffu)); o[1] = bf2f((ushort)(v.x >> 16));
  o[2] = bf2f((ushort)(v.y & 0xffffu)); o[3] = bf2f((ushort)(v.y >> 16));
}

// ---------------------------------------------------------------------------
__global__ __launch_bounds__(64) void pool_mean_k(const float* __restrict__ x,
                                                  float* __restrict__ pooled) {
  int c = blockIdx.x, b = blockIdx.y;
  const float* row = x + ((size_t)b * CDIM + c) * NPIX;
  float s = 0.f;
  for (int i = threadIdx.x; i < NPIX; i += 64) s += row[i];
  #pragma unroll
  for (int off = 32; off; off >>= 1) s += __shfl_down(s, off);
  if (threadIdx.x == 0) pooled[b * CDIM + c] = s * (1.f / NPIX);
}

// ---------------------------------------------------------------------------
__global__ __launch_bounds__(256) void adapt_mlp_k(const float* __restrict__ pooled,
                                                   const float* __restrict__ a1w,
                                                   const float* __restrict__ a1b,
                                                   const float* __restrict__ a2w,
                                                   const float* __restrict__ a2b,
                                                   float* __restrict__ ad) {
  int b = blockIdx.x, tid = threadIdx.x;
  __shared__ float pl[CDIM];
  __shared__ float hh[128];
  for (int i = tid; i < CDIM; i += 256) pl[i] = pooled[b * CDIM + i];
  __syncthreads();
  if (tid < 128) {
    const float* w = a1w + (size_t)tid * CDIM;
    float a = a1b[tid];
    for (int k = 0; k < CDIM; ++k) a += w[k] * pl[k];
    hh[tid] = fmaxf(a, 0.f);
  }
  __syncthreads();
  for (int o = tid; o < 1024; o += 256) {
    const float* w = a2w + (size_t)o * 128;
    float a = a2b[o];
    for (int k = 0; k < 128; ++k) a += w[k] * hh[k];
    ad[b * 1024 + o] = a;
  }
}

// ---------------------------------------------------------------------------
// adaptive LN: read f32 ch-major, write bf16 pixel-major [b][p][512].
template <int STATS>
__global__ __launch_bounds__(256) void ln_pm_k(const float* __restrict__ x,
                                               const float* __restrict__ w,
                                               const float* __restrict__ bias,
                                               const float* __restrict__ ad,
                                               ushort* __restrict__ out,
                                               float* __restrict__ ust,
                                               float* __restrict__ rstp) {
  int b = blockIdx.y;
  int p0 = blockIdx.x * 32;
  int tid = threadIdx.x;
  int px = tid & 31, cg = tid >> 5;
  int p = p0 + px;
  bool valid = p < NPIX;
  const float* xb = x + (size_t)b * CDIM * NPIX;
  float s = 0.f, s2 = 0.f;
  if (valid) {
    for (int c = cg * 64; c < cg * 64 + 64; ++c) {
      float v = xb[(size_t)c * NPIX + p];
      s += v; s2 += v * v;
    }
  }
  __shared__ float rs[8][32], rq[8][32], us[32], vs[32];
  rs[cg][px] = s; rq[cg][px] = s2;
  __syncthreads();
  if (tid < 32) {
    float ts = 0.f, ts2 = 0.f;
    #pragma unroll
    for (int g = 0; g < 8; ++g) { ts += rs[g][tid]; ts2 += rq[g][tid]; }
    float u = ts * (1.f / CDIM);
    float var = ts2 * (1.f / CDIM) - u * u;
    float rv = rsqrtf(var + 1e-6f);
    us[tid] = u; vs[tid] = rv;
    if (STATS && p0 + tid < NPIX) {
      ust[(size_t)b * NPIX + p0 + tid] = u;
      rstp[(size_t)b * NPIX + p0 + tid] = rv;
    }
  }
  __syncthreads();
  if (valid) {
    float u = us[px], rv = vs[px];
    const float* aw = ad + (size_t)b * 1024;
    const float* ab = aw + CDIM;
    ushort* ob = out + ((size_t)(b * NPIX + p)) * CDIM + cg * 64;
    for (int cb = 0; cb < 64; cb += 8) {
      int c = cg * 64 + cb;
      float vv[8];
      #pragma unroll
      for (int q = 0; q < 8; ++q) {
        float v = xb[(size_t)(c + q) * NPIX + p];
        vv[q] = w[c + q] * (1.f + aw[c + q]) * ((v - u) * rv) + (bias[c + q] + ab[c + q]);
      }
      uint4 o = {pack2bf(vv[0], vv[1]), pack2bf(vv[2], vv[3]),
                 pack2bf(vv[4], vv[5]), pack2bf(vv[6], vv[7])};
      *(uint4*)(ob + cb) = o;
    }
  }
}

// ---------------------------------------------------------------------------
// weight convert fp32 -> bf16 (with optional K padding), 11 segments.
struct CvtDesc {
  const float* s[11];
  ushort* d[11];
  int rows[11], sk[11], dk[11];
};
__global__ __launch_bounds__(256) void cvt_w_k(CvtDesc D) {
  int seg = blockIdx.y;
  int sk = D.sk[seg], dk = D.dk[seg];
  int total = D.rows[seg] * dk;
  const float* s = D.s[seg];
  ushort* d = D.d[seg];
  for (int i = blockIdx.x * 256 + threadIdx.x; i < total; i += gridDim.x * 256) {
    int r = i / dk, cc = i - r * dk;
    d[i] = (cc < sk) ? f2bf(s[(size_t)r * sk + cc]) : (ushort)0;
  }
}

// ---------------------------------------------------------------------------
// bias prep: sprpb_bf[h][q][m] = bf16(struct_prior + rpb gather)
__global__ __launch_bounds__(256) void sprpb_k(const float* __restrict__ sp,
                                               const float* __restrict__ rpb,
                                               ushort* __restrict__ out) {
  const int q = blockIdx.x, h = blockIdx.y;
  const int i1 = q / 28, j1 = q - i1 * 28;
  const float* src = sp + ((size_t)h * NPIX + q) * NPIX;
  ushort* dst = out + ((size_t)h * NPIX + q) * NPIX;
  for (int m = threadIdx.x; m < NPIX; m += 256) {
    int i2 = m / 28, j2 = m - i2 * 28;
    float rv = rpb[(size_t)((i1 - i2 + 27) * 55 + (j1 - j2 + 27)) * NHEAD + h];
    dst[m] = f2bf(src[m] + rv);
  }
}

// fp f32 -> bf16 flat cast (16*784*784 / 4 float4s = 2458624, grid 9604)
__global__ __launch_bounds__(256) void fpcvt_k(const float* __restrict__ fp,
                                               ushort* __restrict__ out) {
  size_t i = (size_t)blockIdx.x * 256 + threadIdx.x;
  float4 v = *((const float4*)fp + i);
  ushort4 o;
  o.x = f2bf(v.x); o.y = f2bf(v.y); o.z = f2bf(v.z); o.w = f2bf(v.w);
  *((ushort4*)out + i) = o;
}

// ---------------------------------------------------------------------------
// Universal MFMA GEMM (unchanged).
template <int ORIENT, int EPI>
__global__ __launch_bounds__(256) void mgemm_k(const ushort* __restrict__ X,
                                               const ushort* __restrict__ Wt,
                                               const float* __restrict__ bias,
                                               const float* __restrict__ resid,
                                               const float* __restrict__ scales,
                                               void* __restrict__ OutV,
                                               int Ks, int Nreal, int Nstore) {
  const int b = blockIdx.z;
  const int m0 = blockIdx.x * 112;
  const int n0 = blockIdx.y * 128;
  const int t = threadIdx.x;
  const int w = t >> 6, lane = t & 63, c = lane & 15, g = lane >> 4;
  __shared__ ushort Xs[7168];
  __shared__ ushort Ws[8192];
  f32x4 acc[7][2];
  #pragma unroll
  for (int mi = 0; mi < 7; ++mi)
    #pragma unroll
    for (int ni = 0; ni < 2; ++ni) acc[mi][ni] = (f32x4){0.f, 0.f, 0.f, 0.f};

  const ushort* Xb = X + (size_t)b * NPIX * Ks;
  for (int k0 = 0; k0 < Ks; k0 += 64) {
    for (int i = t; i < 896; i += 256) {
      int m = i >> 3, kg = i & 7;
      uint4 v = *(const uint4*)(Xb + (size_t)(m0 + m) * Ks + k0 + kg * 8);
      *(uint4*)&Xs[m * 64 + ((kg ^ (m & 7)) << 3)] = v;
    }
    for (int i = t; i < 1024; i += 256) {
      int n = i >> 3, kg = i & 7;
      uint4 v = {0u, 0u, 0u, 0u};
      if (n0 + n < Nreal) v = *(const uint4*)(Wt + (size_t)(n0 + n) * Ks + k0 + kg * 8);
      *(uint4*)&Ws[n * 64 + ((kg ^ (n & 7)) << 3)] = v;
    }
    __syncthreads();
    #pragma unroll
    for (int kc = 0; kc < 2; ++kc) {
      bf16x8 xf[7], wf[2];
      #pragma unroll
      for (int mi = 0; mi < 7; ++mi) {
        int m = mi * 16 + c;
        xf[mi] = *(const bf16x8*)&Xs[m * 64 + (((kc * 4 + g) ^ (m & 7)) << 3)];
      }
      #pragma unroll
      for (int ni = 0; ni < 2; ++ni) {
        int n = w * 32 + ni * 16 + c;
        wf[ni] = *(const bf16x8*)&Ws[n * 64 + (((kc * 4 + g) ^ (n & 7)) << 3)];
      }
      #pragma unroll
      for (int mi = 0; mi < 7; ++mi)
        #pragma unroll
        for (int ni = 0; ni < 2; ++ni)
          acc[mi][ni] = (ORIENT == 0)
            ? __builtin_amdgcn_mfma_f32_16x16x32_bf16(wf[ni], xf[mi], acc[mi][ni], 0, 0, 0)
            : __builtin_amdgcn_mfma_f32_16x16x32_bf16(xf[mi], wf[ni], acc[mi][ni], 0, 0, 0);
    }
    __syncthreads();
  }

  if (ORIENT == 0) {
    ushort* Ob = (ushort*)OutV + (size_t)b * NPIX * Nstore;
    const int nbq = n0 + w * 32;
    float bi[2][4];
    #pragma unroll
    for (int ni = 0; ni < 2; ++ni)
      #pragma unroll
      for (int j = 0; j < 4; ++j) {
        int n = nbq + ni * 16 + g * 4 + j;
        bi[ni][j] = (n < Nreal) ? bias[n] : 0.f;
      }
    #pragma unroll
    for (int mi = 0; mi < 7; ++mi) {
      int m = m0 + mi * 16 + c;
      #pragma unroll
      for (int ni = 0; ni < 2; ++ni) {
        int nb = nbq + ni * 16 + g * 4;
        if (nb >= Nstore) continue;
        float v[4];
        #pragma unroll
        for (int j = 0; j < 4; ++j) v[j] = acc[mi][ni][j] + bi[ni][j];
        if (EPI == 1) {
          #pragma unroll
          for (int j = 0; j < 4; ++j) v[j] = fmaxf(v[j], 0.f);
        } else if (EPI == 2) {
          #pragma unroll
          for (int j = 0; j < 4; ++j)
            v[j] = 0.5f * v[j] * (1.f + erff(v[j] * 0.70710678118654752f));
        } else if (EPI == 3) {
          uint2 cm = *(const uint2*)&Ob[(size_t)m * Nstore + nb];
          float cf[4];
          unpack4bf(cm, cf);
          #pragma unroll
          for (int j = 0; j < 4; ++j)
            v[j] = (1.f / (1.f + __expf(-v[j]))) * cf[j];
        }
        uint2 o = {pack2bf(v[0], v[1]), pack2bf(v[2], v[3])};
        *(uint2*)&Ob[(size_t)m * Nstore + nb] = o;
      }
    }
  } else {
    float* Ob = (float*)OutV + (size_t)b * CDIM * NPIX;
    const float* Rb = resid + (size_t)b * CDIM * NPIX;
    float sc = scales ? scales[b * 3] : 1.f;
    #pragma unroll
    for (int ni = 0; ni < 2; ++ni) {
      int n = n0 + w * 32 + ni * 16 + c;
      float bv = bias[n];
      #pragma unroll
      for (int mi = 0; mi < 7; ++mi) {
        int m = m0 + mi * 16 + g * 4;
        size_t off = (size_t)n * NPIX + m;
        float4 r = *(const float4*)&Rb[off];
        f32x4 a = acc[mi][ni];
        float4 o = {r.x + sc * (a[0] + bv), r.y + sc * (a[1] + bv),
                    r.z + sc * (a[2] + bv), r.w + sc * (a[3] + bv)};
        *(float4*)&Ob[off] = o;
      }
    }
  }
}

// ---------------------------------------------------------------------------
// transpose V out of qkvbf:  [b][p][1024+c] bf16 -> vbf [b][c][784] bf16
__global__ __launch_bounds__(256) void vtr_k(const ushort* __restrict__ qkvbf,
                                             ushort* __restrict__ vbf) {
  const int p0 = blockIdx.x * 64, c0 = blockIdx.y * 64, b = blockIdx.z;
  __shared__ ushort T[64][72];
  for (int idx = threadIdx.x; idx < 512; idx += 256) {
    int pl = idx >> 3, cq = idx & 7;
    int p = p0 + pl;
    uint4 v = {0u, 0u, 0u, 0u};
    if (p < NPIX)
      v = *(const uint4*)(qkvbf + (size_t)(b * NPIX + p) * C3 + 1024 + c0 + cq * 8);
    *(uint4*)&T[pl][cq * 8] = v;
  }
  __syncthreads();
  for (int idx = threadIdx.x; idx < 512; idx += 256) {
    int cl = idx >> 3, pq = idx & 7;
    if (p0 + pq * 8 < NPIX) {
      ushort tmp[8];
      #pragma unroll
      for (int i = 0; i < 8; ++i) tmp[i] = T[pq * 8 + i][cl];
      *(uint4*)(vbf + ((size_t)(b * CDIM + c0 + cl)) * NPIX + p0 + pq * 8) =
          *(const uint4*)&tmp[0];
    }
  }
}

// f32 ch-major -> bf16 pixel-major (x3 -> x3bf)
__global__ __launch_bounds__(256) void tr_cvt_k(const float* __restrict__ src,
                                                ushort* __restrict__ dst) {
  const int p0 = blockIdx.x * 64, c0 = blockIdx.y * 64, b = blockIdx.z;
  __shared__ ushort T[64][72];
  const float* sb = src + (size_t)b * CDIM * NPIX;
  for (int idx = threadIdx.x; idx < 4096; idx += 256) {
    int ci = idx >> 6, pj = idx & 63;
    int p = p0 + pj;
    T[pj][ci] = (p < NPIX) ? f2bf(sb[(size_t)(c0 + ci) * NPIX + p]) : (ushort)0;
  }
  __syncthreads();
  for (int idx = threadIdx.x; idx < 512; idx += 256) {
    int pj = idx >> 3, cq = idx & 7;
    int p = p0 + pj;
    if (p < NPIX) {
      uint4 v = *(const uint4*)&T[pj][cq * 8];
      *(uint4*)(dst + ((size_t)(b * NPIX + p)) * CDIM + c0 + cq * 8) = v;
    }
  }
}

// ---------------------------------------------------------------------------
// MFMA flash attention: 32 q rows / wave (2 chunks), shared K/V frags,
// bf16 pre-folded biases, online softmax, wave-autonomous (no barriers).
__global__ __launch_bounds__(256) void attn_mfma_k(const ushort* __restrict__ qkvbf,
                                                   const ushort* __restrict__ vbf,
                                                   const ushort* __restrict__ sprpb,
                                                   const ushort* __restrict__ fpb,
                                                   ushort* __restrict__ obf) {
  const int h = blockIdx.y, b = blockIdx.z;
  const int w = threadIdx.x >> 6, lane = threadIdx.x & 63;
  const int g = lane >> 4, c = lane & 15;
  const int q0 = blockIdx.x * 128 + w * 32;
  if (q0 >= NPIX) return;                       // fully-OOB wave
  const bool hasB = (q0 + 16) < NPIX;           // wave-uniform
  const int qA = q0 + c;
  const int qB = q0 + 16 + c;

  __shared__ uint BL[4][2][384];
  uint* bwA = BL[w][0];
  uint* bwB = BL[w][1];

  // persistent Q fragments
  const ushort* qpA = qkvbf + (size_t)(b * NPIX + qA) * C3 + h * 64 + g * 8;
  const bf16x8 qfA0 = *(const bf16x8*)qpA;
  const bf16x8 qfA1 = *(const bf16x8*)(qpA + 32);
  bf16x8 qfB0, qfB1;
  if (hasB) {
    const ushort* qpB = qkvbf + (size_t)(b * NPIX + qB) * C3 + h * 64 + g * 8;
    qfB0 = *(const bf16x8*)qpB;
    qfB1 = *(const bf16x8*)(qpB + 32);
  }

  const ushort* kbase = qkvbf + (size_t)b * NPIX * C3 + 512 + h * 64 + g * 8;
  const ushort* vbase = vbf + ((size_t)b * CDIM + h * 64) * NPIX;
  const ushort* sprA = sprpb + ((size_t)h * NPIX + qA) * NPIX;
  const ushort* sprB = sprpb + ((size_t)h * NPIX + (hasB ? qB : qA)) * NPIX;
  const ushort* fpA = fpb + ((size_t)b * NPIX + qA) * NPIX;
  const ushort* fpB = fpb + ((size_t)b * NPIX + (hasB ? qB : qA)) * NPIX;

  f32x4 oA0 = {0.f, 0.f, 0.f, 0.f}, oA1 = oA0, oA2 = oA0, oA3 = oA0;
  f32x4 oB0 = oA0, oB1 = oA0, oB2 = oA0, oB3 = oA0;
  float MA = -1e30f, LA = 0.f, MB = -1e30f, LB = 0.f;

  for (int ms = 0; ms < 25; ++ms) {
    const int m0 = ms * 32;
    const bool full = (ms < 24);

    // ---- K fragments (shared by both chunks) ----
    const ushort* kp = kbase + (size_t)(m0 + c) * C3;
    bf16x8 ka0 = *(const bf16x8*)kp;
    bf16x8 ka1 = *(const bf16x8*)(kp + 32);
    bf16x8 kb0, kb1;
    if (full) {
      const ushort* kp1 = kp + (size_t)16 * C3;
      kb0 = *(const bf16x8*)kp1;
      kb1 = *(const bf16x8*)(kp1 + 32);
    }

    // ---- chunk A: S^T, bias, softmax, bounce ----
    f32x4 sA0 = {0.f, 0.f, 0.f, 0.f}, sA1 = sA0;
    sA0 = __builtin_amdgcn_mfma_f32_16x16x32_bf16(ka0, qfA0, sA0, 0, 0, 0);
    sA0 = __builtin_amdgcn_mfma_f32_16x16x32_bf16(ka1, qfA1, sA0, 0, 0, 0);
    if (full) {
      sA1 = __builtin_amdgcn_mfma_f32_16x16x32_bf16(kb0, qfB0 /*dummy avoid*/, sA1, 0, 0, 0);
    }
    // NOTE: the line above must use qfA0/qfA1 — rewritten correctly below.
    if (full) {
      sA1 = (f32x4){0.f, 0.f, 0.f, 0.f};
      sA1 = __builtin_amdgcn_mfma_f32_16x16x32_bf16(kb0, qfA0, sA1, 0, 0, 0);
      sA1 = __builtin_amdgcn_mfma_f32_16x16x32_bf16(kb1, qfA1, sA1, 0, 0, 0);
    }

    float vA0[4], vA1[4];
    {
      float spv[4], fpv[4];
      unpack4bf(*(const uint2*)(sprA + m0 + g * 4), spv);
      unpack4bf(*(const uint2*)(fpA + m0 + g * 4), fpv);
      #pragma unroll
      for (int j = 0; j < 4; ++j) vA0[j] = fmaf(sA0[j], 0.125f, spv[j]) * fpv[j];
      if (full) {
        unpack4bf(*(const uint2*)(sprA + m0 + 16 + g * 4), spv);
        unpack4bf(*(const uint2*)(fpA + m0 + 16 + g * 4), fpv);
        #pragma unroll
        for (int j = 0; j < 4; ++j) vA1[j] = fmaf(sA1[j], 0.125f, spv[j]) * fpv[j];
      }
    }
    {
      float tm = fmaxf(fmaxf(vA0[0], vA0[1]), fmaxf(vA0[2], vA0[3]));
      if (full) tm = fmaxf(tm, fmaxf(fmaxf(vA1[0], vA1[1]), fmaxf(vA1[2], vA1[3])));
      tm = fmaxf(tm, __shfl_xor(tm, 16));
      tm = fmaxf(tm, __shfl_xor(tm, 32));
      const float nM = fmaxf(MA, tm);
      const float fac = __expf(MA - nM);
      float p0v[4], p1v[4];
      float ps = 0.f;
      #pragma unroll
      for (int j = 0; j < 4; ++j) { p0v[j] = __expf(vA0[j] - nM); ps += p0v[j]; }
      if (full) {
        #pragma unroll
        for (int j = 0; j < 4; ++j) { p1v[j] = __expf(vA1[j] - nM); ps += p1v[j]; }
      }
      ps += __shfl_xor(ps, 16);
      ps += __shfl_xor(ps, 32);
      LA = LA * fac + ps;
      MA = nM;
      #pragma unroll
      for (int j = 0; j < 4; ++j) { oA0[j] *= fac; oA1[j] *= fac; oA2[j] *= fac; oA3[j] *= fac; }
      uint2 wlo, whi;
      wlo.x = pack2bf(p0v[0], p0v[1]);
      wlo.y = pack2bf(p0v[2], p0v[3]);
      whi.x = full ? pack2bf(p1v[0], p1v[1]) : 0u;
      whi.y = full ? pack2bf(p1v[2], p1v[3]) : 0u;
      *(uint2*)&bwA[lane * 6] = wlo;
      *(uint2*)&bwA[lane * 6 + 2] = whi;
    }

    // ---- chunk B: S^T, bias, softmax, bounce ----
    if (hasB) {
      f32x4 sB0 = {0.f, 0.f, 0.f, 0.f}, sB1 = sB0;
      sB0 = __builtin_amdgcn_mfma_f32_16x16x32_bf16(ka0, qfB0, sB0, 0, 0, 0);
      sB0 = __builtin_amdgcn_mfma_f32_16x16x32_bf16(ka1, qfB1, sB0, 0, 0, 0);
      if (full) {
        sB1 = __builtin_amdgcn_mfma_f32_16x16x32_bf16(kb0, qfB0, sB1, 0, 0, 0);
        sB1 = __builtin_amdgcn_mfma_f32_16x16x32_bf16(kb1, qfB1, sB1, 0, 0, 0);
      }
      float vB0[4], vB1[4];
      {
        float spv[4], fpv[4];
        unpack4bf(*(const uint2*)(sprB + m0 + g * 4), spv);
        unpack4bf(*(const uint2*)(fpB + m0 + g * 4), fpv);
        #pragma unroll
        for (int j = 0; j < 4; ++j) vB0[j] = fmaf(sB0[j], 0.125f, spv[j]) * fpv[j];
        if (full) {
          unpack4bf(*(const uint2*)(sprB + m0 + 16 + g * 4), spv);
          unpack4bf(*(const uint2*)(fpB + m0 + 16 + g * 4), fpv);
          #pragma unroll
          for (int j = 0; j < 4; ++j) vB1[j] = fmaf(sB1[j], 0.125f, spv[j]) * fpv[j];
        }
      }
      float tm = fmaxf(fmaxf(vB0[0], vB0[1]), fmaxf(vB0[2], vB0[3]));
      if (full) tm = fmaxf(tm, fmaxf(fmaxf(vB1[0], vB1[1]), fmaxf(vB1[2], vB1[3])));
      tm = fmaxf(tm, __shfl_xor(tm, 16));
      tm = fmaxf(tm, __shfl_xor(tm, 32));
      const float nM = fmaxf(MB, tm);
      const float fac = __expf(MB - nM);
      float p0v[4], p1v[4];
      float ps = 0.f;
      #pragma unroll
      for (int j = 0; j < 4; ++j) { p0v[j] = __expf(vB0[j] - nM); ps += p0v[j]; }
      if (full) {
        #pragma unroll
        for (int j = 0; j < 4; ++j) { p1v[j] = __expf(vB1[j] - nM); ps += p1v[j]; }
      }
      ps += __shfl_xor(ps, 16);
      ps += __shfl_xor(ps, 32);
      LB = LB * fac + ps;
      MB = nM;
      #pragma unroll
      for (int j = 0; j < 4; ++j) { oB0[j] *= fac; oB1[j] *= fac; oB2[j] *= fac; oB3[j] *= fac; }
      uint2 wlo, whi;
      wlo.x = pack2bf(p0v[0], p0v[1]);
      wlo.y = pack2bf(p0v[2], p0v[3]);
      whi.x = full ? pack2bf(p1v[0], p1v[1]) : 0u;
      whi.y = full ? pack2bf(p1v[2], p1v[3]) : 0u;
      *(uint2*)&bwB[lane * 6] = wlo;
      *(uint2*)&bwB[lane * 6 + 2] = whi;
    }

    // ---- V fragments (shared) + PV for both chunks ----
    const int f = g >> 1;
    const int slo = 32 * (g & 1) + c;
    uint2 blo = *(const uint2*)&bwA[slo * 6 + f * 2];
    uint2 bhi = *(const uint2*)&bwA[(slo + 16) * 6 + f * 2];
    uint4 bba = {blo.x, blo.y, bhi.x, bhi.y};
    const bf16x8 pfA = __builtin_bit_cast(bf16x8, bba);

    const ushort* vp = vbase + (size_t)c * NPIX + m0 + g * 8;
    bf16x8 vf0 = *(const bf16x8*)(vp);
    bf16x8 vf1 = *(const bf16x8*)(vp + (size_t)16 * NPIX);
    bf16x8 vf2 = *(const bf16x8*)(vp + (size_t)32 * NPIX);
    bf16x8 vf3 = *(const bf16x8*)(vp + (size_t)48 * NPIX);
    oA0 = __builtin_amdgcn_mfma_f32_16x16x32_bf16(vf0, pfA, oA0, 0, 0, 0);
    oA1 = __builtin_amdgcn_mfma_f32_16x16x32_bf16(vf1, pfA, oA1, 0, 0, 0);
    oA2 = __builtin_amdgcn_mfma_f32_16x16x32_bf16(vf2, pfA, oA2, 0, 0, 0);
    oA3 = __builtin_amdgcn_mfma_f32_16x16x32_bf16(vf3, pfA, oA3, 0, 0, 0);
    if (hasB) {
      uint2 clo = *(const uint2*)&bwB[slo * 6 + f * 2];
      uint2 chi = *(const uint2*)&bwB[(slo + 16) * 6 + f * 2];
      uint4 bbb = {clo.x, clo.y, chi.x, chi.y};
      const bf16x8 pfB = __builtin_bit_cast(bf16x8, bbb);
      oB0 = __builtin_amdgcn_mfma_f32_16x16x32_bf16(vf0, pfB, oB0, 0, 0, 0);
      oB1 = __builtin_amdgcn_mfma_f32_16x16x32_bf16(vf1, pfB, oB1, 0, 0, 0);
      oB2 = __builtin_amdgcn_mfma_f32_16x16x32_bf16(vf2, pfB, oB2, 0, 0, 0);
      oB3 = __builtin_amdgcn_mfma_f32_16x16x32_bf16(vf3, pfB, oB3, 0, 0, 0);
    }
  }

  // ---- epilogue: direct stores, [b][p][h*64+d] ----
  {
    const float invL = 1.f / LA;
    ushort* dst = obf + (size_t)(b * NPIX + qA) * CDIM + h * 64 + g * 4;
    f32x4 ot[4] = {oA0, oA1, oA2, oA3};
    #pragma unroll
    for (int t2 = 0; t2 < 4; ++t2) {
      uint2 o = {pack2bf(ot[t2][0] * invL, ot[t2][1] * invL),
                 pack2bf(ot[t2][2] * invL, ot[t2][3] * invL)};
      *(uint2*)(dst + t2 * 16) = o;
    }
  }
  if (hasB) {
    const float invL = 1.f / LB;
    ushort* dst = obf + (size_t)(b * NPIX + qB) * CDIM + h * 64 + g * 4;
    f32x4 ot[4] = {oB0, oB1, oB2, oB3};
    #pragma unroll
    for (int t2 = 0; t2 < 4; ++t2) {
      uint2 o = {pack2bf(ot[t2][0] * invL, ot[t2][1] * invL),
                 pack2bf(ot[t2][2] * invL, ot[t2][3] * invL)};
      *(uint2*)(dst + t2 * 16) = o;
    }
  }
}

// ---------------------------------------------------------------------------
// fused LN2 + depthwise 3x3/5x5/7x7 -> cat pm bf16 [b][p][3*512]
__global__ __launch_bounds__(256) void dwln_k(const float* __restrict__ x2,
    const float* __restrict__ ust, const float* __restrict__ rst,
    const float* __restrict__ ad, const float* __restrict__ n2w,
    const float* __restrict__ n2b,
    const float* __restrict__ ew, const float* __restrict__ eb,
    const float* __restrict__ nw, const float* __restrict__ nb,
    const float* __restrict__ mw, const float* __restrict__ mb,
    ushort* __restrict__ cat) {
  const int cg = blockIdx.x, b = blockIdx.y;
  const int c0 = cg * 16;
  const int t = threadIdx.x;
  __shared__ ushort Sn[16][800];
  __shared__ float uS[NPIX], rS[NPIX];
  __shared__ float Wl[16][83];
  __shared__ float Bl[16][3];
  __shared__ float LWs[16], LBs[16];
  for (int i = t; i < NPIX; i += 256) {
    uS[i] = ust[(size_t)b * NPIX + i];
    rS[i] = rst[(size_t)b * NPIX + i];
  }
  for (int i = t; i < 16 * 83; i += 256) {
    int ci = i / 83, k = i - ci * 83;
    int cc = c0 + ci;
    Wl[ci][k] = (k < 9) ? ew[cc * 9 + k]
              : (k < 34) ? nw[cc * 25 + k - 9] : mw[cc * 49 + k - 34];
  }
  for (int i = t; i < 48; i += 256) {
    int ci = i / 3, kk = i - ci * 3;
    Bl[ci][kk] = (kk == 0 ? eb : kk == 1 ? nb : mb)[c0 + ci];
  }
  if (t < 16) {
    int cc = c0 + t;
    float aw = ad[b * 1024 + cc], ab = ad[b * 1024 + 512 + cc];
    LWs[t] = n2w[cc] * (1.f + aw);
    LBs[t] = n2b[cc] + ab;
  }
  __syncthreads();
  for (int ci = 0; ci < 16; ++ci) {
    float lw = LWs[ci], lb = LBs[ci];
    const float* xp = x2 + ((size_t)(b * CDIM + c0 + ci)) * NPIX;
    for (int p = t; p < NPIX; p += 256)
      Sn[ci][p] = f2bf(lw * (xp[p] - uS[p]) * rS[p] + lb);
  }
  __syncthreads();
  for (int p = t; p < NPIX; p += 256) {
    int y = p / 28, xx = p - y * 28;
    ushort* ob = cat + ((size_t)(b * NPIX + p)) * C3 + c0;
    #pragma unroll
    for (int cv = 0; cv < 3; ++cv) {
      const int R = cv + 1;
      const int wb = (cv == 0) ? 0 : (cv == 1) ? 9 : 34;
      const int Wd = 2 * R + 1;
      float a[16];
      #pragma unroll
      for (int ci = 0; ci < 16; ++ci) a[ci] = Bl[ci][cv];
      for (int dy = -R; dy <= R; ++dy) {
        int yy = y + dy;
        if (yy < 0 || yy >= 28) continue;
        for (int dx = -R; dx <= R; ++dx) {
          int xc = xx + dx;
          if (xc < 0 || xc >= 28) continue;
          int pp = yy * 28 + xc;
          int wk = wb + (dy + R) * Wd + (dx + R);
          #pragma unroll
          for (int ci = 0; ci < 16; ++ci) a[ci] += bf2f(Sn[ci][pp]) * Wl[ci][wk];
        }
      }
      uint4 o0 = {pack2bf(a[0], a[1]), pack2bf(a[2], a[3]),
                  pack2bf(a[4], a[5]), pack2bf(a[6], a[7])};
      uint4 o1 = {pack2bf(a[8], a[9]), pack2bf(a[10], a[11]),
                  pack2bf(a[12], a[13]), pack2bf(a[14], a[15])};
      *(uint4*)(ob + cv * 512) = o0;
      *(uint4*)(ob + cv * 512 + 8) = o1;
    }
  }
}

// ---------------------------------------------------------------------------
__global__ __launch_bounds__(64) void router_k(const float* __restrict__ pooled,
                                               const float* __restrict__ rw,
                                               const float* __restrict__ rb,
                                               float* __restrict__ r) {
  int b = blockIdx.x, lane = threadIdx.x;
  float a0 = 0.f, a1 = 0.f, a2 = 0.f;
  for (int k = lane; k < CDIM; k += 64) {
    float p = pooled[b * CDIM + k];
    a0 += rw[k] * p;
    a1 += rw[CDIM + k] * p;
    a2 += rw[2 * CDIM + k] * p;
  }
  #pragma unroll
  for (int off = 32; off; off >>= 1) {
    a0 += __shfl_down(a0, off);
    a1 += __shfl_down(a1, off);
    a2 += __shfl_down(a2, off);
  }
  if (lane == 0) {
    float l0 = a0 + rb[0], l1 = a1 + rb[1], l2 = a2 + rb[2];
    float mx = fmaxf(l0, fmaxf(l1, l2));
    float e0 = __expf(l0 - mx), e1 = __expf(l1 - mx), e2 = __expf(l2 - mx);
    float inv = 1.f / (e0 + e1 + e2);
    r[b * 3 + 0] = e0 * inv;
    r[b * 3 + 1] = e1 * inv;
    r[b * 3 + 2] = e2 * inv;
  }
}

// ---------------------------------------------------------------------------
extern "C" void kernel_launch(void* const* d_in, const int* in_sizes, int n_in,
                              void* d_out, int out_size, void* d_ws, size_t ws_size,
                              hipStream_t stream) {
  (void)in_sizes; (void)n_in; (void)out_size; (void)ws_size;
  const float* x         = (const float*)d_in[0];
  const float* fpri      = (const float*)d_in[1];
  const float* n1_w      = (const float*)d_in[2];
  const float* n1_b      = (const float*)d_in[3];
  const float* n1_a1w    = (const float*)d_in[4];
  const float* n1_a1b    = (const float*)d_in[5];
  const float* n1_a2w    = (const float*)d_in[6];
  const float* n1_a2b    = (const float*)d_in[7];
  const float* n2_w      = (const float*)d_in[8];
  const float* n2_b      = (const float*)d_in[9];
  const float* n2_a1w    = (const float*)d_in[10];
  const float* n2_a1b    = (const float*)d_in[11];
  const float* n2_a2w    = (const float*)d_in[12];
  const float* n2_a2b    = (const float*)d_in[13];
  const float* qkv_w     = (const float*)d_in[14];
  const float* qkv_b     = (const float*)d_in[15];
  const float* rpb_table = (const float*)d_in[16];
  const float* sprior    = (const float*)d_in[17];
  const float* proj_w    = (const float*)d_in[18];
  const float* proj_b    = (const float*)d_in[19];
  const float* eye_w     = (const float*)d_in[20];
  const float* eye_b     = (const float*)d_in[21];
  const float* nose_w    = (const float*)d_in[22];
  const float* nose_b    = (const float*)d_in[23];
  const float* mouth_w   = (const float*)d_in[24];
  const float* mouth_b   = (const float*)d_in[25];
  const float* fusion_w  = (const float*)d_in[26];
  const float* fusion_b  = (const float*)d_in[27];
  const float* gate1_w   = (const float*)d_in[28];
  const float* gate1_b   = (const float*)d_in[29];
  const float* gate2_w   = (const float*)d_in[30];
  const float* gate2_b   = (const float*)d_in[31];
  const float* e1w[3] = {(const float*)d_in[32], (const float*)d_in[36], (const float*)d_in[40]};
  const float* e1b[3] = {(const float*)d_in[33], (const float*)d_in[37], (const float*)d_in[41]};
  const float* e2w[3] = {(const float*)d_in[34], (const float*)d_in[38], (const float*)d_in[42]};
  const float* e2b[3] = {(const float*)d_in[35], (const float*)d_in[39], (const float*)d_in[43]};
  const float* router_w  = (const float*)d_in[44];
  const float* router_b  = (const float*)d_in[45];

  float* ws    = (float*)d_ws;
  ushort* xpm  = (ushort*)(ws + OFF_XPM);
  ushort* wb   = (ushort*)(ws + OFF_W);
  ushort* r2u  = (ushort*)(ws + OFF_R2);   // qkvbf -> catpm -> he
  ushort* vbf  = (ushort*)(ws + OFF_VBF);  // vbf -> x3bf
  ushort* obf  = (ushort*)(ws + OFF_OBF);  // obf -> g1bf
  float* x2    = ws + OFF_X2;
  float* x3    = ws + OFF_X3;
  float* pld   = ws + OFF_PL;
  float* adb   = ws + OFF_AD;
  float* rbuf  = ws + OFF_RB;
  float* ust   = ws + OFF_US;
  float* rst   = ws + OFF_RS;
  float* outp  = (float*)d_out;

  ushort* qkvw = wb + WOFF_QKV;
  ushort* projw = wb + WOFF_PROJ;
  ushort* g1w  = wb + WOFF_G1;
  ushort* g2w  = wb + WOFF_G2;
  ushort* fusw = wb + WOFF_FUS;

  // attention bias buffers alias the (still-dead) x2/x3 regions
  ushort* fpbf   = (ushort*)x2;   // 19.7 MB <= 25.7 MB; x2 written after attn
  ushort* sprpbf = (ushort*)x3;   // 9.8 MB  <= 25.7 MB; x3 written after attn

  // --- weight conversion (all fp32 -> bf16, e2 K-padded 682->704) ---
  CvtDesc D;
  D.s[0] = qkv_w;    D.d[0] = qkvw;  D.rows[0] = 1536; D.sk[0] = 512;  D.dk[0] = 512;
  D.s[1] = proj_w;   D.d[1] = projw; D.rows[1] = 512;  D.sk[1] = 512;  D.dk[1] = 512;
  D.s[2] = gate1_w;  D.d[2] = g1w;   D.rows[2] = 128;  D.sk[2] = 512;  D.dk[2] = 512;
  D.s[3] = gate2_w;  D.d[3] = g2w;   D.rows[3] = 1536; D.sk[3] = 128;  D.dk[3] = 128;
  D.s[4] = fusion_w; D.d[4] = fusw;  D.rows[4] = 512;  D.sk[4] = 1536; D.dk[4] = 1536;
  for (int e = 0; e < 3; ++e) {
    D.s[5 + e] = e1w[e]; D.d[5 + e] = wb + WOFF_E1 + e * 349184;
    D.rows[5 + e] = 682; D.sk[5 + e] = 512; D.dk[5 + e] = 512;
    D.s[8 + e] = e2w[e]; D.d[8 + e] = wb + WOFF_E2 + e * 360448;
    D.rows[8 + e] = 512; D.sk[8 + e] = 682; D.dk[8 + e] = 704;
  }
  cvt_w_k<<<dim3(512, 11), 256, 0, stream>>>(D);

  // --- attention bias prep ---
  sprpb_k<<<dim3(NPIX, NHEAD), 256, 0, stream>>>(sprior, rpb_table, sprpbf);
  fpcvt_k<<<9604, 256, 0, stream>>>(fpri, fpbf);

  // --- LN1 ---
  pool_mean_k<<<dim3(CDIM, 16), 64, 0, stream>>>(x, pld);
  adapt_mlp_k<<<16, 256, 0, stream>>>(pld, n1_a1w, n1_a1b, n1_a2w, n1_a2b, adb);
  ln_pm_k<0><<<dim3(25, 16), 256, 0, stream>>>(x, n1_w, n1_b, adb, xpm, nullptr, nullptr);

  // --- attention ---
  mgemm_k<0, 0><<<dim3(7, 12, 16), 256, 0, stream>>>(xpm, qkvw, qkv_b, nullptr, nullptr,
                                                     r2u, 512, 1536, 1536);
  vtr_k<<<dim3(13, 8, 16), 256, 0, stream>>>(r2u, vbf);
  attn_mfma_k<<<dim3(7, 8, 16), 256, 0, stream>>>(r2u, vbf, sprpbf, fpbf, obf);
  mgemm_k<1, 4><<<dim3(7, 4, 16), 256, 0, stream>>>(obf, projw, proj_b, x, nullptr,
                                                    x2, 512, 512, 512);

  // --- LN2 + token mixer ---
  pool_mean_k<<<dim3(CDIM, 16), 64, 0, stream>>>(x2, pld);
  adapt_mlp_k<<<16, 256, 0, stream>>>(pld, n2_a1w, n2_a1b, n2_a2w, n2_a2b, adb);
  ln_pm_k<1><<<dim3(25, 16), 256, 0, stream>>>(x2, n2_w, n2_b, adb, xpm, ust, rst);
  dwln_k<<<dim3(32, 16), 256, 0, stream>>>(x2, ust, rst, adb, n2_w, n2_b,
                                           eye_w, eye_b, nose_w, nose_b, mouth_w, mouth_b,
                                           r2u);
  mgemm_k<0, 1><<<dim3(7, 1, 16), 256, 0, stream>>>(xpm, g1w, gate1_b, nullptr, nullptr,
                                                    obf, 512, 128, 128);
  mgemm_k<0, 3><<<dim3(7, 12, 16), 256, 0, stream>>>(obf, g2w, gate2_b, nullptr, nullptr,
                                                     r2u, 128, 1536, 1536);
  mgemm_k<1, 4><<<dim3(7, 4, 16), 256, 0, stream>>>(r2u, fusw, fusion_b, x2, nullptr,
                                                    x3, 1536, 512, 512);

  // --- MoE ---
  tr_cvt_k<<<dim3(13, 8, 16), 256, 0, stream>>>(x3, vbf);
  pool_mean_k<<<dim3(CDIM, 16), 64, 0, stream>>>(x3, pld);
  router_k<<<16, 64, 0, stream>>>(pld, router_w, router_b, rbuf);
  for (int e = 0; e < 3; ++e) {
    mgemm_k<0, 2><<<dim3(7, 6, 16), 256, 0, stream>>>(vbf, wb + WOFF_E1 + e * 349184,
                                                      e1b[e], nullptr, nullptr,
                                                      r2u, 512, 682, 704);
    mgemm_k<1, 4><<<dim3(7, 4, 16), 256, 0, stream>>>(r2u, wb + WOFF_E2 + e * 360448,
                                                      e2b[e], (e == 0) ? x3 : outp,
                                                      rbuf + e, outp, 704, 512, 512);
  }
}

// Round 5
// 902.589 us; speedup vs baseline: 3.2803x; 1.2205x over previous
//
#include <hip/hip_runtime.h>
#include <math.h>

// ---------------------------------------------------------------------------
// EfficientFaceTransformer forward — round 5: sliding-window dwconv rewrite.
// ---------------------------------------------------------------------------

#define NPIX 784
#define CDIM 512
#define NHEAD 8
#define C3 1536

typedef unsigned int uint;
typedef unsigned short ushort;
typedef float f32x4 __attribute__((ext_vector_type(4)));
typedef __bf16 bf16x8 __attribute__((ext_vector_type(8)));

// ---- workspace float offsets ----------------------------------------------
#define OFF_XPM ((size_t)0)          // pm bf16 act 16x784x512 (xa / xn2)
#define OFF_W   ((size_t)3211264)    // all bf16 weights
#define OFF_R2  ((size_t)5324288)    // qkvbf -> catpm -> he
#define OFF_VBF ((size_t)14958080)   // vbf -> x3bf
#define OFF_OBF ((size_t)18169344)   // obf -> g1bf
#define OFF_X2  ((size_t)21380608)   // fp_bf (attn) -> x2 f32 ch-major
#define OFF_X3  ((size_t)27803136)   // sprpb_bf (attn) -> x3 f32 ch-major
#define OFF_PL  ((size_t)34225664)
#define OFF_AD  ((size_t)34233856)
#define OFF_RB  ((size_t)34250240)
#define OFF_US  ((size_t)34250288)
#define OFF_RS  ((size_t)34262832)

// weight sub-offsets (ushort units)
#define WOFF_QKV 0
#define WOFF_PROJ 786432
#define WOFF_G1  1048576
#define WOFF_G2  1114112
#define WOFF_FUS 1310720
#define WOFF_E1  2097152   /* + e*349184, packed [682][512] */
#define WOFF_E2  3144704   /* + e*360448, padded [512][704] */

__device__ __forceinline__ ushort f2bf(float f) {
  unsigned u = __builtin_bit_cast(unsigned, f);
  unsigned r = (u + 0x7fffu + ((u >> 16) & 1u)) >> 16;
  return (ushort)r;
}
__device__ __forceinline__ unsigned pack2bf(float lo, float hi) {
  return (unsigned)f2bf(lo) | ((unsigned)f2bf(hi) << 16);
}
__device__ __forceinline__ float bf2f(ushort u) {
  unsigned x = ((unsigned)u) << 16;
  return __builtin_bit_cast(float, x);
}
__device__ __forceinline__ void unpack4bf(uint2 v, float* o) {
  o[0] = bf2f((ushort)(v.x & 0xffffu)); o[1] = bf2f((ushort)(v.x >> 16));
  o[2] = bf2f((ushort)(v.y & 0xffffu)); o[3] = bf2f((ushort)(v.y >> 16));
}

// ---------------------------------------------------------------------------
__global__ __launch_bounds__(64) void pool_mean_k(const float* __restrict__ x,
                                                  float* __restrict__ pooled) {
  int c = blockIdx.x, b = blockIdx.y;
  const float* row = x + ((size_t)b * CDIM + c) * NPIX;
  float s = 0.f;
  for (int i = threadIdx.x; i < NPIX; i += 64) s += row[i];
  #pragma unroll
  for (int off = 32; off; off >>= 1) s += __shfl_down(s, off);
  if (threadIdx.x == 0) pooled[b * CDIM + c] = s * (1.f / NPIX);
}

// ---------------------------------------------------------------------------
__global__ __launch_bounds__(256) void adapt_mlp_k(const float* __restrict__ pooled,
                                                   const float* __restrict__ a1w,
                                                   const float* __restrict__ a1b,
                                                   const float* __restrict__ a2w,
                                                   const float* __restrict__ a2b,
                                                   float* __restrict__ ad) {
  int b = blockIdx.x, tid = threadIdx.x;
  __shared__ float pl[CDIM];
  __shared__ float hh[128];
  for (int i = tid; i < CDIM; i += 256) pl[i] = pooled[b * CDIM + i];
  __syncthreads();
  if (tid < 128) {
    const float* w = a1w + (size_t)tid * CDIM;
    float a = a1b[tid];
    for (int k = 0; k < CDIM; ++k) a += w[k] * pl[k];
    hh[tid] = fmaxf(a, 0.f);
  }
  __syncthreads();
  for (int o = tid; o < 1024; o += 256) {
    const float* w = a2w + (size_t)o * 128;
    float a = a2b[o];
    for (int k = 0; k < 128; ++k) a += w[k] * hh[k];
    ad[b * 1024 + o] = a;
  }
}

// ---------------------------------------------------------------------------
// adaptive LN: read f32 ch-major, write bf16 pixel-major [b][p][512].
template <int STATS>
__global__ __launch_bounds__(256) void ln_pm_k(const float* __restrict__ x,
                                               const float* __restrict__ w,
                                               const float* __restrict__ bias,
                                               const float* __restrict__ ad,
                                               ushort* __restrict__ out,
                                               float* __restrict__ ust,
                                               float* __restrict__ rstp) {
  int b = blockIdx.y;
  int p0 = blockIdx.x * 32;
  int tid = threadIdx.x;
  int px = tid & 31, cg = tid >> 5;
  int p = p0 + px;
  bool valid = p < NPIX;
  const float* xb = x + (size_t)b * CDIM * NPIX;
  float s = 0.f, s2 = 0.f;
  if (valid) {
    for (int c = cg * 64; c < cg * 64 + 64; ++c) {
      float v = xb[(size_t)c * NPIX + p];
      s += v; s2 += v * v;
    }
  }
  __shared__ float rs[8][32], rq[8][32], us[32], vs[32];
  rs[cg][px] = s; rq[cg][px] = s2;
  __syncthreads();
  if (tid < 32) {
    float ts = 0.f, ts2 = 0.f;
    #pragma unroll
    for (int g = 0; g < 8; ++g) { ts += rs[g][tid]; ts2 += rq[g][tid]; }
    float u = ts * (1.f / CDIM);
    float var = ts2 * (1.f / CDIM) - u * u;
    float rv = rsqrtf(var + 1e-6f);
    us[tid] = u; vs[tid] = rv;
    if (STATS && p0 + tid < NPIX) {
      ust[(size_t)b * NPIX + p0 + tid] = u;
      rstp[(size_t)b * NPIX + p0 + tid] = rv;
    }
  }
  __syncthreads();
  if (valid) {
    float u = us[px], rv = vs[px];
    const float* aw = ad + (size_t)b * 1024;
    const float* ab = aw + CDIM;
    ushort* ob = out + ((size_t)(b * NPIX + p)) * CDIM + cg * 64;
    for (int cb = 0; cb < 64; cb += 8) {
      int c = cg * 64 + cb;
      float vv[8];
      #pragma unroll
      for (int q = 0; q < 8; ++q) {
        float v = xb[(size_t)(c + q) * NPIX + p];
        vv[q] = w[c + q] * (1.f + aw[c + q]) * ((v - u) * rv) + (bias[c + q] + ab[c + q]);
      }
      uint4 o = {pack2bf(vv[0], vv[1]), pack2bf(vv[2], vv[3]),
                 pack2bf(vv[4], vv[5]), pack2bf(vv[6], vv[7])};
      *(uint4*)(ob + cb) = o;
    }
  }
}

// ---------------------------------------------------------------------------
// weight convert fp32 -> bf16 (with optional K padding), 11 segments.
struct CvtDesc {
  const float* s[11];
  ushort* d[11];
  int rows[11], sk[11], dk[11];
};
__global__ __launch_bounds__(256) void cvt_w_k(CvtDesc D) {
  int seg = blockIdx.y;
  int sk = D.sk[seg], dk = D.dk[seg];
  int total = D.rows[seg] * dk;
  const float* s = D.s[seg];
  ushort* d = D.d[seg];
  for (int i = blockIdx.x * 256 + threadIdx.x; i < total; i += gridDim.x * 256) {
    int r = i / dk, cc = i - r * dk;
    d[i] = (cc < sk) ? f2bf(s[(size_t)r * sk + cc]) : (ushort)0;
  }
}

// ---------------------------------------------------------------------------
// bias prep: sprpb_bf[h][q][m] = bf16(struct_prior + rpb gather)
__global__ __launch_bounds__(256) void sprpb_k(const float* __restrict__ sp,
                                               const float* __restrict__ rpb,
                                               ushort* __restrict__ out) {
  const int q = blockIdx.x, h = blockIdx.y;
  const int i1 = q / 28, j1 = q - i1 * 28;
  const float* src = sp + ((size_t)h * NPIX + q) * NPIX;
  ushort* dst = out + ((size_t)h * NPIX + q) * NPIX;
  for (int m = threadIdx.x; m < NPIX; m += 256) {
    int i2 = m / 28, j2 = m - i2 * 28;
    float rv = rpb[(size_t)((i1 - i2 + 27) * 55 + (j1 - j2 + 27)) * NHEAD + h];
    dst[m] = f2bf(src[m] + rv);
  }
}

// fp f32 -> bf16 flat cast (16*784*784 / 4 float4s = 2458624, grid 9604)
__global__ __launch_bounds__(256) void fpcvt_k(const float* __restrict__ fp,
                                               ushort* __restrict__ out) {
  size_t i = (size_t)blockIdx.x * 256 + threadIdx.x;
  float4 v = *((const float4*)fp + i);
  ushort4 o;
  o.x = f2bf(v.x); o.y = f2bf(v.y); o.z = f2bf(v.z); o.w = f2bf(v.w);
  *((ushort4*)out + i) = o;
}

// ---------------------------------------------------------------------------
// Universal MFMA GEMM (unchanged).
template <int ORIENT, int EPI>
__global__ __launch_bounds__(256) void mgemm_k(const ushort* __restrict__ X,
                                               const ushort* __restrict__ Wt,
                                               const float* __restrict__ bias,
                                               const float* __restrict__ resid,
                                               const float* __restrict__ scales,
                                               void* __restrict__ OutV,
                                               int Ks, int Nreal, int Nstore) {
  const int b = blockIdx.z;
  const int m0 = blockIdx.x * 112;
  const int n0 = blockIdx.y * 128;
  const int t = threadIdx.x;
  const int w = t >> 6, lane = t & 63, c = lane & 15, g = lane >> 4;
  __shared__ ushort Xs[7168];
  __shared__ ushort Ws[8192];
  f32x4 acc[7][2];
  #pragma unroll
  for (int mi = 0; mi < 7; ++mi)
    #pragma unroll
    for (int ni = 0; ni < 2; ++ni) acc[mi][ni] = (f32x4){0.f, 0.f, 0.f, 0.f};

  const ushort* Xb = X + (size_t)b * NPIX * Ks;
  for (int k0 = 0; k0 < Ks; k0 += 64) {
    for (int i = t; i < 896; i += 256) {
      int m = i >> 3, kg = i & 7;
      uint4 v = *(const uint4*)(Xb + (size_t)(m0 + m) * Ks + k0 + kg * 8);
      *(uint4*)&Xs[m * 64 + ((kg ^ (m & 7)) << 3)] = v;
    }
    for (int i = t; i < 1024; i += 256) {
      int n = i >> 3, kg = i & 7;
      uint4 v = {0u, 0u, 0u, 0u};
      if (n0 + n < Nreal) v = *(const uint4*)(Wt + (size_t)(n0 + n) * Ks + k0 + kg * 8);
      *(uint4*)&Ws[n * 64 + ((kg ^ (n & 7)) << 3)] = v;
    }
    __syncthreads();
    #pragma unroll
    for (int kc = 0; kc < 2; ++kc) {
      bf16x8 xf[7], wf[2];
      #pragma unroll
      for (int mi = 0; mi < 7; ++mi) {
        int m = mi * 16 + c;
        xf[mi] = *(const bf16x8*)&Xs[m * 64 + (((kc * 4 + g) ^ (m & 7)) << 3)];
      }
      #pragma unroll
      for (int ni = 0; ni < 2; ++ni) {
        int n = w * 32 + ni * 16 + c;
        wf[ni] = *(const bf16x8*)&Ws[n * 64 + (((kc * 4 + g) ^ (n & 7)) << 3)];
      }
      #pragma unroll
      for (int mi = 0; mi < 7; ++mi)
        #pragma unroll
        for (int ni = 0; ni < 2; ++ni)
          acc[mi][ni] = (ORIENT == 0)
            ? __builtin_amdgcn_mfma_f32_16x16x32_bf16(wf[ni], xf[mi], acc[mi][ni], 0, 0, 0)
            : __builtin_amdgcn_mfma_f32_16x16x32_bf16(xf[mi], wf[ni], acc[mi][ni], 0, 0, 0);
    }
    __syncthreads();
  }

  if (ORIENT == 0) {
    ushort* Ob = (ushort*)OutV + (size_t)b * NPIX * Nstore;
    const int nbq = n0 + w * 32;
    float bi[2][4];
    #pragma unroll
    for (int ni = 0; ni < 2; ++ni)
      #pragma unroll
      for (int j = 0; j < 4; ++j) {
        int n = nbq + ni * 16 + g * 4 + j;
        bi[ni][j] = (n < Nreal) ? bias[n] : 0.f;
      }
    #pragma unroll
    for (int mi = 0; mi < 7; ++mi) {
      int m = m0 + mi * 16 + c;
      #pragma unroll
      for (int ni = 0; ni < 2; ++ni) {
        int nb = nbq + ni * 16 + g * 4;
        if (nb >= Nstore) continue;
        float v[4];
        #pragma unroll
        for (int j = 0; j < 4; ++j) v[j] = acc[mi][ni][j] + bi[ni][j];
        if (EPI == 1) {
          #pragma unroll
          for (int j = 0; j < 4; ++j) v[j] = fmaxf(v[j], 0.f);
        } else if (EPI == 2) {
          #pragma unroll
          for (int j = 0; j < 4; ++j)
            v[j] = 0.5f * v[j] * (1.f + erff(v[j] * 0.70710678118654752f));
        } else if (EPI == 3) {
          uint2 cm = *(const uint2*)&Ob[(size_t)m * Nstore + nb];
          float cf[4];
          unpack4bf(cm, cf);
          #pragma unroll
          for (int j = 0; j < 4; ++j)
            v[j] = (1.f / (1.f + __expf(-v[j]))) * cf[j];
        }
        uint2 o = {pack2bf(v[0], v[1]), pack2bf(v[2], v[3])};
        *(uint2*)&Ob[(size_t)m * Nstore + nb] = o;
      }
    }
  } else {
    float* Ob = (float*)OutV + (size_t)b * CDIM * NPIX;
    const float* Rb = resid + (size_t)b * CDIM * NPIX;
    float sc = scales ? scales[b * 3] : 1.f;
    #pragma unroll
    for (int ni = 0; ni < 2; ++ni) {
      int n = n0 + w * 32 + ni * 16 + c;
      float bv = bias[n];
      #pragma unroll
      for (int mi = 0; mi < 7; ++mi) {
        int m = m0 + mi * 16 + g * 4;
        size_t off = (size_t)n * NPIX + m;
        float4 r = *(const float4*)&Rb[off];
        f32x4 a = acc[mi][ni];
        float4 o = {r.x + sc * (a[0] + bv), r.y + sc * (a[1] + bv),
                    r.z + sc * (a[2] + bv), r.w + sc * (a[3] + bv)};
        *(float4*)&Ob[off] = o;
      }
    }
  }
}

// ---------------------------------------------------------------------------
// transpose V out of qkvbf:  [b][p][1024+c] bf16 -> vbf [b][c][784] bf16
__global__ __launch_bounds__(256) void vtr_k(const ushort* __restrict__ qkvbf,
                                             ushort* __restrict__ vbf) {
  const int p0 = blockIdx.x * 64, c0 = blockIdx.y * 64, b = blockIdx.z;
  __shared__ ushort T[64][72];
  for (int idx = threadIdx.x; idx < 512; idx += 256) {
    int pl = idx >> 3, cq = idx & 7;
    int p = p0 + pl;
    uint4 v = {0u, 0u, 0u, 0u};
    if (p < NPIX)
      v = *(const uint4*)(qkvbf + (size_t)(b * NPIX + p) * C3 + 1024 + c0 + cq * 8);
    *(uint4*)&T[pl][cq * 8] = v;
  }
  __syncthreads();
  for (int idx = threadIdx.x; idx < 512; idx += 256) {
    int cl = idx >> 3, pq = idx & 7;
    if (p0 + pq * 8 < NPIX) {
      ushort tmp[8];
      #pragma unroll
      for (int i = 0; i < 8; ++i) tmp[i] = T[pq * 8 + i][cl];
      *(uint4*)(vbf + ((size_t)(b * CDIM + c0 + cl)) * NPIX + p0 + pq * 8) =
          *(const uint4*)&tmp[0];
    }
  }
}

// f32 ch-major -> bf16 pixel-major (x3 -> x3bf)
__global__ __launch_bounds__(256) void tr_cvt_k(const float* __restrict__ src,
                                                ushort* __restrict__ dst) {
  const int p0 = blockIdx.x * 64, c0 = blockIdx.y * 64, b = blockIdx.z;
  __shared__ ushort T[64][72];
  const float* sb = src + (size_t)b * CDIM * NPIX;
  for (int idx = threadIdx.x; idx < 4096; idx += 256) {
    int ci = idx >> 6, pj = idx & 63;
    int p = p0 + pj;
    T[pj][ci] = (p < NPIX) ? f2bf(sb[(size_t)(c0 + ci) * NPIX + p]) : (ushort)0;
  }
  __syncthreads();
  for (int idx = threadIdx.x; idx < 512; idx += 256) {
    int pj = idx >> 3, cq = idx & 7;
    int p = p0 + pj;
    if (p < NPIX) {
      uint4 v = *(const uint4*)&T[pj][cq * 8];
      *(uint4*)(dst + ((size_t)(b * NPIX + p)) * CDIM + c0 + cq * 8) = v;
    }
  }
}

// ---------------------------------------------------------------------------
// MFMA flash attention: 32 q rows / wave (2 chunks), shared K/V frags,
// bf16 pre-folded biases, online softmax, wave-autonomous (no barriers).
__global__ __launch_bounds__(256) void attn_mfma_k(const ushort* __restrict__ qkvbf,
                                                   const ushort* __restrict__ vbf,
                                                   const ushort* __restrict__ sprpb,
                                                   const ushort* __restrict__ fpb,
                                                   ushort* __restrict__ obf) {
  const int h = blockIdx.y, b = blockIdx.z;
  const int w = threadIdx.x >> 6, lane = threadIdx.x & 63;
  const int g = lane >> 4, c = lane & 15;
  const int q0 = blockIdx.x * 128 + w * 32;
  if (q0 >= NPIX) return;
  const bool hasB = (q0 + 16) < NPIX;
  const int qA = q0 + c;
  const int qB = q0 + 16 + c;

  __shared__ uint BL[4][2][384];
  uint* bwA = BL[w][0];
  uint* bwB = BL[w][1];

  const ushort* qpA = qkvbf + (size_t)(b * NPIX + qA) * C3 + h * 64 + g * 8;
  const bf16x8 qfA0 = *(const bf16x8*)qpA;
  const bf16x8 qfA1 = *(const bf16x8*)(qpA + 32);
  bf16x8 qfB0 = qfA0, qfB1 = qfA1;
  if (hasB) {
    const ushort* qpB = qkvbf + (size_t)(b * NPIX + qB) * C3 + h * 64 + g * 8;
    qfB0 = *(const bf16x8*)qpB;
    qfB1 = *(const bf16x8*)(qpB + 32);
  }

  const ushort* kbase = qkvbf + (size_t)b * NPIX * C3 + 512 + h * 64 + g * 8;
  const ushort* vbase = vbf + ((size_t)b * CDIM + h * 64) * NPIX;
  const ushort* sprA = sprpb + ((size_t)h * NPIX + qA) * NPIX;
  const ushort* sprB = sprpb + ((size_t)h * NPIX + (hasB ? qB : qA)) * NPIX;
  const ushort* fpA = fpb + ((size_t)b * NPIX + qA) * NPIX;
  const ushort* fpB = fpb + ((size_t)b * NPIX + (hasB ? qB : qA)) * NPIX;

  f32x4 oA0 = {0.f, 0.f, 0.f, 0.f}, oA1 = oA0, oA2 = oA0, oA3 = oA0;
  f32x4 oB0 = oA0, oB1 = oA0, oB2 = oA0, oB3 = oA0;
  float MA = -1e30f, LA = 0.f, MB = -1e30f, LB = 0.f;

  for (int ms = 0; ms < 25; ++ms) {
    const int m0 = ms * 32;
    const bool full = (ms < 24);

    const ushort* kp = kbase + (size_t)(m0 + c) * C3;
    bf16x8 ka0 = *(const bf16x8*)kp;
    bf16x8 ka1 = *(const bf16x8*)(kp + 32);
    bf16x8 kb0 = ka0, kb1 = ka1;
    if (full) {
      const ushort* kp1 = kp + (size_t)16 * C3;
      kb0 = *(const bf16x8*)kp1;
      kb1 = *(const bf16x8*)(kp1 + 32);
    }

    // ---- chunk A ----
    f32x4 sA0 = {0.f, 0.f, 0.f, 0.f}, sA1 = sA0;
    sA0 = __builtin_amdgcn_mfma_f32_16x16x32_bf16(ka0, qfA0, sA0, 0, 0, 0);
    sA0 = __builtin_amdgcn_mfma_f32_16x16x32_bf16(ka1, qfA1, sA0, 0, 0, 0);
    if (full) {
      sA1 = __builtin_amdgcn_mfma_f32_16x16x32_bf16(kb0, qfA0, sA1, 0, 0, 0);
      sA1 = __builtin_amdgcn_mfma_f32_16x16x32_bf16(kb1, qfA1, sA1, 0, 0, 0);
    }

    float vA0[4], vA1[4];
    {
      float spv[4], fpv[4];
      unpack4bf(*(const uint2*)(sprA + m0 + g * 4), spv);
      unpack4bf(*(const uint2*)(fpA + m0 + g * 4), fpv);
      #pragma unroll
      for (int j = 0; j < 4; ++j) vA0[j] = fmaf(sA0[j], 0.125f, spv[j]) * fpv[j];
      if (full) {
        unpack4bf(*(const uint2*)(sprA + m0 + 16 + g * 4), spv);
        unpack4bf(*(const uint2*)(fpA + m0 + 16 + g * 4), fpv);
        #pragma unroll
        for (int j = 0; j < 4; ++j) vA1[j] = fmaf(sA1[j], 0.125f, spv[j]) * fpv[j];
      }
    }
    {
      float tm = fmaxf(fmaxf(vA0[0], vA0[1]), fmaxf(vA0[2], vA0[3]));
      if (full) tm = fmaxf(tm, fmaxf(fmaxf(vA1[0], vA1[1]), fmaxf(vA1[2], vA1[3])));
      tm = fmaxf(tm, __shfl_xor(tm, 16));
      tm = fmaxf(tm, __shfl_xor(tm, 32));
      const float nM = fmaxf(MA, tm);
      const float fac = __expf(MA - nM);
      float p0v[4], p1v[4];
      float ps = 0.f;
      #pragma unroll
      for (int j = 0; j < 4; ++j) { p0v[j] = __expf(vA0[j] - nM); ps += p0v[j]; }
      if (full) {
        #pragma unroll
        for (int j = 0; j < 4; ++j) { p1v[j] = __expf(vA1[j] - nM); ps += p1v[j]; }
      }
      ps += __shfl_xor(ps, 16);
      ps += __shfl_xor(ps, 32);
      LA = LA * fac + ps;
      MA = nM;
      #pragma unroll
      for (int j = 0; j < 4; ++j) { oA0[j] *= fac; oA1[j] *= fac; oA2[j] *= fac; oA3[j] *= fac; }
      uint2 wlo, whi;
      wlo.x = pack2bf(p0v[0], p0v[1]);
      wlo.y = pack2bf(p0v[2], p0v[3]);
      whi.x = full ? pack2bf(p1v[0], p1v[1]) : 0u;
      whi.y = full ? pack2bf(p1v[2], p1v[3]) : 0u;
      *(uint2*)&bwA[lane * 6] = wlo;
      *(uint2*)&bwA[lane * 6 + 2] = whi;
    }

    // ---- chunk B ----
    if (hasB) {
      f32x4 sB0 = {0.f, 0.f, 0.f, 0.f}, sB1 = sB0;
      sB0 = __builtin_amdgcn_mfma_f32_16x16x32_bf16(ka0, qfB0, sB0, 0, 0, 0);
      sB0 = __builtin_amdgcn_mfma_f32_16x16x32_bf16(ka1, qfB1, sB0, 0, 0, 0);
      if (full) {
        sB1 = __builtin_amdgcn_mfma_f32_16x16x32_bf16(kb0, qfB0, sB1, 0, 0, 0);
        sB1 = __builtin_amdgcn_mfma_f32_16x16x32_bf16(kb1, qfB1, sB1, 0, 0, 0);
      }
      float vB0[4], vB1[4];
      {
        float spv[4], fpv[4];
        unpack4bf(*(const uint2*)(sprB + m0 + g * 4), spv);
        unpack4bf(*(const uint2*)(fpB + m0 + g * 4), fpv);
        #pragma unroll
        for (int j = 0; j < 4; ++j) vB0[j] = fmaf(sB0[j], 0.125f, spv[j]) * fpv[j];
        if (full) {
          unpack4bf(*(const uint2*)(sprB + m0 + 16 + g * 4), spv);
          unpack4bf(*(const uint2*)(fpB + m0 + 16 + g * 4), fpv);
          #pragma unroll
          for (int j = 0; j < 4; ++j) vB1[j] = fmaf(sB1[j], 0.125f, spv[j]) * fpv[j];
        }
      }
      float tm = fmaxf(fmaxf(vB0[0], vB0[1]), fmaxf(vB0[2], vB0[3]));
      if (full) tm = fmaxf(tm, fmaxf(fmaxf(vB1[0], vB1[1]), fmaxf(vB1[2], vB1[3])));
      tm = fmaxf(tm, __shfl_xor(tm, 16));
      tm = fmaxf(tm, __shfl_xor(tm, 32));
      const float nM = fmaxf(MB, tm);
      const float fac = __expf(MB - nM);
      float p0v[4], p1v[4];
      float ps = 0.f;
      #pragma unroll
      for (int j = 0; j < 4; ++j) { p0v[j] = __expf(vB0[j] - nM); ps += p0v[j]; }
      if (full) {
        #pragma unroll
        for (int j = 0; j < 4; ++j) { p1v[j] = __expf(vB1[j] - nM); ps += p1v[j]; }
      }
      ps += __shfl_xor(ps, 16);
      ps += __shfl_xor(ps, 32);
      LB = LB * fac + ps;
      MB = nM;
      #pragma unroll
      for (int j = 0; j < 4; ++j) { oB0[j] *= fac; oB1[j] *= fac; oB2[j] *= fac; oB3[j] *= fac; }
      uint2 wlo, whi;
      wlo.x = pack2bf(p0v[0], p0v[1]);
      wlo.y = pack2bf(p0v[2], p0v[3]);
      whi.x = full ? pack2bf(p1v[0], p1v[1]) : 0u;
      whi.y = full ? pack2bf(p1v[2], p1v[3]) : 0u;
      *(uint2*)&bwB[lane * 6] = wlo;
      *(uint2*)&bwB[lane * 6 + 2] = whi;
    }

    // ---- V fragments (shared) + PV for both chunks ----
    const int f = g >> 1;
    const int slo = 32 * (g & 1) + c;
    uint2 blo = *(const uint2*)&bwA[slo * 6 + f * 2];
    uint2 bhi = *(const uint2*)&bwA[(slo + 16) * 6 + f * 2];
    uint4 bba = {blo.x, blo.y, bhi.x, bhi.y};
    const bf16x8 pfA = __builtin_bit_cast(bf16x8, bba);

    const ushort* vp = vbase + (size_t)c * NPIX + m0 + g * 8;
    bf16x8 vf0 = *(const bf16x8*)(vp);
    bf16x8 vf1 = *(const bf16x8*)(vp + (size_t)16 * NPIX);
    bf16x8 vf2 = *(const bf16x8*)(vp + (size_t)32 * NPIX);
    bf16x8 vf3 = *(const bf16x8*)(vp + (size_t)48 * NPIX);
    oA0 = __builtin_amdgcn_mfma_f32_16x16x32_bf16(vf0, pfA, oA0, 0, 0, 0);
    oA1 = __builtin_amdgcn_mfma_f32_16x16x32_bf16(vf1, pfA, oA1, 0, 0, 0);
    oA2 = __builtin_amdgcn_mfma_f32_16x16x32_bf16(vf2, pfA, oA2, 0, 0, 0);
    oA3 = __builtin_amdgcn_mfma_f32_16x16x32_bf16(vf3, pfA, oA3, 0, 0, 0);
    if (hasB) {
      uint2 clo = *(const uint2*)&bwB[slo * 6 + f * 2];
      uint2 chi = *(const uint2*)&bwB[(slo + 16) * 6 + f * 2];
      uint4 bbb = {clo.x, clo.y, chi.x, chi.y};
      const bf16x8 pfB = __builtin_bit_cast(bf16x8, bbb);
      oB0 = __builtin_amdgcn_mfma_f32_16x16x32_bf16(vf0, pfB, oB0, 0, 0, 0);
      oB1 = __builtin_amdgcn_mfma_f32_16x16x32_bf16(vf1, pfB, oB1, 0, 0, 0);
      oB2 = __builtin_amdgcn_mfma_f32_16x16x32_bf16(vf2, pfB, oB2, 0, 0, 0);
      oB3 = __builtin_amdgcn_mfma_f32_16x16x32_bf16(vf3, pfB, oB3, 0, 0, 0);
    }
  }

  {
    const float invL = 1.f / LA;
    ushort* dst = obf + (size_t)(b * NPIX + qA) * CDIM + h * 64 + g * 4;
    f32x4 ot[4] = {oA0, oA1, oA2, oA3};
    #pragma unroll
    for (int t2 = 0; t2 < 4; ++t2) {
      uint2 o = {pack2bf(ot[t2][0] * invL, ot[t2][1] * invL),
                 pack2bf(ot[t2][2] * invL, ot[t2][3] * invL)};
      *(uint2*)(dst + t2 * 16) = o;
    }
  }
  if (hasB) {
    const float invL = 1.f / LB;
    ushort* dst = obf + (size_t)(b * NPIX + qB) * CDIM + h * 64 + g * 4;
    f32x4 ot[4] = {oB0, oB1, oB2, oB3};
    #pragma unroll
    for (int t2 = 0; t2 < 4; ++t2) {
      uint2 o = {pack2bf(ot[t2][0] * invL, ot[t2][1] * invL),
                 pack2bf(ot[t2][2] * invL, ot[t2][3] * invL)};
      *(uint2*)(dst + t2 * 16) = o;
    }
  }
}

// ---------------------------------------------------------------------------
// Sliding-window fused LN2 + depthwise conv (3x3/5x5/7x7) -> cat pm bf16.
// Block: 16 channels x whole 28x28 plane. Zero-padded 34x34 halo planes in
// LDS (no boundary branches); per thread: 1 channel x 7 runs of 7 px.
__device__ __forceinline__ float bf2f_s(ushort u) { return bf2f(u); }

template <int R>
__device__ __forceinline__ void conv_pass(const ushort* __restrict__ plane_ci,
                                          const float* __restrict__ wl_ci,
                                          float bv, int slot,
                                          ushort (*__restrict__ outb)[16], int ci) {
  constexpr int K = 2 * R + 1;
  float wreg[K * K];
  #pragma unroll
  for (int i = 0; i < K * K; ++i) wreg[i] = wl_ci[i];
  #pragma unroll
  for (int r7 = 0; r7 < 7; ++r7) {
    const int run = slot + r7 * 16;
    const int y = run >> 2, x0 = (run & 3) * 7;
    float acc[7];
    #pragma unroll
    for (int i = 0; i < 7; ++i) acc[i] = bv;
    #pragma unroll
    for (int dy = 0; dy < K; ++dy) {
      const ushort* rp = plane_ci + (y + 3 - R + dy) * 34 + (x0 + 3 - R);
      float win[7 + 2 * R];
      #pragma unroll
      for (int k = 0; k < 7 + 2 * R; ++k) win[k] = bf2f_s(rp[k]);
      #pragma unroll
      for (int i = 0; i < 7; ++i)
        #pragma unroll
        for (int k = 0; k < K; ++k)
          acc[i] = fmaf(win[i + k], wreg[dy * K + k], acc[i]);
    }
    #pragma unroll
    for (int i = 0; i < 7; ++i) outb[y * 28 + x0 + i][ci] = f2bf(acc[i]);
  }
}

__global__ __launch_bounds__(256) void dwln_k(const float* __restrict__ x2,
    const float* __restrict__ ust, const float* __restrict__ rst,
    const float* __restrict__ ad, const float* __restrict__ n2w,
    const float* __restrict__ n2b,
    const float* __restrict__ ew, const float* __restrict__ eb,
    const float* __restrict__ nw, const float* __restrict__ nb,
    const float* __restrict__ mw, const float* __restrict__ mb,
    ushort* __restrict__ cat) {
  const int cg = blockIdx.x, b = blockIdx.y;
  const int c0 = cg * 16;
  const int t = threadIdx.x;
  const int ci = t & 15, slot = t >> 4;

  __shared__ ushort plane[16][1156];   // 34x34 halo planes, 37.0 KB
  __shared__ ushort outb[784][16];     // 25.1 KB
  __shared__ float Wl[16 * 49];        // 3.1 KB
  __shared__ float LWs[16], LBs[16];

  // zero planes (incl. halo)
  {
    uint* pz = (uint*)&plane[0][0];
    for (int i = t; i < 16 * 1156 / 2; i += 256) pz[i] = 0u;
  }
  if (t < 16) {
    int cc = c0 + t;
    float aw = ad[b * 1024 + cc], ab = ad[b * 1024 + 512 + cc];
    LWs[t] = n2w[cc] * (1.f + aw);
    LBs[t] = n2b[cc] + ab;
  }
  __syncthreads();

  // normalize + fill planes
  {
    float uu[4], rr[4];
    #pragma unroll
    for (int j = 0; j < 4; ++j) {
      int p = t + j * 256;
      if (p < NPIX) {
        uu[j] = ust[(size_t)b * NPIX + p];
        rr[j] = rst[(size_t)b * NPIX + p];
      }
    }
    for (int cc = 0; cc < 16; ++cc) {
      const float* xp = x2 + ((size_t)(b * CDIM + c0 + cc)) * NPIX;
      float lw = LWs[cc], lb = LBs[cc];
      #pragma unroll
      for (int j = 0; j < 4; ++j) {
        int p = t + j * 256;
        if (p < NPIX) {
          int y = p / 28, xx2 = p - y * 28;
          plane[cc][(y + 3) * 34 + xx2 + 3] = f2bf(lw * (xp[p] - uu[j]) * rr[j] + lb);
        }
      }
    }
  }
  __syncthreads();

  // three conv passes
  #pragma unroll 1
  for (int cv = 0; cv < 3; ++cv) {
    const float* gw = (cv == 0) ? ew : (cv == 1) ? nw : mw;
    const float* gb = (cv == 0) ? eb : (cv == 1) ? nb : mb;
    const int K2 = (cv == 0) ? 9 : (cv == 1) ? 25 : 49;
    for (int i = t; i < 16 * K2; i += 256) {
      int cc = i / K2, k = i - cc * K2;
      Wl[cc * K2 + k] = gw[(size_t)(c0 + cc) * K2 + k];
    }
    __syncthreads();
    float bv = gb[c0 + ci];
    if (cv == 0)      conv_pass<1>(&plane[ci][0], &Wl[ci * 9],  bv, slot, outb, ci);
    else if (cv == 1) conv_pass<2>(&plane[ci][0], &Wl[ci * 25], bv, slot, outb, ci);
    else              conv_pass<3>(&plane[ci][0], &Wl[ci * 49], bv, slot, outb, ci);
    __syncthreads();
    // coalesced pm write: cat[b][p][cv*512 + c0 .. +16]
    for (int idx = t; idx < NPIX * 2; idx += 256) {
      int p = idx >> 1, half = idx & 1;
      uint4 v = *(const uint4*)&outb[p][half * 8];
      *(uint4*)(cat + ((size_t)(b * NPIX + p)) * C3 + cv * 512 + c0 + half * 8) = v;
    }
    __syncthreads();
  }
}

// ---------------------------------------------------------------------------
__global__ __launch_bounds__(64) void router_k(const float* __restrict__ pooled,
                                               const float* __restrict__ rw,
                                               const float* __restrict__ rb,
                                               float* __restrict__ r) {
  int b = blockIdx.x, lane = threadIdx.x;
  float a0 = 0.f, a1 = 0.f, a2 = 0.f;
  for (int k = lane; k < CDIM; k += 64) {
    float p = pooled[b * CDIM + k];
    a0 += rw[k] * p;
    a1 += rw[CDIM + k] * p;
    a2 += rw[2 * CDIM + k] * p;
  }
  #pragma unroll
  for (int off = 32; off; off >>= 1) {
    a0 += __shfl_down(a0, off);
    a1 += __shfl_down(a1, off);
    a2 += __shfl_down(a2, off);
  }
  if (lane == 0) {
    float l0 = a0 + rb[0], l1 = a1 + rb[1], l2 = a2 + rb[2];
    float mx = fmaxf(l0, fmaxf(l1, l2));
    float e0 = __expf(l0 - mx), e1 = __expf(l1 - mx), e2 = __expf(l2 - mx);
    float inv = 1.f / (e0 + e1 + e2);
    r[b * 3 + 0] = e0 * inv;
    r[b * 3 + 1] = e1 * inv;
    r[b * 3 + 2] = e2 * inv;
  }
}

// ---------------------------------------------------------------------------
extern "C" void kernel_launch(void* const* d_in, const int* in_sizes, int n_in,
                              void* d_out, int out_size, void* d_ws, size_t ws_size,
                              hipStream_t stream) {
  (void)in_sizes; (void)n_in; (void)out_size; (void)ws_size;
  const float* x         = (const float*)d_in[0];
  const float* fpri      = (const float*)d_in[1];
  const float* n1_w      = (const float*)d_in[2];
  const float* n1_b      = (const float*)d_in[3];
  const float* n1_a1w    = (const float*)d_in[4];
  const float* n1_a1b    = (const float*)d_in[5];
  const float* n1_a2w    = (const float*)d_in[6];
  const float* n1_a2b    = (const float*)d_in[7];
  const float* n2_w      = (const float*)d_in[8];
  const float* n2_b      = (const float*)d_in[9];
  const float* n2_a1w    = (const float*)d_in[10];
  const float* n2_a1b    = (const float*)d_in[11];
  const float* n2_a2w    = (const float*)d_in[12];
  const float* n2_a2b    = (const float*)d_in[13];
  const float* qkv_w     = (const float*)d_in[14];
  const float* qkv_b     = (const float*)d_in[15];
  const float* rpb_table = (const float*)d_in[16];
  const float* sprior    = (const float*)d_in[17];
  const float* proj_w    = (const float*)d_in[18];
  const float* proj_b    = (const float*)d_in[19];
  const float* eye_w     = (const float*)d_in[20];
  const float* eye_b     = (const float*)d_in[21];
  const float* nose_w    = (const float*)d_in[22];
  const float* nose_b    = (const float*)d_in[23];
  const float* mouth_w   = (const float*)d_in[24];
  const float* mouth_b   = (const float*)d_in[25];
  const float* fusion_w  = (const float*)d_in[26];
  const float* fusion_b  = (const float*)d_in[27];
  const float* gate1_w   = (const float*)d_in[28];
  const float* gate1_b   = (const float*)d_in[29];
  const float* gate2_w   = (const float*)d_in[30];
  const float* gate2_b   = (const float*)d_in[31];
  const float* e1w[3] = {(const float*)d_in[32], (const float*)d_in[36], (const float*)d_in[40]};
  const float* e1b[3] = {(const float*)d_in[33], (const float*)d_in[37], (const float*)d_in[41]};
  const float* e2w[3] = {(const float*)d_in[34], (const float*)d_in[38], (const float*)d_in[42]};
  const float* e2b[3] = {(const float*)d_in[35], (const float*)d_in[39], (const float*)d_in[43]};
  const float* router_w  = (const float*)d_in[44];
  const float* router_b  = (const float*)d_in[45];

  float* ws    = (float*)d_ws;
  ushort* xpm  = (ushort*)(ws + OFF_XPM);
  ushort* wb   = (ushort*)(ws + OFF_W);
  ushort* r2u  = (ushort*)(ws + OFF_R2);   // qkvbf -> catpm -> he
  ushort* vbf  = (ushort*)(ws + OFF_VBF);  // vbf -> x3bf
  ushort* obf  = (ushort*)(ws + OFF_OBF);  // obf -> g1bf
  float* x2    = ws + OFF_X2;
  float* x3    = ws + OFF_X3;
  float* pld   = ws + OFF_PL;
  float* adb   = ws + OFF_AD;
  float* rbuf  = ws + OFF_RB;
  float* ust   = ws + OFF_US;
  float* rst   = ws + OFF_RS;
  float* outp  = (float*)d_out;

  ushort* qkvw = wb + WOFF_QKV;
  ushort* projw = wb + WOFF_PROJ;
  ushort* g1w  = wb + WOFF_G1;
  ushort* g2w  = wb + WOFF_G2;
  ushort* fusw = wb + WOFF_FUS;

  // attention bias buffers alias the (still-dead) x2/x3 regions
  ushort* fpbf   = (ushort*)x2;   // 19.7 MB; x2 written after attn
  ushort* sprpbf = (ushort*)x3;   // 9.8 MB; x3 written after attn

  // --- weight conversion (all fp32 -> bf16, e2 K-padded 682->704) ---
  CvtDesc D;
  D.s[0] = qkv_w;    D.d[0] = qkvw;  D.rows[0] = 1536; D.sk[0] = 512;  D.dk[0] = 512;
  D.s[1] = proj_w;   D.d[1] = projw; D.rows[1] = 512;  D.sk[1] = 512;  D.dk[1] = 512;
  D.s[2] = gate1_w;  D.d[2] = g1w;   D.rows[2] = 128;  D.sk[2] = 512;  D.dk[2] = 512;
  D.s[3] = gate2_w;  D.d[3] = g2w;   D.rows[3] = 1536; D.sk[3] = 128;  D.dk[3] = 128;
  D.s[4] = fusion_w; D.d[4] = fusw;  D.rows[4] = 512;  D.sk[4] = 1536; D.dk[4] = 1536;
  for (int e = 0; e < 3; ++e) {
    D.s[5 + e] = e1w[e]; D.d[5 + e] = wb + WOFF_E1 + e * 349184;
    D.rows[5 + e] = 682; D.sk[5 + e] = 512; D.dk[5 + e] = 512;
    D.s[8 + e] = e2w[e]; D.d[8 + e] = wb + WOFF_E2 + e * 360448;
    D.rows[8 + e] = 512; D.sk[8 + e] = 682; D.dk[8 + e] = 704;
  }
  cvt_w_k<<<dim3(512, 11), 256, 0, stream>>>(D);

  // --- attention bias prep ---
  sprpb_k<<<dim3(NPIX, NHEAD), 256, 0, stream>>>(sprior, rpb_table, sprpbf);
  fpcvt_k<<<9604, 256, 0, stream>>>(fpri, fpbf);

  // --- LN1 ---
  pool_mean_k<<<dim3(CDIM, 16), 64, 0, stream>>>(x, pld);
  adapt_mlp_k<<<16, 256, 0, stream>>>(pld, n1_a1w, n1_a1b, n1_a2w, n1_a2b, adb);
  ln_pm_k<0><<<dim3(25, 16), 256, 0, stream>>>(x, n1_w, n1_b, adb, xpm, nullptr, nullptr);

  // --- attention ---
  mgemm_k<0, 0><<<dim3(7, 12, 16), 256, 0, stream>>>(xpm, qkvw, qkv_b, nullptr, nullptr,
                                                     r2u, 512, 1536, 1536);
  vtr_k<<<dim3(13, 8, 16), 256, 0, stream>>>(r2u, vbf);
  attn_mfma_k<<<dim3(7, 8, 16), 256, 0, stream>>>(r2u, vbf, sprpbf, fpbf, obf);
  mgemm_k<1, 4><<<dim3(7, 4, 16), 256, 0, stream>>>(obf, projw, proj_b, x, nullptr,
                                                    x2, 512, 512, 512);

  // --- LN2 + token mixer ---
  pool_mean_k<<<dim3(CDIM, 16), 64, 0, stream>>>(x2, pld);
  adapt_mlp_k<<<16, 256, 0, stream>>>(pld, n2_a1w, n2_a1b, n2_a2w, n2_a2b, adb);
  ln_pm_k<1><<<dim3(25, 16), 256, 0, stream>>>(x2, n2_w, n2_b, adb, xpm, ust, rst);
  dwln_k<<<dim3(32, 16), 256, 0, stream>>>(x2, ust, rst, adb, n2_w, n2_b,
                                           eye_w, eye_b, nose_w, nose_b, mouth_w, mouth_b,
                                           r2u);
  mgemm_k<0, 1><<<dim3(7, 1, 16), 256, 0, stream>>>(xpm, g1w, gate1_b, nullptr, nullptr,
                                                    obf, 512, 128, 128);
  mgemm_k<0, 3><<<dim3(7, 12, 16), 256, 0, stream>>>(obf, g2w, gate2_b, nullptr, nullptr,
                                                     r2u, 128, 1536, 1536);
  mgemm_k<1, 4><<<dim3(7, 4, 16), 256, 0, stream>>>(r2u, fusw, fusion_b, x2, nullptr,
                                                    x3, 1536, 512, 512);

  // --- MoE ---
  tr_cvt_k<<<dim3(13, 8, 16), 256, 0, stream>>>(x3, vbf);
  pool_mean_k<<<dim3(CDIM, 16), 64, 0, stream>>>(x3, pld);
  router_k<<<16, 64, 0, stream>>>(pld, router_w, router_b, rbuf);
  for (int e = 0; e < 3; ++e) {
    mgemm_k<0, 2><<<dim3(7, 6, 16), 256, 0, stream>>>(vbf, wb + WOFF_E1 + e * 349184,
                                                      e1b[e], nullptr, nullptr,
                                                      r2u, 512, 682, 704);
    mgemm_k<1, 4><<<dim3(7, 4, 16), 256, 0, stream>>>(r2u, wb + WOFF_E2 + e * 360448,
                                                      e2b[e], (e == 0) ? x3 : outp,
                                                      rbuf + e, outp, 704, 512, 512);
  }
}

// Round 6
// 862.435 us; speedup vs baseline: 3.4330x; 1.0466x over previous
//
#include <hip/hip_runtime.h>
#include <math.h>

// ---------------------------------------------------------------------------
// EfficientFaceTransformer forward — round 6: XCD-aware scheduling.
// attn: batch-per-XCD placement (K/V + fp L2 reuse).
// mgemm: batch flattened into M (M=12544), per-XCD m-panel x n-tile order.
// ---------------------------------------------------------------------------

#define NPIX 784
#define CDIM 512
#define NHEAD 8
#define C3 1536
#define MTOT 12544   /* 16 * 784 */

typedef unsigned int uint;
typedef unsigned short ushort;
typedef float f32x4 __attribute__((ext_vector_type(4)));
typedef __bf16 bf16x8 __attribute__((ext_vector_type(8)));

// ---- workspace float offsets ----------------------------------------------
#define OFF_XPM ((size_t)0)          // pm bf16 act 16x784x512 (xa / xn2)
#define OFF_W   ((size_t)3211264)    // all bf16 weights
#define OFF_R2  ((size_t)5324288)    // qkvbf -> catpm -> he
#define OFF_VBF ((size_t)14958080)   // vbf -> x3bf
#define OFF_OBF ((size_t)18169344)   // obf -> g1bf
#define OFF_X2  ((size_t)21380608)   // fp_bf (attn) -> x2 f32 ch-major
#define OFF_X3  ((size_t)27803136)   // sprpb_bf (attn) -> x3 f32 ch-major
#define OFF_PL  ((size_t)34225664)
#define OFF_AD  ((size_t)34233856)
#define OFF_RB  ((size_t)34250240)
#define OFF_US  ((size_t)34250288)
#define OFF_RS  ((size_t)34262832)

// weight sub-offsets (ushort units)
#define WOFF_QKV 0
#define WOFF_PROJ 786432
#define WOFF_G1  1048576
#define WOFF_G2  1114112
#define WOFF_FUS 1310720
#define WOFF_E1  2097152   /* + e*349184, packed [682][512] */
#define WOFF_E2  3144704   /* + e*360448, padded [512][704] */

__device__ __forceinline__ ushort f2bf(float f) {
  unsigned u = __builtin_bit_cast(unsigned, f);
  unsigned r = (u + 0x7fffu + ((u >> 16) & 1u)) >> 16;
  return (ushort)r;
}
__device__ __forceinline__ unsigned pack2bf(float lo, float hi) {
  return (unsigned)f2bf(lo) | ((unsigned)f2bf(hi) << 16);
}
__device__ __forceinline__ float bf2f(ushort u) {
  unsigned x = ((unsigned)u) << 16;
  return __builtin_bit_cast(float, x);
}
__device__ __forceinline__ void unpack4bf(uint2 v, float* o) {
  o[0] = bf2f((ushort)(v.x & 0xffffu)); o[1] = bf2f((ushort)(v.x >> 16));
  o[2] = bf2f((ushort)(v.y & 0xffffu)); o[3] = bf2f((ushort)(v.y >> 16));
}

// ---------------------------------------------------------------------------
__global__ __launch_bounds__(64) void pool_mean_k(const float* __restrict__ x,
                                                  float* __restrict__ pooled) {
  int c = blockIdx.x, b = blockIdx.y;
  const float* row = x + ((size_t)b * CDIM + c) * NPIX;
  float s = 0.f;
  for (int i = threadIdx.x; i < NPIX; i += 64) s += row[i];
  #pragma unroll
  for (int off = 32; off; off >>= 1) s += __shfl_down(s, off);
  if (threadIdx.x == 0) pooled[b * CDIM + c] = s * (1.f / NPIX);
}

// ---------------------------------------------------------------------------
__global__ __launch_bounds__(256) void adapt_mlp_k(const float* __restrict__ pooled,
                                                   const float* __restrict__ a1w,
                                                   const float* __restrict__ a1b,
                                                   const float* __restrict__ a2w,
                                                   const float* __restrict__ a2b,
                                                   float* __restrict__ ad) {
  int b = blockIdx.x, tid = threadIdx.x;
  __shared__ float pl[CDIM];
  __shared__ float hh[128];
  for (int i = tid; i < CDIM; i += 256) pl[i] = pooled[b * CDIM + i];
  __syncthreads();
  if (tid < 128) {
    const float* w = a1w + (size_t)tid * CDIM;
    float a = a1b[tid];
    for (int k = 0; k < CDIM; ++k) a += w[k] * pl[k];
    hh[tid] = fmaxf(a, 0.f);
  }
  __syncthreads();
  for (int o = tid; o < 1024; o += 256) {
    const float* w = a2w + (size_t)o * 128;
    float a = a2b[o];
    for (int k = 0; k < 128; ++k) a += w[k] * hh[k];
    ad[b * 1024 + o] = a;
  }
}

// ---------------------------------------------------------------------------
// adaptive LN: read f32 ch-major, write bf16 pixel-major [b][p][512].
template <int STATS>
__global__ __launch_bounds__(256) void ln_pm_k(const float* __restrict__ x,
                                               const float* __restrict__ w,
                                               const float* __restrict__ bias,
                                               const float* __restrict__ ad,
                                               ushort* __restrict__ out,
                                               float* __restrict__ ust,
                                               float* __restrict__ rstp) {
  int b = blockIdx.y;
  int p0 = blockIdx.x * 32;
  int tid = threadIdx.x;
  int px = tid & 31, cg = tid >> 5;
  int p = p0 + px;
  bool valid = p < NPIX;
  const float* xb = x + (size_t)b * CDIM * NPIX;
  float s = 0.f, s2 = 0.f;
  if (valid) {
    for (int c = cg * 64; c < cg * 64 + 64; ++c) {
      float v = xb[(size_t)c * NPIX + p];
      s += v; s2 += v * v;
    }
  }
  __shared__ float rs[8][32], rq[8][32], us[32], vs[32];
  rs[cg][px] = s; rq[cg][px] = s2;
  __syncthreads();
  if (tid < 32) {
    float ts = 0.f, ts2 = 0.f;
    #pragma unroll
    for (int g = 0; g < 8; ++g) { ts += rs[g][tid]; ts2 += rq[g][tid]; }
    float u = ts * (1.f / CDIM);
    float var = ts2 * (1.f / CDIM) - u * u;
    float rv = rsqrtf(var + 1e-6f);
    us[tid] = u; vs[tid] = rv;
    if (STATS && p0 + tid < NPIX) {
      ust[(size_t)b * NPIX + p0 + tid] = u;
      rstp[(size_t)b * NPIX + p0 + tid] = rv;
    }
  }
  __syncthreads();
  if (valid) {
    float u = us[px], rv = vs[px];
    const float* aw = ad + (size_t)b * 1024;
    const float* ab = aw + CDIM;
    ushort* ob = out + ((size_t)(b * NPIX + p)) * CDIM + cg * 64;
    for (int cb = 0; cb < 64; cb += 8) {
      int c = cg * 64 + cb;
      float vv[8];
      #pragma unroll
      for (int q = 0; q < 8; ++q) {
        float v = xb[(size_t)(c + q) * NPIX + p];
        vv[q] = w[c + q] * (1.f + aw[c + q]) * ((v - u) * rv) + (bias[c + q] + ab[c + q]);
      }
      uint4 o = {pack2bf(vv[0], vv[1]), pack2bf(vv[2], vv[3]),
                 pack2bf(vv[4], vv[5]), pack2bf(vv[6], vv[7])};
      *(uint4*)(ob + cb) = o;
    }
  }
}

// ---------------------------------------------------------------------------
// weight convert fp32 -> bf16 (with optional K padding), 11 segments.
struct CvtDesc {
  const float* s[11];
  ushort* d[11];
  int rows[11], sk[11], dk[11];
};
__global__ __launch_bounds__(256) void cvt_w_k(CvtDesc D) {
  int seg = blockIdx.y;
  int sk = D.sk[seg], dk = D.dk[seg];
  int total = D.rows[seg] * dk;
  const float* s = D.s[seg];
  ushort* d = D.d[seg];
  for (int i = blockIdx.x * 256 + threadIdx.x; i < total; i += gridDim.x * 256) {
    int r = i / dk, cc = i - r * dk;
    d[i] = (cc < sk) ? f2bf(s[(size_t)r * sk + cc]) : (ushort)0;
  }
}

// ---------------------------------------------------------------------------
// bias prep: sprpb_bf[h][q][m] = bf16(struct_prior + rpb gather)
__global__ __launch_bounds__(256) void sprpb_k(const float* __restrict__ sp,
                                               const float* __restrict__ rpb,
                                               ushort* __restrict__ out) {
  const int q = blockIdx.x, h = blockIdx.y;
  const int i1 = q / 28, j1 = q - i1 * 28;
  const float* src = sp + ((size_t)h * NPIX + q) * NPIX;
  ushort* dst = out + ((size_t)h * NPIX + q) * NPIX;
  for (int m = threadIdx.x; m < NPIX; m += 256) {
    int i2 = m / 28, j2 = m - i2 * 28;
    float rv = rpb[(size_t)((i1 - i2 + 27) * 55 + (j1 - j2 + 27)) * NHEAD + h];
    dst[m] = f2bf(src[m] + rv);
  }
}

// fp f32 -> bf16 flat cast
__global__ __launch_bounds__(256) void fpcvt_k(const float* __restrict__ fp,
                                               ushort* __restrict__ out) {
  size_t i = (size_t)blockIdx.x * 256 + threadIdx.x;
  float4 v = *((const float4*)fp + i);
  ushort4 o;
  o.x = f2bf(v.x); o.y = f2bf(v.y); o.z = f2bf(v.z); o.w = f2bf(v.w);
  *((ushort4*)out + i) = o;
}

// ---------------------------------------------------------------------------
// Universal MFMA GEMM, batch-flattened M (=12544 rows, pixel-major contiguous).
// 1D grid of 112*NT blocks. XCD-aware: xcd = bid&7 owns 14 m-tiles (2 batches),
// iterates n-tiles m-fastest so each W-tile stays in that XCD's L2.
// ORIENT 0: out pm bf16 [m][Nstore]; EPI 0 none/1 relu/2 gelu/3 sigmoid*inplace
// ORIENT 1: out ch f32 [b][512][784]; out = resid + sc*(acc + bias).
template <int ORIENT, int EPI>
__global__ __launch_bounds__(256) void mgemm_k(const ushort* __restrict__ X,
                                               const ushort* __restrict__ Wt,
                                               const float* __restrict__ bias,
                                               const float* __restrict__ resid,
                                               const float* __restrict__ scales,
                                               void* __restrict__ OutV,
                                               int Ks, int Nreal, int Nstore) {
  const int bid = blockIdx.x;
  const int xcd = bid & 7;
  const int i = bid >> 3;
  const int mt_local = i % 14;
  const int nt = i / 14;
  const int m0 = (xcd * 14 + mt_local) * 112;
  const int n0 = nt * 128;
  const int t = threadIdx.x;
  const int w = t >> 6, lane = t & 63, c = lane & 15, g = lane >> 4;
  __shared__ ushort Xs[7168];
  __shared__ ushort Ws[8192];
  f32x4 acc[7][2];
  #pragma unroll
  for (int mi = 0; mi < 7; ++mi)
    #pragma unroll
    for (int ni = 0; ni < 2; ++ni) acc[mi][ni] = (f32x4){0.f, 0.f, 0.f, 0.f};

  for (int k0 = 0; k0 < Ks; k0 += 64) {
    for (int ii = t; ii < 896; ii += 256) {
      int m = ii >> 3, kg = ii & 7;
      uint4 v = *(const uint4*)(X + (size_t)(m0 + m) * Ks + k0 + kg * 8);
      *(uint4*)&Xs[m * 64 + ((kg ^ (m & 7)) << 3)] = v;
    }
    for (int ii = t; ii < 1024; ii += 256) {
      int n = ii >> 3, kg = ii & 7;
      uint4 v = {0u, 0u, 0u, 0u};
      if (n0 + n < Nreal) v = *(const uint4*)(Wt + (size_t)(n0 + n) * Ks + k0 + kg * 8);
      *(uint4*)&Ws[n * 64 + ((kg ^ (n & 7)) << 3)] = v;
    }
    __syncthreads();
    #pragma unroll
    for (int kc = 0; kc < 2; ++kc) {
      bf16x8 xf[7], wf[2];
      #pragma unroll
      for (int mi = 0; mi < 7; ++mi) {
        int m = mi * 16 + c;
        xf[mi] = *(const bf16x8*)&Xs[m * 64 + (((kc * 4 + g) ^ (m & 7)) << 3)];
      }
      #pragma unroll
      for (int ni = 0; ni < 2; ++ni) {
        int n = w * 32 + ni * 16 + c;
        wf[ni] = *(const bf16x8*)&Ws[n * 64 + (((kc * 4 + g) ^ (n & 7)) << 3)];
      }
      #pragma unroll
      for (int mi = 0; mi < 7; ++mi)
        #pragma unroll
        for (int ni = 0; ni < 2; ++ni)
          acc[mi][ni] = (ORIENT == 0)
            ? __builtin_amdgcn_mfma_f32_16x16x32_bf16(wf[ni], xf[mi], acc[mi][ni], 0, 0, 0)
            : __builtin_amdgcn_mfma_f32_16x16x32_bf16(xf[mi], wf[ni], acc[mi][ni], 0, 0, 0);
    }
    __syncthreads();
  }

  if (ORIENT == 0) {
    ushort* Ob = (ushort*)OutV;
    const int nbq = n0 + w * 32;
    float bi[2][4];
    #pragma unroll
    for (int ni = 0; ni < 2; ++ni)
      #pragma unroll
      for (int j = 0; j < 4; ++j) {
        int n = nbq + ni * 16 + g * 4 + j;
        bi[ni][j] = (n < Nreal) ? bias[n] : 0.f;
      }
    #pragma unroll
    for (int mi = 0; mi < 7; ++mi) {
      int m = m0 + mi * 16 + c;
      #pragma unroll
      for (int ni = 0; ni < 2; ++ni) {
        int nb = nbq + ni * 16 + g * 4;
        if (nb >= Nstore) continue;
        float v[4];
        #pragma unroll
        for (int j = 0; j < 4; ++j) v[j] = acc[mi][ni][j] + bi[ni][j];
        if (EPI == 1) {
          #pragma unroll
          for (int j = 0; j < 4; ++j) v[j] = fmaxf(v[j], 0.f);
        } else if (EPI == 2) {
          #pragma unroll
          for (int j = 0; j < 4; ++j)
            v[j] = 0.5f * v[j] * (1.f + erff(v[j] * 0.70710678118654752f));
        } else if (EPI == 3) {
          uint2 cm = *(const uint2*)&Ob[(size_t)m * Nstore + nb];
          float cf[4];
          unpack4bf(cm, cf);
          #pragma unroll
          for (int j = 0; j < 4; ++j)
            v[j] = (1.f / (1.f + __expf(-v[j]))) * cf[j];
        }
        uint2 o = {pack2bf(v[0], v[1]), pack2bf(v[2], v[3])};
        *(uint2*)&Ob[(size_t)m * Nstore + nb] = o;
      }
    }
  } else {
    const int bb = m0 / NPIX;
    const int prow = m0 - bb * NPIX;
    float* Ob = (float*)OutV + (size_t)bb * CDIM * NPIX;
    const float* Rb = resid + (size_t)bb * CDIM * NPIX;
    float sc = scales ? scales[bb * 3] : 1.f;
    #pragma unroll
    for (int ni = 0; ni < 2; ++ni) {
      int n = n0 + w * 32 + ni * 16 + c;
      float bv = bias[n];
      #pragma unroll
      for (int mi = 0; mi < 7; ++mi) {
        int p = prow + mi * 16 + g * 4;
        size_t off = (size_t)n * NPIX + p;
        float4 r = *(const float4*)&Rb[off];
        f32x4 a = acc[mi][ni];
        float4 o = {r.x + sc * (a[0] + bv), r.y + sc * (a[1] + bv),
                    r.z + sc * (a[2] + bv), r.w + sc * (a[3] + bv)};
        *(float4*)&Ob[off] = o;
      }
    }
  }
}

// ---------------------------------------------------------------------------
// transpose V out of qkvbf:  [b][p][1024+c] bf16 -> vbf [b][c][784] bf16
__global__ __launch_bounds__(256) void vtr_k(const ushort* __restrict__ qkvbf,
                                             ushort* __restrict__ vbf) {
  const int p0 = blockIdx.x * 64, c0 = blockIdx.y * 64, b = blockIdx.z;
  __shared__ ushort T[64][72];
  for (int idx = threadIdx.x; idx < 512; idx += 256) {
    int pl = idx >> 3, cq = idx & 7;
    int p = p0 + pl;
    uint4 v = {0u, 0u, 0u, 0u};
    if (p < NPIX)
      v = *(const uint4*)(qkvbf + (size_t)(b * NPIX + p) * C3 + 1024 + c0 + cq * 8);
    *(uint4*)&T[pl][cq * 8] = v;
  }
  __syncthreads();
  for (int idx = threadIdx.x; idx < 512; idx += 256) {
    int cl = idx >> 3, pq = idx & 7;
    if (p0 + pq * 8 < NPIX) {
      ushort tmp[8];
      #pragma unroll
      for (int i = 0; i < 8; ++i) tmp[i] = T[pq * 8 + i][cl];
      *(uint4*)(vbf + ((size_t)(b * CDIM + c0 + cl)) * NPIX + p0 + pq * 8) =
          *(const uint4*)&tmp[0];
    }
  }
}

// f32 ch-major -> bf16 pixel-major (x3 -> x3bf)
__global__ __launch_bounds__(256) void tr_cvt_k(const float* __restrict__ src,
                                                ushort* __restrict__ dst) {
  const int p0 = blockIdx.x * 64, c0 = blockIdx.y * 64, b = blockIdx.z;
  __shared__ ushort T[64][72];
  const float* sb = src + (size_t)b * CDIM * NPIX;
  for (int idx = threadIdx.x; idx < 4096; idx += 256) {
    int ci = idx >> 6, pj = idx & 63;
    int p = p0 + pj;
    T[pj][ci] = (p < NPIX) ? f2bf(sb[(size_t)(c0 + ci) * NPIX + p]) : (ushort)0;
  }
  __syncthreads();
  for (int idx = threadIdx.x; idx < 512; idx += 256) {
    int pj = idx >> 3, cq = idx & 7;
    int p = p0 + pj;
    if (p < NPIX) {
      uint4 v = *(const uint4*)&T[pj][cq * 8];
      *(uint4*)(dst + ((size_t)(b * NPIX + p)) * CDIM + c0 + cq * 8) = v;
    }
  }
}

// ---------------------------------------------------------------------------
// MFMA flash attention: 32 q rows / wave (2 chunks), shared K/V frags,
// bf16 pre-folded biases, online softmax, wave-autonomous (no barriers).
// 1D grid of 896; XCD-aware: batch b = (bid&7) + 8*(i/56) -> all 56 blocks of
// one batch co-reside on one XCD (K/V + fp[b] L2 reuse).
__global__ __launch_bounds__(256) void attn_mfma_k(const ushort* __restrict__ qkvbf,
                                                   const ushort* __restrict__ vbf,
                                                   const ushort* __restrict__ sprpb,
                                                   const ushort* __restrict__ fpb,
                                                   ushort* __restrict__ obf) {
  const int bid = blockIdx.x;
  const int xcd = bid & 7;
  const int i = bid >> 3;              // 0..111
  const int b = xcd + 8 * (i / 56);
  const int r = i % 56;
  const int h = r & 7;
  const int qt = r >> 3;               // 0..6
  const int w = threadIdx.x >> 6, lane = threadIdx.x & 63;
  const int g = lane >> 4, c = lane & 15;
  const int q0 = qt * 128 + w * 32;
  if (q0 >= NPIX) return;
  const bool hasB = (q0 + 16) < NPIX;
  const int qA = q0 + c;
  const int qB = q0 + 16 + c;

  __shared__ uint BL[4][2][384];
  uint* bwA = BL[w][0];
  uint* bwB = BL[w][1];

  const ushort* qpA = qkvbf + (size_t)(b * NPIX + qA) * C3 + h * 64 + g * 8;
  const bf16x8 qfA0 = *(const bf16x8*)qpA;
  const bf16x8 qfA1 = *(const bf16x8*)(qpA + 32);
  bf16x8 qfB0 = qfA0, qfB1 = qfA1;
  if (hasB) {
    const ushort* qpB = qkvbf + (size_t)(b * NPIX + qB) * C3 + h * 64 + g * 8;
    qfB0 = *(const bf16x8*)qpB;
    qfB1 = *(const bf16x8*)(qpB + 32);
  }

  const ushort* kbase = qkvbf + (size_t)b * NPIX * C3 + 512 + h * 64 + g * 8;
  const ushort* vbase = vbf + ((size_t)b * CDIM + h * 64) * NPIX;
  const ushort* sprA = sprpb + ((size_t)h * NPIX + qA) * NPIX;
  const ushort* sprB = sprpb + ((size_t)h * NPIX + (hasB ? qB : qA)) * NPIX;
  const ushort* fpA = fpb + ((size_t)b * NPIX + qA) * NPIX;
  const ushort* fpB = fpb + ((size_t)b * NPIX + (hasB ? qB : qA)) * NPIX;

  f32x4 oA0 = {0.f, 0.f, 0.f, 0.f}, oA1 = oA0, oA2 = oA0, oA3 = oA0;
  f32x4 oB0 = oA0, oB1 = oA0, oB2 = oA0, oB3 = oA0;
  float MA = -1e30f, LA = 0.f, MB = -1e30f, LB = 0.f;

  for (int ms = 0; ms < 25; ++ms) {
    const int m0 = ms * 32;
    const bool full = (ms < 24);

    const ushort* kp = kbase + (size_t)(m0 + c) * C3;
    bf16x8 ka0 = *(const bf16x8*)kp;
    bf16x8 ka1 = *(const bf16x8*)(kp + 32);
    bf16x8 kb0 = ka0, kb1 = ka1;
    if (full) {
      const ushort* kp1 = kp + (size_t)16 * C3;
      kb0 = *(const bf16x8*)kp1;
      kb1 = *(const bf16x8*)(kp1 + 32);
    }

    // ---- chunk A ----
    f32x4 sA0 = {0.f, 0.f, 0.f, 0.f}, sA1 = sA0;
    sA0 = __builtin_amdgcn_mfma_f32_16x16x32_bf16(ka0, qfA0, sA0, 0, 0, 0);
    sA0 = __builtin_amdgcn_mfma_f32_16x16x32_bf16(ka1, qfA1, sA0, 0, 0, 0);
    if (full) {
      sA1 = __builtin_amdgcn_mfma_f32_16x16x32_bf16(kb0, qfA0, sA1, 0, 0, 0);
      sA1 = __builtin_amdgcn_mfma_f32_16x16x32_bf16(kb1, qfA1, sA1, 0, 0, 0);
    }

    float vA0[4], vA1[4];
    {
      float spv[4], fpv[4];
      unpack4bf(*(const uint2*)(sprA + m0 + g * 4), spv);
      unpack4bf(*(const uint2*)(fpA + m0 + g * 4), fpv);
      #pragma unroll
      for (int j = 0; j < 4; ++j) vA0[j] = fmaf(sA0[j], 0.125f, spv[j]) * fpv[j];
      if (full) {
        unpack4bf(*(const uint2*)(sprA + m0 + 16 + g * 4), spv);
        unpack4bf(*(const uint2*)(fpA + m0 + 16 + g * 4), fpv);
        #pragma unroll
        for (int j = 0; j < 4; ++j) vA1[j] = fmaf(sA1[j], 0.125f, spv[j]) * fpv[j];
      }
    }
    {
      float tm = fmaxf(fmaxf(vA0[0], vA0[1]), fmaxf(vA0[2], vA0[3]));
      if (full) tm = fmaxf(tm, fmaxf(fmaxf(vA1[0], vA1[1]), fmaxf(vA1[2], vA1[3])));
      tm = fmaxf(tm, __shfl_xor(tm, 16));
      tm = fmaxf(tm, __shfl_xor(tm, 32));
      const float nM = fmaxf(MA, tm);
      const float fac = __expf(MA - nM);
      float p0v[4], p1v[4];
      float ps = 0.f;
      #pragma unroll
      for (int j = 0; j < 4; ++j) { p0v[j] = __expf(vA0[j] - nM); ps += p0v[j]; }
      if (full) {
        #pragma unroll
        for (int j = 0; j < 4; ++j) { p1v[j] = __expf(vA1[j] - nM); ps += p1v[j]; }
      }
      ps += __shfl_xor(ps, 16);
      ps += __shfl_xor(ps, 32);
      LA = LA * fac + ps;
      MA = nM;
      #pragma unroll
      for (int j = 0; j < 4; ++j) { oA0[j] *= fac; oA1[j] *= fac; oA2[j] *= fac; oA3[j] *= fac; }
      uint2 wlo, whi;
      wlo.x = pack2bf(p0v[0], p0v[1]);
      wlo.y = pack2bf(p0v[2], p0v[3]);
      whi.x = full ? pack2bf(p1v[0], p1v[1]) : 0u;
      whi.y = full ? pack2bf(p1v[2], p1v[3]) : 0u;
      *(uint2*)&bwA[lane * 6] = wlo;
      *(uint2*)&bwA[lane * 6 + 2] = whi;
    }

    // ---- chunk B ----
    if (hasB) {
      f32x4 sB0 = {0.f, 0.f, 0.f, 0.f}, sB1 = sB0;
      sB0 = __builtin_amdgcn_mfma_f32_16x16x32_bf16(ka0, qfB0, sB0, 0, 0, 0);
      sB0 = __builtin_amdgcn_mfma_f32_16x16x32_bf16(ka1, qfB1, sB0, 0, 0, 0);
      if (full) {
        sB1 = __builtin_amdgcn_mfma_f32_16x16x32_bf16(kb0, qfB0, sB1, 0, 0, 0);
        sB1 = __builtin_amdgcn_mfma_f32_16x16x32_bf16(kb1, qfB1, sB1, 0, 0, 0);
      }
      float vB0[4], vB1[4];
      {
        float spv[4], fpv[4];
        unpack4bf(*(const uint2*)(sprB + m0 + g * 4), spv);
        unpack4bf(*(const uint2*)(fpB + m0 + g * 4), fpv);
        #pragma unroll
        for (int j = 0; j < 4; ++j) vB0[j] = fmaf(sB0[j], 0.125f, spv[j]) * fpv[j];
        if (full) {
          unpack4bf(*(const uint2*)(sprB + m0 + 16 + g * 4), spv);
          unpack4bf(*(const uint2*)(fpB + m0 + 16 + g * 4), fpv);
          #pragma unroll
          for (int j = 0; j < 4; ++j) vB1[j] = fmaf(sB1[j], 0.125f, spv[j]) * fpv[j];
        }
      }
      float tm = fmaxf(fmaxf(vB0[0], vB0[1]), fmaxf(vB0[2], vB0[3]));
      if (full) tm = fmaxf(tm, fmaxf(fmaxf(vB1[0], vB1[1]), fmaxf(vB1[2], vB1[3])));
      tm = fmaxf(tm, __shfl_xor(tm, 16));
      tm = fmaxf(tm, __shfl_xor(tm, 32));
      const float nM = fmaxf(MB, tm);
      const float fac = __expf(MB - nM);
      float p0v[4], p1v[4];
      float ps = 0.f;
      #pragma unroll
      for (int j = 0; j < 4; ++j) { p0v[j] = __expf(vB0[j] - nM); ps += p0v[j]; }
      if (full) {
        #pragma unroll
        for (int j = 0; j < 4; ++j) { p1v[j] = __expf(vB1[j] - nM); ps += p1v[j]; }
      }
      ps += __shfl_xor(ps, 16);
      ps += __shfl_xor(ps, 32);
      LB = LB * fac + ps;
      MB = nM;
      #pragma unroll
      for (int j = 0; j < 4; ++j) { oB0[j] *= fac; oB1[j] *= fac; oB2[j] *= fac; oB3[j] *= fac; }
      uint2 wlo, whi;
      wlo.x = pack2bf(p0v[0], p0v[1]);
      wlo.y = pack2bf(p0v[2], p0v[3]);
      whi.x = full ? pack2bf(p1v[0], p1v[1]) : 0u;
      whi.y = full ? pack2bf(p1v[2], p1v[3]) : 0u;
      *(uint2*)&bwB[lane * 6] = wlo;
      *(uint2*)&bwB[lane * 6 + 2] = whi;
    }

    // ---- V fragments (shared) + PV for both chunks ----
    const int f = g >> 1;
    const int slo = 32 * (g & 1) + c;
    uint2 blo = *(const uint2*)&bwA[slo * 6 + f * 2];
    uint2 bhi = *(const uint2*)&bwA[(slo + 16) * 6 + f * 2];
    uint4 bba = {blo.x, blo.y, bhi.x, bhi.y};
    const bf16x8 pfA = __builtin_bit_cast(bf16x8, bba);

    const ushort* vp = vbase + (size_t)c * NPIX + m0 + g * 8;
    bf16x8 vf0 = *(const bf16x8*)(vp);
    bf16x8 vf1 = *(const bf16x8*)(vp + (size_t)16 * NPIX);
    bf16x8 vf2 = *(const bf16x8*)(vp + (size_t)32 * NPIX);
    bf16x8 vf3 = *(const bf16x8*)(vp + (size_t)48 * NPIX);
    oA0 = __builtin_amdgcn_mfma_f32_16x16x32_bf16(vf0, pfA, oA0, 0, 0, 0);
    oA1 = __builtin_amdgcn_mfma_f32_16x16x32_bf16(vf1, pfA, oA1, 0, 0, 0);
    oA2 = __builtin_amdgcn_mfma_f32_16x16x32_bf16(vf2, pfA, oA2, 0, 0, 0);
    oA3 = __builtin_amdgcn_mfma_f32_16x16x32_bf16(vf3, pfA, oA3, 0, 0, 0);
    if (hasB) {
      uint2 clo = *(const uint2*)&bwB[slo * 6 + f * 2];
      uint2 chi = *(const uint2*)&bwB[(slo + 16) * 6 + f * 2];
      uint4 bbb = {clo.x, clo.y, chi.x, chi.y};
      const bf16x8 pfB = __builtin_bit_cast(bf16x8, bbb);
      oB0 = __builtin_amdgcn_mfma_f32_16x16x32_bf16(vf0, pfB, oB0, 0, 0, 0);
      oB1 = __builtin_amdgcn_mfma_f32_16x16x32_bf16(vf1, pfB, oB1, 0, 0, 0);
      oB2 = __builtin_amdgcn_mfma_f32_16x16x32_bf16(vf2, pfB, oB2, 0, 0, 0);
      oB3 = __builtin_amdgcn_mfma_f32_16x16x32_bf16(vf3, pfB, oB3, 0, 0, 0);
    }
  }

  {
    const float invL = 1.f / LA;
    ushort* dst = obf + (size_t)(b * NPIX + qA) * CDIM + h * 64 + g * 4;
    f32x4 ot[4] = {oA0, oA1, oA2, oA3};
    #pragma unroll
    for (int t2 = 0; t2 < 4; ++t2) {
      uint2 o = {pack2bf(ot[t2][0] * invL, ot[t2][1] * invL),
                 pack2bf(ot[t2][2] * invL, ot[t2][3] * invL)};
      *(uint2*)(dst + t2 * 16) = o;
    }
  }
  if (hasB) {
    const float invL = 1.f / LB;
    ushort* dst = obf + (size_t)(b * NPIX + qB) * CDIM + h * 64 + g * 4;
    f32x4 ot[4] = {oB0, oB1, oB2, oB3};
    #pragma unroll
    for (int t2 = 0; t2 < 4; ++t2) {
      uint2 o = {pack2bf(ot[t2][0] * invL, ot[t2][1] * invL),
                 pack2bf(ot[t2][2] * invL, ot[t2][3] * invL)};
      *(uint2*)(dst + t2 * 16) = o;
    }
  }
}

// ---------------------------------------------------------------------------
// Sliding-window fused LN2 + depthwise conv (3x3/5x5/7x7) -> cat pm bf16.
__device__ __forceinline__ float bf2f_s(ushort u) { return bf2f(u); }

template <int R>
__device__ __forceinline__ void conv_pass(const ushort* __restrict__ plane_ci,
                                          const float* __restrict__ wl_ci,
                                          float bv, int slot,
                                          ushort (*__restrict__ outb)[16], int ci) {
  constexpr int K = 2 * R + 1;
  float wreg[K * K];
  #pragma unroll
  for (int i = 0; i < K * K; ++i) wreg[i] = wl_ci[i];
  #pragma unroll
  for (int r7 = 0; r7 < 7; ++r7) {
    const int run = slot + r7 * 16;
    const int y = run >> 2, x0 = (run & 3) * 7;
    float acc[7];
    #pragma unroll
    for (int i = 0; i < 7; ++i) acc[i] = bv;
    #pragma unroll
    for (int dy = 0; dy < K; ++dy) {
      const ushort* rp = plane_ci + (y + 3 - R + dy) * 34 + (x0 + 3 - R);
      float win[7 + 2 * R];
      #pragma unroll
      for (int k = 0; k < 7 + 2 * R; ++k) win[k] = bf2f_s(rp[k]);
      #pragma unroll
      for (int i = 0; i < 7; ++i)
        #pragma unroll
        for (int k = 0; k < K; ++k)
          acc[i] = fmaf(win[i + k], wreg[dy * K + k], acc[i]);
    }
    #pragma unroll
    for (int i = 0; i < 7; ++i) outb[y * 28 + x0 + i][ci] = f2bf(acc[i]);
  }
}

__global__ __launch_bounds__(256) void dwln_k(const float* __restrict__ x2,
    const float* __restrict__ ust, const float* __restrict__ rst,
    const float* __restrict__ ad, const float* __restrict__ n2w,
    const float* __restrict__ n2b,
    const float* __restrict__ ew, const float* __restrict__ eb,
    const float* __restrict__ nw, const float* __restrict__ nb,
    const float* __restrict__ mw, const float* __restrict__ mb,
    ushort* __restrict__ cat) {
  const int cg = blockIdx.x, b = blockIdx.y;
  const int c0 = cg * 16;
  const int t = threadIdx.x;
  const int ci = t & 15, slot = t >> 4;

  __shared__ ushort plane[16][1156];
  __shared__ ushort outb[784][16];
  __shared__ float Wl[16 * 49];
  __shared__ float LWs[16], LBs[16];

  {
    uint* pz = (uint*)&plane[0][0];
    for (int i = t; i < 16 * 1156 / 2; i += 256) pz[i] = 0u;
  }
  if (t < 16) {
    int cc = c0 + t;
    float aw = ad[b * 1024 + cc], ab = ad[b * 1024 + 512 + cc];
    LWs[t] = n2w[cc] * (1.f + aw);
    LBs[t] = n2b[cc] + ab;
  }
  __syncthreads();

  {
    float uu[4], rr[4];
    #pragma unroll
    for (int j = 0; j < 4; ++j) {
      int p = t + j * 256;
      if (p < NPIX) {
        uu[j] = ust[(size_t)b * NPIX + p];
        rr[j] = rst[(size_t)b * NPIX + p];
      }
    }
    for (int cc = 0; cc < 16; ++cc) {
      const float* xp = x2 + ((size_t)(b * CDIM + c0 + cc)) * NPIX;
      float lw = LWs[cc], lb = LBs[cc];
      #pragma unroll
      for (int j = 0; j < 4; ++j) {
        int p = t + j * 256;
        if (p < NPIX) {
          int y = p / 28, xx2 = p - y * 28;
          plane[cc][(y + 3) * 34 + xx2 + 3] = f2bf(lw * (xp[p] - uu[j]) * rr[j] + lb);
        }
      }
    }
  }
  __syncthreads();

  #pragma unroll 1
  for (int cv = 0; cv < 3; ++cv) {
    const float* gw = (cv == 0) ? ew : (cv == 1) ? nw : mw;
    const float* gb = (cv == 0) ? eb : (cv == 1) ? nb : mb;
    const int K2 = (cv == 0) ? 9 : (cv == 1) ? 25 : 49;
    for (int i = t; i < 16 * K2; i += 256) {
      int cc = i / K2, k = i - cc * K2;
      Wl[cc * K2 + k] = gw[(size_t)(c0 + cc) * K2 + k];
    }
    __syncthreads();
    float bv = gb[c0 + ci];
    if (cv == 0)      conv_pass<1>(&plane[ci][0], &Wl[ci * 9],  bv, slot, outb, ci);
    else if (cv == 1) conv_pass<2>(&plane[ci][0], &Wl[ci * 25], bv, slot, outb, ci);
    else              conv_pass<3>(&plane[ci][0], &Wl[ci * 49], bv, slot, outb, ci);
    __syncthreads();
    for (int idx = t; idx < NPIX * 2; idx += 256) {
      int p = idx >> 1, half = idx & 1;
      uint4 v = *(const uint4*)&outb[p][half * 8];
      *(uint4*)(cat + ((size_t)(b * NPIX + p)) * C3 + cv * 512 + c0 + half * 8) = v;
    }
    __syncthreads();
  }
}

// ---------------------------------------------------------------------------
__global__ __launch_bounds__(64) void router_k(const float* __restrict__ pooled,
                                               const float* __restrict__ rw,
                                               const float* __restrict__ rb,
                                               float* __restrict__ r) {
  int b = blockIdx.x, lane = threadIdx.x;
  float a0 = 0.f, a1 = 0.f, a2 = 0.f;
  for (int k = lane; k < CDIM; k += 64) {
    float p = pooled[b * CDIM + k];
    a0 += rw[k] * p;
    a1 += rw[CDIM + k] * p;
    a2 += rw[2 * CDIM + k] * p;
  }
  #pragma unroll
  for (int off = 32; off; off >>= 1) {
    a0 += __shfl_down(a0, off);
    a1 += __shfl_down(a1, off);
    a2 += __shfl_down(a2, off);
  }
  if (lane == 0) {
    float l0 = a0 + rb[0], l1 = a1 + rb[1], l2 = a2 + rb[2];
    float mx = fmaxf(l0, fmaxf(l1, l2));
    float e0 = __expf(l0 - mx), e1 = __expf(l1 - mx), e2 = __expf(l2 - mx);
    float inv = 1.f / (e0 + e1 + e2);
    r[b * 3 + 0] = e0 * inv;
    r[b * 3 + 1] = e1 * inv;
    r[b * 3 + 2] = e2 * inv;
  }
}

// ---------------------------------------------------------------------------
extern "C" void kernel_launch(void* const* d_in, const int* in_sizes, int n_in,
                              void* d_out, int out_size, void* d_ws, size_t ws_size,
                              hipStream_t stream) {
  (void)in_sizes; (void)n_in; (void)out_size; (void)ws_size;
  const float* x         = (const float*)d_in[0];
  const float* fpri      = (const float*)d_in[1];
  const float* n1_w      = (const float*)d_in[2];
  const float* n1_b      = (const float*)d_in[3];
  const float* n1_a1w    = (const float*)d_in[4];
  const float* n1_a1b    = (const float*)d_in[5];
  const float* n1_a2w    = (const float*)d_in[6];
  const float* n1_a2b    = (const float*)d_in[7];
  const float* n2_w      = (const float*)d_in[8];
  const float* n2_b      = (const float*)d_in[9];
  const float* n2_a1w    = (const float*)d_in[10];
  const float* n2_a1b    = (const float*)d_in[11];
  const float* n2_a2w    = (const float*)d_in[12];
  const float* n2_a2b    = (const float*)d_in[13];
  const float* qkv_w     = (const float*)d_in[14];
  const float* qkv_b     = (const float*)d_in[15];
  const float* rpb_table = (const float*)d_in[16];
  const float* sprior    = (const float*)d_in[17];
  const float* proj_w    = (const float*)d_in[18];
  const float* proj_b    = (const float*)d_in[19];
  const float* eye_w     = (const float*)d_in[20];
  const float* eye_b     = (const float*)d_in[21];
  const float* nose_w    = (const float*)d_in[22];
  const float* nose_b    = (const float*)d_in[23];
  const float* mouth_w   = (const float*)d_in[24];
  const float* mouth_b   = (const float*)d_in[25];
  const float* fusion_w  = (const float*)d_in[26];
  const float* fusion_b  = (const float*)d_in[27];
  const float* gate1_w   = (const float*)d_in[28];
  const float* gate1_b   = (const float*)d_in[29];
  const float* gate2_w   = (const float*)d_in[30];
  const float* gate2_b   = (const float*)d_in[31];
  const float* e1w[3] = {(const float*)d_in[32], (const float*)d_in[36], (const float*)d_in[40]};
  const float* e1b[3] = {(const float*)d_in[33], (const float*)d_in[37], (const float*)d_in[41]};
  const float* e2w[3] = {(const float*)d_in[34], (const float*)d_in[38], (const float*)d_in[42]};
  const float* e2b[3] = {(const float*)d_in[35], (const float*)d_in[39], (const float*)d_in[43]};
  const float* router_w  = (const float*)d_in[44];
  const float* router_b  = (const float*)d_in[45];

  float* ws    = (float*)d_ws;
  ushort* xpm  = (ushort*)(ws + OFF_XPM);
  ushort* wb   = (ushort*)(ws + OFF_W);
  ushort* r2u  = (ushort*)(ws + OFF_R2);   // qkvbf -> catpm -> he
  ushort* vbf  = (ushort*)(ws + OFF_VBF);  // vbf -> x3bf
  ushort* obf  = (ushort*)(ws + OFF_OBF);  // obf -> g1bf
  float* x2    = ws + OFF_X2;
  float* x3    = ws + OFF_X3;
  float* pld   = ws + OFF_PL;
  float* adb   = ws + OFF_AD;
  float* rbuf  = ws + OFF_RB;
  float* ust   = ws + OFF_US;
  float* rst   = ws + OFF_RS;
  float* outp  = (float*)d_out;

  ushort* qkvw = wb + WOFF_QKV;
  ushort* projw = wb + WOFF_PROJ;
  ushort* g1w  = wb + WOFF_G1;
  ushort* g2w  = wb + WOFF_G2;
  ushort* fusw = wb + WOFF_FUS;

  // attention bias buffers alias the (still-dead) x2/x3 regions
  ushort* fpbf   = (ushort*)x2;   // 19.7 MB; x2 written after attn
  ushort* sprpbf = (ushort*)x3;   // 9.8 MB; x3 written after attn

  // --- weight conversion (all fp32 -> bf16, e2 K-padded 682->704) ---
  CvtDesc D;
  D.s[0] = qkv_w;    D.d[0] = qkvw;  D.rows[0] = 1536; D.sk[0] = 512;  D.dk[0] = 512;
  D.s[1] = proj_w;   D.d[1] = projw; D.rows[1] = 512;  D.sk[1] = 512;  D.dk[1] = 512;
  D.s[2] = gate1_w;  D.d[2] = g1w;   D.rows[2] = 128;  D.sk[2] = 512;  D.dk[2] = 512;
  D.s[3] = gate2_w;  D.d[3] = g2w;   D.rows[3] = 1536; D.sk[3] = 128;  D.dk[3] = 128;
  D.s[4] = fusion_w; D.d[4] = fusw;  D.rows[4] = 512;  D.sk[4] = 1536; D.dk[4] = 1536;
  for (int e = 0; e < 3; ++e) {
    D.s[5 + e] = e1w[e]; D.d[5 + e] = wb + WOFF_E1 + e * 349184;
    D.rows[5 + e] = 682; D.sk[5 + e] = 512; D.dk[5 + e] = 512;
    D.s[8 + e] = e2w[e]; D.d[8 + e] = wb + WOFF_E2 + e * 360448;
    D.rows[8 + e] = 512; D.sk[8 + e] = 682; D.dk[8 + e] = 704;
  }
  cvt_w_k<<<dim3(512, 11), 256, 0, stream>>>(D);

  // --- attention bias prep ---
  sprpb_k<<<dim3(NPIX, NHEAD), 256, 0, stream>>>(sprior, rpb_table, sprpbf);
  fpcvt_k<<<9604, 256, 0, stream>>>(fpri, fpbf);

  // --- LN1 ---
  pool_mean_k<<<dim3(CDIM, 16), 64, 0, stream>>>(x, pld);
  adapt_mlp_k<<<16, 256, 0, stream>>>(pld, n1_a1w, n1_a1b, n1_a2w, n1_a2b, adb);
  ln_pm_k<0><<<dim3(25, 16), 256, 0, stream>>>(x, n1_w, n1_b, adb, xpm, nullptr, nullptr);

  // --- attention ---
  mgemm_k<0, 0><<<1344, 256, 0, stream>>>(xpm, qkvw, qkv_b, nullptr, nullptr,
                                          r2u, 512, 1536, 1536);
  vtr_k<<<dim3(13, 8, 16), 256, 0, stream>>>(r2u, vbf);
  attn_mfma_k<<<896, 256, 0, stream>>>(r2u, vbf, sprpbf, fpbf, obf);
  mgemm_k<1, 4><<<448, 256, 0, stream>>>(obf, projw, proj_b, x, nullptr,
                                         x2, 512, 512, 512);

  // --- LN2 + token mixer ---
  pool_mean_k<<<dim3(CDIM, 16), 64, 0, stream>>>(x2, pld);
  adapt_mlp_k<<<16, 256, 0, stream>>>(pld, n2_a1w, n2_a1b, n2_a2w, n2_a2b, adb);
  ln_pm_k<1><<<dim3(25, 16), 256, 0, stream>>>(x2, n2_w, n2_b, adb, xpm, ust, rst);
  dwln_k<<<dim3(32, 16), 256, 0, stream>>>(x2, ust, rst, adb, n2_w, n2_b,
                                           eye_w, eye_b, nose_w, nose_b, mouth_w, mouth_b,
                                           r2u);
  mgemm_k<0, 1><<<112, 256, 0, stream>>>(xpm, g1w, gate1_b, nullptr, nullptr,
                                         obf, 512, 128, 128);
  mgemm_k<0, 3><<<1344, 256, 0, stream>>>(obf, g2w, gate2_b, nullptr, nullptr,
                                          r2u, 128, 1536, 1536);
  mgemm_k<1, 4><<<448, 256, 0, stream>>>(r2u, fusw, fusion_b, x2, nullptr,
                                         x3, 1536, 512, 512);

  // --- MoE ---
  tr_cvt_k<<<dim3(13, 8, 16), 256, 0, stream>>>(x3, vbf);
  pool_mean_k<<<dim3(CDIM, 16), 64, 0, stream>>>(x3, pld);
  router_k<<<16, 64, 0, stream>>>(pld, router_w, router_b, rbuf);
  for (int e = 0; e < 3; ++e) {
    mgemm_k<0, 2><<<672, 256, 0, stream>>>(vbf, wb + WOFF_E1 + e * 349184,
                                           e1b[e], nullptr, nullptr,
                                           r2u, 512, 682, 704);
    mgemm_k<1, 4><<<448, 256, 0, stream>>>(r2u, wb + WOFF_E2 + e * 360448,
                                           e2b[e], (e == 0) ? x3 : outp,
                                           rbuf + e, outp, 704, 512, 512);
  }
}

// Round 7
// 816.655 us; speedup vs baseline: 3.6254x; 1.0561x over previous
//
#include <hip/hip_runtime.h>
#include <math.h>

// ---------------------------------------------------------------------------
// EfficientFaceTransformer forward — round 7: fused MoE (stacked experts,
// router folded into gelu epilogue), attn defer-max, native v_cvt_pk_bf16.
// ---------------------------------------------------------------------------

#define NPIX 784
#define CDIM 512
#define NHEAD 8
#define C3 1536

typedef unsigned int uint;
typedef unsigned short ushort;
typedef float f32x4 __attribute__((ext_vector_type(4)));
typedef __bf16 bf16x8 __attribute__((ext_vector_type(8)));
typedef __bf16 bf16x2 __attribute__((ext_vector_type(2)));

// ---- workspace float offsets ----------------------------------------------
#define OFF_XPM ((size_t)0)          // pm bf16 act (xa / xn2 / x3bf)
#define OFF_W   ((size_t)3211264)    // bf16 weights (qkv,proj,g1,g2,fus,e1cat,e2cat... e2cat tail-relocated)
#define OFF_R2  ((size_t)5324288)    // qkvbf -> catpm -> he (he spans R2+VBF+part of OBF)
#define OFF_VBF ((size_t)14958080)   // vbf (attn V)
#define OFF_OBF ((size_t)18169344)   // obf -> g1bf
#define OFF_X2  ((size_t)21380608)   // fp_bf (attn) -> x2 f32 ch-major
#define OFF_X3  ((size_t)27803136)   // sprpb_bf (attn) -> x3 f32 ch-major
#define OFF_PL  ((size_t)34225664)
#define OFF_AD  ((size_t)34233856)   // adapt out -> be[16][512] + e1bcat[2112]
#define OFF_RB  ((size_t)34250240)
#define OFF_US  ((size_t)34250288)
#define OFF_RS  ((size_t)34262832)
#define OFF_E2C ((size_t)34275392)   // e2cat bf16 [512][2112] (540672 floats)

// weight sub-offsets (ushort units)
#define WOFF_QKV 0
#define WOFF_PROJ 786432
#define WOFF_G1  1048576
#define WOFF_G2  1114112
#define WOFF_FUS 1310720
#define WOFF_E1  2097152   /* e1cat [2112][512] stacked, 704-aligned */

__device__ __forceinline__ ushort f2bf(float f) {
  __bf16 h = (__bf16)f;
  return __builtin_bit_cast(ushort, h);
}
__device__ __forceinline__ unsigned pack2bf(float lo, float hi) {
  bf16x2 v = {(__bf16)lo, (__bf16)hi};
  return __builtin_bit_cast(unsigned, v);
}
__device__ __forceinline__ float bf2f(ushort u) {
  unsigned x = ((unsigned)u) << 16;
  return __builtin_bit_cast(float, x);
}
__device__ __forceinline__ void unpack4bf(uint2 v, float* o) {
  o[0] = bf2f((ushort)(v.x & 0xffffu)); o[1] = bf2f((ushort)(v.x >> 16));
  o[2] = bf2f((ushort)(v.y & 0xffffu)); o[3] = bf2f((ushort)(v.y >> 16));
}

// ---------------------------------------------------------------------------
__global__ __launch_bounds__(64) void pool_mean_k(const float* __restrict__ x,
                                                  float* __restrict__ pooled) {
  int c = blockIdx.x, b = blockIdx.y;
  const float* row = x + ((size_t)b * CDIM + c) * NPIX;
  float s = 0.f;
  for (int i = threadIdx.x; i < NPIX; i += 64) s += row[i];
  #pragma unroll
  for (int off = 32; off; off >>= 1) s += __shfl_down(s, off);
  if (threadIdx.x == 0) pooled[b * CDIM + c] = s * (1.f / NPIX);
}

// ---------------------------------------------------------------------------
__global__ __launch_bounds__(256) void adapt_mlp_k(const float* __restrict__ pooled,
                                                   const float* __restrict__ a1w,
                                                   const float* __restrict__ a1b,
                                                   const float* __restrict__ a2w,
                                                   const float* __restrict__ a2b,
                                                   float* __restrict__ ad) {
  int b = blockIdx.x, tid = threadIdx.x;
  __shared__ float pl[CDIM];
  __shared__ float hh[128];
  for (int i = tid; i < CDIM; i += 256) pl[i] = pooled[b * CDIM + i];
  __syncthreads();
  if (tid < 128) {
    const float* w = a1w + (size_t)tid * CDIM;
    float a = a1b[tid];
    for (int k = 0; k < CDIM; ++k) a += w[k] * pl[k];
    hh[tid] = fmaxf(a, 0.f);
  }
  __syncthreads();
  for (int o = tid; o < 1024; o += 256) {
    const float* w = a2w + (size_t)o * 128;
    float a = a2b[o];
    for (int k = 0; k < 128; ++k) a += w[k] * hh[k];
    ad[b * 1024 + o] = a;
  }
}

// ---------------------------------------------------------------------------
// adaptive LN: read f32 ch-major, write bf16 pixel-major [b][p][512].
template <int STATS>
__global__ __launch_bounds__(256) void ln_pm_k(const float* __restrict__ x,
                                               const float* __restrict__ w,
                                               const float* __restrict__ bias,
                                               const float* __restrict__ ad,
                                               ushort* __restrict__ out,
                                               float* __restrict__ ust,
                                               float* __restrict__ rstp) {
  int b = blockIdx.y;
  int p0 = blockIdx.x * 32;
  int tid = threadIdx.x;
  int px = tid & 31, cg = tid >> 5;
  int p = p0 + px;
  bool valid = p < NPIX;
  const float* xb = x + (size_t)b * CDIM * NPIX;
  float s = 0.f, s2 = 0.f;
  if (valid) {
    for (int c = cg * 64; c < cg * 64 + 64; ++c) {
      float v = xb[(size_t)c * NPIX + p];
      s += v; s2 += v * v;
    }
  }
  __shared__ float rs[8][32], rq[8][32], us[32], vs[32];
  rs[cg][px] = s; rq[cg][px] = s2;
  __syncthreads();
  if (tid < 32) {
    float ts = 0.f, ts2 = 0.f;
    #pragma unroll
    for (int g = 0; g < 8; ++g) { ts += rs[g][tid]; ts2 += rq[g][tid]; }
    float u = ts * (1.f / CDIM);
    float var = ts2 * (1.f / CDIM) - u * u;
    float rv = rsqrtf(var + 1e-6f);
    us[tid] = u; vs[tid] = rv;
    if (STATS && p0 + tid < NPIX) {
      ust[(size_t)b * NPIX + p0 + tid] = u;
      rstp[(size_t)b * NPIX + p0 + tid] = rv;
    }
  }
  __syncthreads();
  if (valid) {
    float u = us[px], rv = vs[px];
    const float* aw = ad + (size_t)b * 1024;
    const float* ab = aw + CDIM;
    ushort* ob = out + ((size_t)(b * NPIX + p)) * CDIM + cg * 64;
    for (int cb = 0; cb < 64; cb += 8) {
      int c = cg * 64 + cb;
      float vv[8];
      #pragma unroll
      for (int q = 0; q < 8; ++q) {
        float v = xb[(size_t)(c + q) * NPIX + p];
        vv[q] = w[c + q] * (1.f + aw[c + q]) * ((v - u) * rv) + (bias[c + q] + ab[c + q]);
      }
      uint4 o = {pack2bf(vv[0], vv[1]), pack2bf(vv[2], vv[3]),
                 pack2bf(vv[4], vv[5]), pack2bf(vv[6], vv[7])};
      *(uint4*)(ob + cb) = o;
    }
  }
}

// ---------------------------------------------------------------------------
// weight convert fp32 -> bf16 with stacking: d[r*ds + cc], zero outside
// (cc < sk && r < rr).
struct CvtDesc {
  const float* s[11];
  ushort* d[11];
  int rows[11], sk[11], dk[11], ds[11], rr[11];
};
__global__ __launch_bounds__(256) void cvt_w_k(CvtDesc D) {
  int seg = blockIdx.y;
  int sk = D.sk[seg], dk = D.dk[seg], ds = D.ds[seg], rr = D.rr[seg];
  int total = D.rows[seg] * dk;
  const float* s = D.s[seg];
  ushort* d = D.d[seg];
  for (int i = blockIdx.x * 256 + threadIdx.x; i < total; i += gridDim.x * 256) {
    int r = i / dk, cc = i - r * dk;
    d[(size_t)r * ds + cc] = (cc < sk && r < rr) ? f2bf(s[(size_t)r * sk + cc]) : (ushort)0;
  }
}

// ---------------------------------------------------------------------------
// bias prep: sprpb_bf[h][q][m] = bf16(struct_prior + rpb gather)
__global__ __launch_bounds__(256) void sprpb_k(const float* __restrict__ sp,
                                               const float* __restrict__ rpb,
                                               ushort* __restrict__ out) {
  const int q = blockIdx.x, h = blockIdx.y;
  const int i1 = q / 28, j1 = q - i1 * 28;
  const float* src = sp + ((size_t)h * NPIX + q) * NPIX;
  ushort* dst = out + ((size_t)h * NPIX + q) * NPIX;
  for (int m = threadIdx.x; m < NPIX; m += 256) {
    int i2 = m / 28, j2 = m - i2 * 28;
    float rv = rpb[(size_t)((i1 - i2 + 27) * 55 + (j1 - j2 + 27)) * NHEAD + h];
    dst[m] = f2bf(src[m] + rv);
  }
}

// fp f32 -> bf16 flat cast
__global__ __launch_bounds__(256) void fpcvt_k(const float* __restrict__ fp,
                                               ushort* __restrict__ out) {
  size_t i = (size_t)blockIdx.x * 256 + threadIdx.x;
  float4 v = *((const float4*)fp + i);
  ushort4 o;
  o.x = f2bf(v.x); o.y = f2bf(v.y); o.z = f2bf(v.z); o.w = f2bf(v.w);
  *((ushort4*)out + i) = o;
}

// ---------------------------------------------------------------------------
// MoE prep: be[b][n] = sum_e r_e * e2b_e[n]; e1bcat[2112] concat (704-aligned).
__global__ __launch_bounds__(512) void biaseff_k(const float* __restrict__ rbuf,
                                                 const float* __restrict__ b0,
                                                 const float* __restrict__ b1,
                                                 const float* __restrict__ b2,
                                                 const float* __restrict__ a0,
                                                 const float* __restrict__ a1,
                                                 const float* __restrict__ a2,
                                                 float* __restrict__ be,
                                                 float* __restrict__ e1bcat) {
  int b = blockIdx.x;
  if (b < 16) {
    int n = threadIdx.x;
    be[b * 512 + n] = rbuf[b * 3] * b0[n] + rbuf[b * 3 + 1] * b1[n] + rbuf[b * 3 + 2] * b2[n];
  } else {
    for (int i = threadIdx.x; i < 2112; i += 512) {
      int e = i / 704, r = i - e * 704;
      e1bcat[i] = (r < 682) ? (e == 0 ? a0 : e == 1 ? a1 : a2)[r] : 0.f;
    }
  }
}

// ---------------------------------------------------------------------------
// Universal MFMA GEMM, batch-flattened M (=12544), XCD-aware 1D grid.
// grid = 8 * 14 * NT; xcd=bid&7 owns 14 m-tiles; nt = (bid>>3)/14.
// ORIENT 0: out pm bf16 [m][Nstore]; EPI 0 none / 1 relu / 2 gelu /
//           3 sigmoid*inplace / 5 gelu * scales[b*3 + n/704] (stacked MoE).
// ORIENT 1: out ch f32 [b][512][784];
//           EPI 4: out = resid + sc*(acc + bias[n]), sc = scales[b*3]
//           EPI 5: out = resid + acc + bias[b*512+n]   (bias_eff 2D)
template <int ORIENT, int EPI>
__global__ __launch_bounds__(256) void mgemm_k(const ushort* __restrict__ X,
                                               const ushort* __restrict__ Wt,
                                               const float* __restrict__ bias,
                                               const float* __restrict__ resid,
                                               const float* __restrict__ scales,
                                               void* __restrict__ OutV,
                                               int Ks, int Nreal, int Nstore) {
  const int bid = blockIdx.x;
  const int xcd = bid & 7;
  const int i = bid >> 3;
  const int mt_local = i % 14;
  const int nt = i / 14;
  const int m0 = (xcd * 14 + mt_local) * 112;
  const int n0 = nt * 128;
  const int bb = m0 / NPIX;
  const int t = threadIdx.x;
  const int w = t >> 6, lane = t & 63, c = lane & 15, g = lane >> 4;
  __shared__ ushort Xs[7168];
  __shared__ ushort Ws[8192];
  f32x4 acc[7][2];
  #pragma unroll
  for (int mi = 0; mi < 7; ++mi)
    #pragma unroll
    for (int ni = 0; ni < 2; ++ni) acc[mi][ni] = (f32x4){0.f, 0.f, 0.f, 0.f};

  for (int k0 = 0; k0 < Ks; k0 += 64) {
    for (int ii = t; ii < 896; ii += 256) {
      int m = ii >> 3, kg = ii & 7;
      uint4 v = *(const uint4*)(X + (size_t)(m0 + m) * Ks + k0 + kg * 8);
      *(uint4*)&Xs[m * 64 + ((kg ^ (m & 7)) << 3)] = v;
    }
    for (int ii = t; ii < 1024; ii += 256) {
      int n = ii >> 3, kg = ii & 7;
      uint4 v = {0u, 0u, 0u, 0u};
      if (n0 + n < Nreal) v = *(const uint4*)(Wt + (size_t)(n0 + n) * Ks + k0 + kg * 8);
      *(uint4*)&Ws[n * 64 + ((kg ^ (n & 7)) << 3)] = v;
    }
    __syncthreads();
    #pragma unroll
    for (int kc = 0; kc < 2; ++kc) {
      bf16x8 xf[7], wf[2];
      #pragma unroll
      for (int mi = 0; mi < 7; ++mi) {
        int m = mi * 16 + c;
        xf[mi] = *(const bf16x8*)&Xs[m * 64 + (((kc * 4 + g) ^ (m & 7)) << 3)];
      }
      #pragma unroll
      for (int ni = 0; ni < 2; ++ni) {
        int n = w * 32 + ni * 16 + c;
        wf[ni] = *(const bf16x8*)&Ws[n * 64 + (((kc * 4 + g) ^ (n & 7)) << 3)];
      }
      #pragma unroll
      for (int mi = 0; mi < 7; ++mi)
        #pragma unroll
        for (int ni = 0; ni < 2; ++ni)
          acc[mi][ni] = (ORIENT == 0)
            ? __builtin_amdgcn_mfma_f32_16x16x32_bf16(wf[ni], xf[mi], acc[mi][ni], 0, 0, 0)
            : __builtin_amdgcn_mfma_f32_16x16x32_bf16(xf[mi], wf[ni], acc[mi][ni], 0, 0, 0);
    }
    __syncthreads();
  }

  if (ORIENT == 0) {
    ushort* Ob = (ushort*)OutV;
    const int nbq = n0 + w * 32;
    float bi[2][4];
    #pragma unroll
    for (int ni = 0; ni < 2; ++ni)
      #pragma unroll
      for (int j = 0; j < 4; ++j) {
        int n = nbq + ni * 16 + g * 4 + j;
        bi[ni][j] = (n < Nreal) ? bias[n] : 0.f;
      }
    #pragma unroll
    for (int mi = 0; mi < 7; ++mi) {
      int m = m0 + mi * 16 + c;
      #pragma unroll
      for (int ni = 0; ni < 2; ++ni) {
        int nb = nbq + ni * 16 + g * 4;
        if (nb >= Nstore) continue;
        float v[4];
        #pragma unroll
        for (int j = 0; j < 4; ++j) v[j] = acc[mi][ni][j] + bi[ni][j];
        if (EPI == 1) {
          #pragma unroll
          for (int j = 0; j < 4; ++j) v[j] = fmaxf(v[j], 0.f);
        } else if (EPI == 2) {
          #pragma unroll
          for (int j = 0; j < 4; ++j)
            v[j] = 0.5f * v[j] * (1.f + erff(v[j] * 0.70710678118654752f));
        } else if (EPI == 3) {
          uint2 cm = *(const uint2*)&Ob[(size_t)m * Nstore + nb];
          float cf[4];
          unpack4bf(cm, cf);
          #pragma unroll
          for (int j = 0; j < 4; ++j)
            v[j] = (1.f / (1.f + __expf(-v[j]))) * cf[j];
        } else if (EPI == 5) {
          int e = nb / 704; e = (e > 2) ? 2 : e;
          float sc = scales[bb * 3 + e];
          #pragma unroll
          for (int j = 0; j < 4; ++j)
            v[j] = 0.5f * v[j] * (1.f + erff(v[j] * 0.70710678118654752f)) * sc;
        }
        uint2 o = {pack2bf(v[0], v[1]), pack2bf(v[2], v[3])};
        *(uint2*)&Ob[(size_t)m * Nstore + nb] = o;
      }
    }
  } else {
    const int prow = m0 - bb * NPIX;
    float* Ob = (float*)OutV + (size_t)bb * CDIM * NPIX;
    const float* Rb = resid + (size_t)bb * CDIM * NPIX;
    float sc = (EPI == 4 && scales) ? scales[bb * 3] : 1.f;
    #pragma unroll
    for (int ni = 0; ni < 2; ++ni) {
      int n = n0 + w * 32 + ni * 16 + c;
      float bv = (EPI == 5) ? bias[(size_t)bb * CDIM + n] : bias[n];
      #pragma unroll
      for (int mi = 0; mi < 7; ++mi) {
        int p = prow + mi * 16 + g * 4;
        size_t off = (size_t)n * NPIX + p;
        float4 r = *(const float4*)&Rb[off];
        f32x4 a = acc[mi][ni];
        float4 o = {r.x + sc * (a[0] + bv), r.y + sc * (a[1] + bv),
                    r.z + sc * (a[2] + bv), r.w + sc * (a[3] + bv)};
        *(float4*)&Ob[off] = o;
      }
    }
  }
}

// ---------------------------------------------------------------------------
// transpose V out of qkvbf:  [b][p][1024+c] bf16 -> vbf [b][c][784] bf16
__global__ __launch_bounds__(256) void vtr_k(const ushort* __restrict__ qkvbf,
                                             ushort* __restrict__ vbf) {
  const int p0 = blockIdx.x * 64, c0 = blockIdx.y * 64, b = blockIdx.z;
  __shared__ ushort T[64][72];
  for (int idx = threadIdx.x; idx < 512; idx += 256) {
    int pl = idx >> 3, cq = idx & 7;
    int p = p0 + pl;
    uint4 v = {0u, 0u, 0u, 0u};
    if (p < NPIX)
      v = *(const uint4*)(qkvbf + (size_t)(b * NPIX + p) * C3 + 1024 + c0 + cq * 8);
    *(uint4*)&T[pl][cq * 8] = v;
  }
  __syncthreads();
  for (int idx = threadIdx.x; idx < 512; idx += 256) {
    int cl = idx >> 3, pq = idx & 7;
    if (p0 + pq * 8 < NPIX) {
      ushort tmp[8];
      #pragma unroll
      for (int i = 0; i < 8; ++i) tmp[i] = T[pq * 8 + i][cl];
      *(uint4*)(vbf + ((size_t)(b * CDIM + c0 + cl)) * NPIX + p0 + pq * 8) =
          *(const uint4*)&tmp[0];
    }
  }
}

// f32 ch-major -> bf16 pixel-major (x3 -> x3bf)
__global__ __launch_bounds__(256) void tr_cvt_k(const float* __restrict__ src,
                                                ushort* __restrict__ dst) {
  const int p0 = blockIdx.x * 64, c0 = blockIdx.y * 64, b = blockIdx.z;
  __shared__ ushort T[64][72];
  const float* sb = src + (size_t)b * CDIM * NPIX;
  for (int idx = threadIdx.x; idx < 4096; idx += 256) {
    int ci = idx >> 6, pj = idx & 63;
    int p = p0 + pj;
    T[pj][ci] = (p < NPIX) ? f2bf(sb[(size_t)(c0 + ci) * NPIX + p]) : (ushort)0;
  }
  __syncthreads();
  for (int idx = threadIdx.x; idx < 512; idx += 256) {
    int pj = idx >> 3, cq = idx & 7;
    int p = p0 + pj;
    if (p < NPIX) {
      uint4 v = *(const uint4*)&T[pj][cq * 8];
      *(uint4*)(dst + ((size_t)(b * NPIX + p)) * CDIM + c0 + cq * 8) = v;
    }
  }
}

// ---------------------------------------------------------------------------
// MFMA flash attention: 32 q rows / wave (2 chunks), shared K/V frags,
// bf16 pre-folded biases, online softmax w/ defer-max, wave-autonomous.
// XCD-aware: batch b = (bid&7) + 8*(i/56).
__global__ __launch_bounds__(256) void attn_mfma_k(const ushort* __restrict__ qkvbf,
                                                   const ushort* __restrict__ vbf,
                                                   const ushort* __restrict__ sprpb,
                                                   const ushort* __restrict__ fpb,
                                                   ushort* __restrict__ obf) {
  const int bid = blockIdx.x;
  const int xcd = bid & 7;
  const int i = bid >> 3;
  const int b = xcd + 8 * (i / 56);
  const int r = i % 56;
  const int h = r & 7;
  const int qt = r >> 3;
  const int w = threadIdx.x >> 6, lane = threadIdx.x & 63;
  const int g = lane >> 4, c = lane & 15;
  const int q0 = qt * 128 + w * 32;
  if (q0 >= NPIX) return;
  const bool hasB = (q0 + 16) < NPIX;
  const int qA = q0 + c;
  const int qB = q0 + 16 + c;

  __shared__ uint BL[4][2][384];
  uint* bwA = BL[w][0];
  uint* bwB = BL[w][1];

  const ushort* qpA = qkvbf + (size_t)(b * NPIX + qA) * C3 + h * 64 + g * 8;
  const bf16x8 qfA0 = *(const bf16x8*)qpA;
  const bf16x8 qfA1 = *(const bf16x8*)(qpA + 32);
  bf16x8 qfB0 = qfA0, qfB1 = qfA1;
  if (hasB) {
    const ushort* qpB = qkvbf + (size_t)(b * NPIX + qB) * C3 + h * 64 + g * 8;
    qfB0 = *(const bf16x8*)qpB;
    qfB1 = *(const bf16x8*)(qpB + 32);
  }

  const ushort* kbase = qkvbf + (size_t)b * NPIX * C3 + 512 + h * 64 + g * 8;
  const ushort* vbase = vbf + ((size_t)b * CDIM + h * 64) * NPIX;
  const ushort* sprA = sprpb + ((size_t)h * NPIX + qA) * NPIX;
  const ushort* sprB = sprpb + ((size_t)h * NPIX + (hasB ? qB : qA)) * NPIX;
  const ushort* fpA = fpb + ((size_t)b * NPIX + qA) * NPIX;
  const ushort* fpB = fpb + ((size_t)b * NPIX + (hasB ? qB : qA)) * NPIX;

  f32x4 oA0 = {0.f, 0.f, 0.f, 0.f}, oA1 = oA0, oA2 = oA0, oA3 = oA0;
  f32x4 oB0 = oA0, oB1 = oA0, oB2 = oA0, oB3 = oA0;
  float MA = -1e30f, LA = 0.f, MB = -1e30f, LB = 0.f;

  for (int ms = 0; ms < 25; ++ms) {
    const int m0 = ms * 32;
    const bool full = (ms < 24);

    const ushort* kp = kbase + (size_t)(m0 + c) * C3;
    bf16x8 ka0 = *(const bf16x8*)kp;
    bf16x8 ka1 = *(const bf16x8*)(kp + 32);
    bf16x8 kb0 = ka0, kb1 = ka1;
    if (full) {
      const ushort* kp1 = kp + (size_t)16 * C3;
      kb0 = *(const bf16x8*)kp1;
      kb1 = *(const bf16x8*)(kp1 + 32);
    }

    // ---- chunk A ----
    f32x4 sA0 = {0.f, 0.f, 0.f, 0.f}, sA1 = sA0;
    sA0 = __builtin_amdgcn_mfma_f32_16x16x32_bf16(ka0, qfA0, sA0, 0, 0, 0);
    sA0 = __builtin_amdgcn_mfma_f32_16x16x32_bf16(ka1, qfA1, sA0, 0, 0, 0);
    if (full) {
      sA1 = __builtin_amdgcn_mfma_f32_16x16x32_bf16(kb0, qfA0, sA1, 0, 0, 0);
      sA1 = __builtin_amdgcn_mfma_f32_16x16x32_bf16(kb1, qfA1, sA1, 0, 0, 0);
    }

    float vA0[4], vA1[4];
    {
      float spv[4], fpv[4];
      unpack4bf(*(const uint2*)(sprA + m0 + g * 4), spv);
      unpack4bf(*(const uint2*)(fpA + m0 + g * 4), fpv);
      #pragma unroll
      for (int j = 0; j < 4; ++j) vA0[j] = fmaf(sA0[j], 0.125f, spv[j]) * fpv[j];
      if (full) {
        unpack4bf(*(const uint2*)(sprA + m0 + 16 + g * 4), spv);
        unpack4bf(*(const uint2*)(fpA + m0 + 16 + g * 4), fpv);
        #pragma unroll
        for (int j = 0; j < 4; ++j) vA1[j] = fmaf(sA1[j], 0.125f, spv[j]) * fpv[j];
      }
    }
    {
      float tm = fmaxf(fmaxf(vA0[0], vA0[1]), fmaxf(vA0[2], vA0[3]));
      if (full) tm = fmaxf(tm, fmaxf(fmaxf(vA1[0], vA1[1]), fmaxf(vA1[2], vA1[3])));
      tm = fmaxf(tm, __shfl_xor(tm, 16));
      tm = fmaxf(tm, __shfl_xor(tm, 32));
      if (__any(tm > MA)) {               // defer-max: skip rescale when max flat
        const float nM = fmaxf(MA, tm);
        const float fac = __expf(MA - nM);
        LA *= fac;
        #pragma unroll
        for (int j = 0; j < 4; ++j) { oA0[j] *= fac; oA1[j] *= fac; oA2[j] *= fac; oA3[j] *= fac; }
        MA = nM;
      }
      float p0v[4], p1v[4];
      float ps = 0.f;
      #pragma unroll
      for (int j = 0; j < 4; ++j) { p0v[j] = __expf(vA0[j] - MA); ps += p0v[j]; }
      if (full) {
        #pragma unroll
        for (int j = 0; j < 4; ++j) { p1v[j] = __expf(vA1[j] - MA); ps += p1v[j]; }
      }
      ps += __shfl_xor(ps, 16);
      ps += __shfl_xor(ps, 32);
      LA += ps;
      uint2 wlo, whi;
      wlo.x = pack2bf(p0v[0], p0v[1]);
      wlo.y = pack2bf(p0v[2], p0v[3]);
      whi.x = full ? pack2bf(p1v[0], p1v[1]) : 0u;
      whi.y = full ? pack2bf(p1v[2], p1v[3]) : 0u;
      *(uint2*)&bwA[lane * 6] = wlo;
      *(uint2*)&bwA[lane * 6 + 2] = whi;
    }

    // ---- chunk B ----
    if (hasB) {
      f32x4 sB0 = {0.f, 0.f, 0.f, 0.f}, sB1 = sB0;
      sB0 = __builtin_amdgcn_mfma_f32_16x16x32_bf16(ka0, qfB0, sB0, 0, 0, 0);
      sB0 = __builtin_amdgcn_mfma_f32_16x16x32_bf16(ka1, qfB1, sB0, 0, 0, 0);
      if (full) {
        sB1 = __builtin_amdgcn_mfma_f32_16x16x32_bf16(kb0, qfB0, sB1, 0, 0, 0);
        sB1 = __builtin_amdgcn_mfma_f32_16x16x32_bf16(kb1, qfB1, sB1, 0, 0, 0);
      }
      float vB0[4], vB1[4];
      {
        float spv[4], fpv[4];
        unpack4bf(*(const uint2*)(sprB + m0 + g * 4), spv);
        unpack4bf(*(const uint2*)(fpB + m0 + g * 4), fpv);
        #pragma unroll
        for (int j = 0; j < 4; ++j) vB0[j] = fmaf(sB0[j], 0.125f, spv[j]) * fpv[j];
        if (full) {
          unpack4bf(*(const uint2*)(sprB + m0 + 16 + g * 4), spv);
          unpack4bf(*(const uint2*)(fpB + m0 + 16 + g * 4), fpv);
          #pragma unroll
          for (int j = 0; j < 4; ++j) vB1[j] = fmaf(sB1[j], 0.125f, spv[j]) * fpv[j];
        }
      }
      float tm = fmaxf(fmaxf(vB0[0], vB0[1]), fmaxf(vB0[2], vB0[3]));
      if (full) tm = fmaxf(tm, fmaxf(fmaxf(vB1[0], vB1[1]), fmaxf(vB1[2], vB1[3])));
      tm = fmaxf(tm, __shfl_xor(tm, 16));
      tm = fmaxf(tm, __shfl_xor(tm, 32));
      if (__any(tm > MB)) {
        const float nM = fmaxf(MB, tm);
        const float fac = __expf(MB - nM);
        LB *= fac;
        #pragma unroll
        for (int j = 0; j < 4; ++j) { oB0[j] *= fac; oB1[j] *= fac; oB2[j] *= fac; oB3[j] *= fac; }
        MB = nM;
      }
      float p0v[4], p1v[4];
      float ps = 0.f;
      #pragma unroll
      for (int j = 0; j < 4; ++j) { p0v[j] = __expf(vB0[j] - MB); ps += p0v[j]; }
      if (full) {
        #pragma unroll
        for (int j = 0; j < 4; ++j) { p1v[j] = __expf(vB1[j] - MB); ps += p1v[j]; }
      }
      ps += __shfl_xor(ps, 16);
      ps += __shfl_xor(ps, 32);
      LB += ps;
      uint2 wlo, whi;
      wlo.x = pack2bf(p0v[0], p0v[1]);
      wlo.y = pack2bf(p0v[2], p0v[3]);
      whi.x = full ? pack2bf(p1v[0], p1v[1]) : 0u;
      whi.y = full ? pack2bf(p1v[2], p1v[3]) : 0u;
      *(uint2*)&bwB[lane * 6] = wlo;
      *(uint2*)&bwB[lane * 6 + 2] = whi;
    }

    // ---- V fragments (shared) + PV for both chunks ----
    const int f = g >> 1;
    const int slo = 32 * (g & 1) + c;
    uint2 blo = *(const uint2*)&bwA[slo * 6 + f * 2];
    uint2 bhi = *(const uint2*)&bwA[(slo + 16) * 6 + f * 2];
    uint4 bba = {blo.x, blo.y, bhi.x, bhi.y};
    const bf16x8 pfA = __builtin_bit_cast(bf16x8, bba);

    const ushort* vp = vbase + (size_t)c * NPIX + m0 + g * 8;
    bf16x8 vf0 = *(const bf16x8*)(vp);
    bf16x8 vf1 = *(const bf16x8*)(vp + (size_t)16 * NPIX);
    bf16x8 vf2 = *(const bf16x8*)(vp + (size_t)32 * NPIX);
    bf16x8 vf3 = *(const bf16x8*)(vp + (size_t)48 * NPIX);
    oA0 = __builtin_amdgcn_mfma_f32_16x16x32_bf16(vf0, pfA, oA0, 0, 0, 0);
    oA1 = __builtin_amdgcn_mfma_f32_16x16x32_bf16(vf1, pfA, oA1, 0, 0, 0);
    oA2 = __builtin_amdgcn_mfma_f32_16x16x32_bf16(vf2, pfA, oA2, 0, 0, 0);
    oA3 = __builtin_amdgcn_mfma_f32_16x16x32_bf16(vf3, pfA, oA3, 0, 0, 0);
    if (hasB) {
      uint2 clo = *(const uint2*)&bwB[slo * 6 + f * 2];
      uint2 chi = *(const uint2*)&bwB[(slo + 16) * 6 + f * 2];
      uint4 bbb = {clo.x, clo.y, chi.x, chi.y};
      const bf16x8 pfB = __builtin_bit_cast(bf16x8, bbb);
      oB0 = __builtin_amdgcn_mfma_f32_16x16x32_bf16(vf0, pfB, oB0, 0, 0, 0);
      oB1 = __builtin_amdgcn_mfma_f32_16x16x32_bf16(vf1, pfB, oB1, 0, 0, 0);
      oB2 = __builtin_amdgcn_mfma_f32_16x16x32_bf16(vf2, pfB, oB2, 0, 0, 0);
      oB3 = __builtin_amdgcn_mfma_f32_16x16x32_bf16(vf3, pfB, oB3, 0, 0, 0);
    }
  }

  {
    const float invL = 1.f / LA;
    ushort* dst = obf + (size_t)(b * NPIX + qA) * CDIM + h * 64 + g * 4;
    f32x4 ot[4] = {oA0, oA1, oA2, oA3};
    #pragma unroll
    for (int t2 = 0; t2 < 4; ++t2) {
      uint2 o = {pack2bf(ot[t2][0] * invL, ot[t2][1] * invL),
                 pack2bf(ot[t2][2] * invL, ot[t2][3] * invL)};
      *(uint2*)(dst + t2 * 16) = o;
    }
  }
  if (hasB) {
    const float invL = 1.f / LB;
    ushort* dst = obf + (size_t)(b * NPIX + qB) * CDIM + h * 64 + g * 4;
    f32x4 ot[4] = {oB0, oB1, oB2, oB3};
    #pragma unroll
    for (int t2 = 0; t2 < 4; ++t2) {
      uint2 o = {pack2bf(ot[t2][0] * invL, ot[t2][1] * invL),
                 pack2bf(ot[t2][2] * invL, ot[t2][3] * invL)};
      *(uint2*)(dst + t2 * 16) = o;
    }
  }
}

// ---------------------------------------------------------------------------
// Sliding-window fused LN2 + depthwise conv (3x3/5x5/7x7) -> cat pm bf16.
__device__ __forceinline__ float bf2f_s(ushort u) { return bf2f(u); }

template <int R>
__device__ __forceinline__ void conv_pass(const ushort* __restrict__ plane_ci,
                                          const float* __restrict__ wl_ci,
                                          float bv, int slot,
                                          ushort (*__restrict__ outb)[16], int ci) {
  constexpr int K = 2 * R + 1;
  float wreg[K * K];
  #pragma unroll
  for (int i = 0; i < K * K; ++i) wreg[i] = wl_ci[i];
  #pragma unroll
  for (int r7 = 0; r7 < 7; ++r7) {
    const int run = slot + r7 * 16;
    const int y = run >> 2, x0 = (run & 3) * 7;
    float acc[7];
    #pragma unroll
    for (int i = 0; i < 7; ++i) acc[i] = bv;
    #pragma unroll
    for (int dy = 0; dy < K; ++dy) {
      const ushort* rp = plane_ci + (y + 3 - R + dy) * 34 + (x0 + 3 - R);
      float win[7 + 2 * R];
      #pragma unroll
      for (int k = 0; k < 7 + 2 * R; ++k) win[k] = bf2f_s(rp[k]);
      #pragma unroll
      for (int i = 0; i < 7; ++i)
        #pragma unroll
        for (int k = 0; k < K; ++k)
          acc[i] = fmaf(win[i + k], wreg[dy * K + k], acc[i]);
    }
    #pragma unroll
    for (int i = 0; i < 7; ++i) outb[y * 28 + x0 + i][ci] = f2bf(acc[i]);
  }
}

__global__ __launch_bounds__(256) void dwln_k(const float* __restrict__ x2,
    const float* __restrict__ ust, const float* __restrict__ rst,
    const float* __restrict__ ad, const float* __restrict__ n2w,
    const float* __restrict__ n2b,
    const float* __restrict__ ew, const float* __restrict__ eb,
    const float* __restrict__ nw, const float* __restrict__ nb,
    const float* __restrict__ mw, const float* __restrict__ mb,
    ushort* __restrict__ cat) {
  const int cg = blockIdx.x, b = blockIdx.y;
  const int c0 = cg * 16;
  const int t = threadIdx.x;
  const int ci = t & 15, slot = t >> 4;

  __shared__ ushort plane[16][1156];
  __shared__ ushort outb[784][16];
  __shared__ float Wl[16 * 49];
  __shared__ float LWs[16], LBs[16];

  {
    uint* pz = (uint*)&plane[0][0];
    for (int i = t; i < 16 * 1156 / 2; i += 256) pz[i] = 0u;
  }
  if (t < 16) {
    int cc = c0 + t;
    float aw = ad[b * 1024 + cc], ab = ad[b * 1024 + 512 + cc];
    LWs[t] = n2w[cc] * (1.f + aw);
    LBs[t] = n2b[cc] + ab;
  }
  __syncthreads();

  {
    float uu[4], rr[4];
    #pragma unroll
    for (int j = 0; j < 4; ++j) {
      int p = t + j * 256;
      if (p < NPIX) {
        uu[j] = ust[(size_t)b * NPIX + p];
        rr[j] = rst[(size_t)b * NPIX + p];
      }
    }
    for (int cc = 0; cc < 16; ++cc) {
      const float* xp = x2 + ((size_t)(b * CDIM + c0 + cc)) * NPIX;
      float lw = LWs[cc], lb = LBs[cc];
      #pragma unroll
      for (int j = 0; j < 4; ++j) {
        int p = t + j * 256;
        if (p < NPIX) {
          int y = p / 28, xx2 = p - y * 28;
          plane[cc][(y + 3) * 34 + xx2 + 3] = f2bf(lw * (xp[p] - uu[j]) * rr[j] + lb);
        }
      }
    }
  }
  __syncthreads();

  #pragma unroll 1
  for (int cv = 0; cv < 3; ++cv) {
    const float* gw = (cv == 0) ? ew : (cv == 1) ? nw : mw;
    const float* gb = (cv == 0) ? eb : (cv == 1) ? nb : mb;
    const int K2 = (cv == 0) ? 9 : (cv == 1) ? 25 : 49;
    for (int i = t; i < 16 * K2; i += 256) {
      int cc = i / K2, k = i - cc * K2;
      Wl[cc * K2 + k] = gw[(size_t)(c0 + cc) * K2 + k];
    }
    __syncthreads();
    float bv = gb[c0 + ci];
    if (cv == 0)      conv_pass<1>(&plane[ci][0], &Wl[ci * 9],  bv, slot, outb, ci);
    else if (cv == 1) conv_pass<2>(&plane[ci][0], &Wl[ci * 25], bv, slot, outb, ci);
    else              conv_pass<3>(&plane[ci][0], &Wl[ci * 49], bv, slot, outb, ci);
    __syncthreads();
    for (int idx = t; idx < NPIX * 2; idx += 256) {
      int p = idx >> 1, half = idx & 1;
      uint4 v = *(const uint4*)&outb[p][half * 8];
      *(uint4*)(cat + ((size_t)(b * NPIX + p)) * C3 + cv * 512 + c0 + half * 8) = v;
    }
    __syncthreads();
  }
}

// ---------------------------------------------------------------------------
__global__ __launch_bounds__(64) void router_k(const float* __restrict__ pooled,
                                               const float* __restrict__ rw,
                                               const float* __restrict__ rb,
                                               float* __restrict__ r) {
  int b = blockIdx.x, lane = threadIdx.x;
  float a0 = 0.f, a1 = 0.f, a2 = 0.f;
  for (int k = lane; k < CDIM; k += 64) {
    float p = pooled[b * CDIM + k];
    a0 += rw[k] * p;
    a1 += rw[CDIM + k] * p;
    a2 += rw[2 * CDIM + k] * p;
  }
  #pragma unroll
  for (int off = 32; off; off >>= 1) {
    a0 += __shfl_down(a0, off);
    a1 += __shfl_down(a1, off);
    a2 += __shfl_down(a2, off);
  }
  if (lane == 0) {
    float l0 = a0 + rb[0], l1 = a1 + rb[1], l2 = a2 + rb[2];
    float mx = fmaxf(l0, fmaxf(l1, l2));
    float e0 = __expf(l0 - mx), e1 = __expf(l1 - mx), e2 = __expf(l2 - mx);
    float inv = 1.f / (e0 + e1 + e2);
    r[b * 3 + 0] = e0 * inv;
    r[b * 3 + 1] = e1 * inv;
    r[b * 3 + 2] = e2 * inv;
  }
}

// ---------------------------------------------------------------------------
extern "C" void kernel_launch(void* const* d_in, const int* in_sizes, int n_in,
                              void* d_out, int out_size, void* d_ws, size_t ws_size,
                              hipStream_t stream) {
  (void)in_sizes; (void)n_in; (void)out_size; (void)ws_size;
  const float* x         = (const float*)d_in[0];
  const float* fpri      = (const float*)d_in[1];
  const float* n1_w      = (const float*)d_in[2];
  const float* n1_b      = (const float*)d_in[3];
  const float* n1_a1w    = (const float*)d_in[4];
  const float* n1_a1b    = (const float*)d_in[5];
  const float* n1_a2w    = (const float*)d_in[6];
  const float* n1_a2b    = (const float*)d_in[7];
  const float* n2_w      = (const float*)d_in[8];
  const float* n2_b      = (const float*)d_in[9];
  const float* n2_a1w    = (const float*)d_in[10];
  const float* n2_a1b    = (const float*)d_in[11];
  const float* n2_a2w    = (const float*)d_in[12];
  const float* n2_a2b    = (const float*)d_in[13];
  const float* qkv_w     = (const float*)d_in[14];
  const float* qkv_b     = (const float*)d_in[15];
  const float* rpb_table = (const float*)d_in[16];
  const float* sprior    = (const float*)d_in[17];
  const float* proj_w    = (const float*)d_in[18];
  const float* proj_b    = (const float*)d_in[19];
  const float* eye_w     = (const float*)d_in[20];
  const float* eye_b     = (const float*)d_in[21];
  const float* nose_w    = (const float*)d_in[22];
  const float* nose_b    = (const float*)d_in[23];
  const float* mouth_w   = (const float*)d_in[24];
  const float* mouth_b   = (const float*)d_in[25];
  const float* fusion_w  = (const float*)d_in[26];
  const float* fusion_b  = (const float*)d_in[27];
  const float* gate1_w   = (const float*)d_in[28];
  const float* gate1_b   = (const float*)d_in[29];
  const float* gate2_w   = (const float*)d_in[30];
  const float* gate2_b   = (const float*)d_in[31];
  const float* e1w[3] = {(const float*)d_in[32], (const float*)d_in[36], (const float*)d_in[40]};
  const float* e1b[3] = {(const float*)d_in[33], (const float*)d_in[37], (const float*)d_in[41]};
  const float* e2w[3] = {(const float*)d_in[34], (const float*)d_in[38], (const float*)d_in[42]};
  const float* e2b[3] = {(const float*)d_in[35], (const float*)d_in[39], (const float*)d_in[43]};
  const float* router_w  = (const float*)d_in[44];
  const float* router_b  = (const float*)d_in[45];

  float* ws    = (float*)d_ws;
  ushort* xpm  = (ushort*)(ws + OFF_XPM);   // xa / xn2 -> x3bf (MoE)
  ushort* wb   = (ushort*)(ws + OFF_W);
  ushort* r2u  = (ushort*)(ws + OFF_R2);    // qkvbf -> catpm -> he (spans R2+VBF+OBF)
  ushort* vbf  = (ushort*)(ws + OFF_VBF);
  ushort* obf  = (ushort*)(ws + OFF_OBF);   // attn O -> g1bf
  float* x2    = ws + OFF_X2;
  float* x3    = ws + OFF_X3;
  float* pld   = ws + OFF_PL;
  float* adb   = ws + OFF_AD;               // adapt out -> be + e1bcat
  float* rbuf  = ws + OFF_RB;
  float* ust   = ws + OFF_US;
  float* rst   = ws + OFF_RS;
  float* outp  = (float*)d_out;

  ushort* qkvw  = wb + WOFF_QKV;
  ushort* projw = wb + WOFF_PROJ;
  ushort* g1w   = wb + WOFF_G1;
  ushort* g2w   = wb + WOFF_G2;
  ushort* fusw  = wb + WOFF_FUS;
  ushort* e1cat = wb + WOFF_E1;             // [2112][512]
  ushort* e2cat = (ushort*)(ws + OFF_E2C);  // [512][2112]
  float* be     = adb;                      // [16][512]
  float* e1bcat = adb + 8192;               // [2112]

  // attention bias buffers alias the (still-dead) x2/x3 regions
  ushort* fpbf   = (ushort*)x2;
  ushort* sprpbf = (ushort*)x3;

  // --- weight conversion + expert stacking (704-aligned) ---
  CvtDesc D;
  auto seg = [&](int s2, const float* src, ushort* dst, int rows, int sk, int dk,
                 int ds, int rr) {
    D.s[s2] = src; D.d[s2] = dst; D.rows[s2] = rows; D.sk[s2] = sk;
    D.dk[s2] = dk; D.ds[s2] = ds; D.rr[s2] = rr;
  };
  seg(0, qkv_w,    qkvw,  1536, 512,  512,  512,  1536);
  seg(1, proj_w,   projw, 512,  512,  512,  512,  512);
  seg(2, gate1_w,  g1w,   128,  512,  512,  512,  128);
  seg(3, gate2_w,  g2w,   1536, 128,  128,  128,  1536);
  seg(4, fusion_w, fusw,  512,  1536, 1536, 1536, 512);
  for (int e = 0; e < 3; ++e) {
    seg(5 + e, e1w[e], e1cat + (size_t)e * 704 * 512, 704, 512, 512, 512, 682);
    seg(8 + e, e2w[e], e2cat + (size_t)e * 704,       512, 682, 704, 2112, 512);
  }
  cvt_w_k<<<dim3(512, 11), 256, 0, stream>>>(D);

  // --- attention bias prep ---
  sprpb_k<<<dim3(NPIX, NHEAD), 256, 0, stream>>>(sprior, rpb_table, sprpbf);
  fpcvt_k<<<9604, 256, 0, stream>>>(fpri, fpbf);

  // --- LN1 ---
  pool_mean_k<<<dim3(CDIM, 16), 64, 0, stream>>>(x, pld);
  adapt_mlp_k<<<16, 256, 0, stream>>>(pld, n1_a1w, n1_a1b, n1_a2w, n1_a2b, adb);
  ln_pm_k<0><<<dim3(25, 16), 256, 0, stream>>>(x, n1_w, n1_b, adb, xpm, nullptr, nullptr);

  // --- attention ---
  mgemm_k<0, 0><<<1344, 256, 0, stream>>>(xpm, qkvw, qkv_b, nullptr, nullptr,
                                          r2u, 512, 1536, 1536);
  vtr_k<<<dim3(13, 8, 16), 256, 0, stream>>>(r2u, vbf);
  attn_mfma_k<<<896, 256, 0, stream>>>(r2u, vbf, sprpbf, fpbf, obf);
  mgemm_k<1, 4><<<448, 256, 0, stream>>>(obf, projw, proj_b, x, nullptr,
                                         x2, 512, 512, 512);

  // --- LN2 + token mixer ---
  pool_mean_k<<<dim3(CDIM, 16), 64, 0, stream>>>(x2, pld);
  adapt_mlp_k<<<16, 256, 0, stream>>>(pld, n2_a1w, n2_a1b, n2_a2w, n2_a2b, adb);
  ln_pm_k<1><<<dim3(25, 16), 256, 0, stream>>>(x2, n2_w, n2_b, adb, xpm, ust, rst);
  dwln_k<<<dim3(32, 16), 256, 0, stream>>>(x2, ust, rst, adb, n2_w, n2_b,
                                           eye_w, eye_b, nose_w, nose_b, mouth_w, mouth_b,
                                           r2u);
  mgemm_k<0, 1><<<112, 256, 0, stream>>>(xpm, g1w, gate1_b, nullptr, nullptr,
                                         obf, 512, 128, 128);
  mgemm_k<0, 3><<<1344, 256, 0, stream>>>(obf, g2w, gate2_b, nullptr, nullptr,
                                          r2u, 128, 1536, 1536);
  mgemm_k<1, 4><<<448, 256, 0, stream>>>(r2u, fusw, fusion_b, x2, nullptr,
                                         x3, 1536, 512, 512);

  // --- MoE (fused: 2 stacked GEMMs) ---
  tr_cvt_k<<<dim3(13, 8, 16), 256, 0, stream>>>(x3, xpm);   // x3bf -> xpm region
  pool_mean_k<<<dim3(CDIM, 16), 64, 0, stream>>>(x3, pld);
  router_k<<<16, 64, 0, stream>>>(pld, router_w, router_b, rbuf);
  biaseff_k<<<17, 512, 0, stream>>>(rbuf, e2b[0], e2b[1], e2b[2],
                                    e1b[0], e1b[1], e1b[2], be, e1bcat);
  // he[m][2112] = r_e * gelu(x3bf @ e1cat^T + e1bcat)   (he at r2u base)
  mgemm_k<0, 5><<<1904, 256, 0, stream>>>(xpm, e1cat, e1bcat, nullptr, rbuf,
                                          r2u, 512, 2112, 2112);
  // out = x3 + he @ e2cat^T + be[b]
  mgemm_k<1, 5><<<448, 256, 0, stream>>>(r2u, e2cat, be, x3, nullptr,
                                         outp, 2112, 512, 512);
}

// Round 8
// 787.722 us; speedup vs baseline: 3.7586x; 1.0367x over previous
//
#include <hip/hip_runtime.h>
#include <math.h>

// ---------------------------------------------------------------------------
// EfficientFaceTransformer forward — round 8: attn register software-pipeline,
// pool fused into GEMM epilogues (atomics), fusion dual-writes x3bf.
// ---------------------------------------------------------------------------

#define NPIX 784
#define CDIM 512
#define NHEAD 8
#define C3 1536

typedef unsigned int uint;
typedef unsigned short ushort;
typedef float f32x4 __attribute__((ext_vector_type(4)));
typedef __bf16 bf16x8 __attribute__((ext_vector_type(8)));
typedef __bf16 bf16x2 __attribute__((ext_vector_type(2)));

// ---- workspace float offsets ----------------------------------------------
#define OFF_XPM ((size_t)0)          // pm bf16 act (xa / xn2 / x3bf)
#define OFF_W   ((size_t)3211264)    // bf16 weights
#define OFF_R2  ((size_t)5324288)    // qkvbf -> catpm -> he
#define OFF_VBF ((size_t)14958080)   // vbf (attn V)
#define OFF_OBF ((size_t)18169344)   // obf -> g1bf
#define OFF_X2  ((size_t)21380608)   // fp_bf (attn) -> x2 f32 ch-major
#define OFF_X3  ((size_t)27803136)   // sprpb_bf (attn) -> x3 f32 ch-major
#define OFF_PL  ((size_t)34225664)
#define OFF_AD  ((size_t)34233856)
#define OFF_RB  ((size_t)34250240)
#define OFF_US  ((size_t)34250288)
#define OFF_RS  ((size_t)34262832)
#define OFF_E2C ((size_t)34275392)   // e2cat bf16 [512][2112]

// weight sub-offsets (ushort units)
#define WOFF_QKV 0
#define WOFF_PROJ 786432
#define WOFF_G1  1048576
#define WOFF_G2  1114112
#define WOFF_FUS 1310720
#define WOFF_E1  2097152   /* e1cat [2112][512] stacked, 704-aligned */

__device__ __forceinline__ ushort f2bf(float f) {
  __bf16 h = (__bf16)f;
  return __builtin_bit_cast(ushort, h);
}
__device__ __forceinline__ unsigned pack2bf(float lo, float hi) {
  bf16x2 v = {(__bf16)lo, (__bf16)hi};
  return __builtin_bit_cast(unsigned, v);
}
__device__ __forceinline__ float bf2f(ushort u) {
  unsigned x = ((unsigned)u) << 16;
  return __builtin_bit_cast(float, x);
}
__device__ __forceinline__ void unpack4bf(uint2 v, float* o) {
  o[0] = bf2f((ushort)(v.x & 0xffffu)); o[1] = bf2f((ushort)(v.x >> 16));
  o[2] = bf2f((ushort)(v.y & 0xffffu)); o[3] = bf2f((ushort)(v.y >> 16));
}

// ---------------------------------------------------------------------------
// pooled[b,c] = SUM_p x[b,c,p]  (consumers apply 1/784)
__global__ __launch_bounds__(64) void pool_mean_k(const float* __restrict__ x,
                                                  float* __restrict__ pooled) {
  int c = blockIdx.x, b = blockIdx.y;
  const float* row = x + ((size_t)b * CDIM + c) * NPIX;
  float s = 0.f;
  for (int i = threadIdx.x; i < NPIX; i += 64) s += row[i];
  #pragma unroll
  for (int off = 32; off; off >>= 1) s += __shfl_down(s, off);
  if (threadIdx.x == 0) pooled[b * CDIM + c] = s;
}

// ---------------------------------------------------------------------------
__global__ __launch_bounds__(256) void adapt_mlp_k(const float* __restrict__ pooled,
                                                   const float* __restrict__ a1w,
                                                   const float* __restrict__ a1b,
                                                   const float* __restrict__ a2w,
                                                   const float* __restrict__ a2b,
                                                   float* __restrict__ ad) {
  int b = blockIdx.x, tid = threadIdx.x;
  __shared__ float pl[CDIM];
  __shared__ float hh[128];
  for (int i = tid; i < CDIM; i += 256)
    pl[i] = pooled[b * CDIM + i] * (1.f / NPIX);
  __syncthreads();
  if (tid < 128) {
    const float* w = a1w + (size_t)tid * CDIM;
    float a = a1b[tid];
    for (int k = 0; k < CDIM; ++k) a += w[k] * pl[k];
    hh[tid] = fmaxf(a, 0.f);
  }
  __syncthreads();
  for (int o = tid; o < 1024; o += 256) {
    const float* w = a2w + (size_t)o * 128;
    float a = a2b[o];
    for (int k = 0; k < 128; ++k) a += w[k] * hh[k];
    ad[b * 1024 + o] = a;
  }
}

// ---------------------------------------------------------------------------
// adaptive LN: read f32 ch-major, write bf16 pixel-major [b][p][512].
template <int STATS>
__global__ __launch_bounds__(256) void ln_pm_k(const float* __restrict__ x,
                                               const float* __restrict__ w,
                                               const float* __restrict__ bias,
                                               const float* __restrict__ ad,
                                               ushort* __restrict__ out,
                                               float* __restrict__ ust,
                                               float* __restrict__ rstp) {
  int b = blockIdx.y;
  int p0 = blockIdx.x * 32;
  int tid = threadIdx.x;
  int px = tid & 31, cg = tid >> 5;
  int p = p0 + px;
  bool valid = p < NPIX;
  const float* xb = x + (size_t)b * CDIM * NPIX;
  float s = 0.f, s2 = 0.f;
  if (valid) {
    for (int c = cg * 64; c < cg * 64 + 64; ++c) {
      float v = xb[(size_t)c * NPIX + p];
      s += v; s2 += v * v;
    }
  }
  __shared__ float rs[8][32], rq[8][32], us[32], vs[32];
  rs[cg][px] = s; rq[cg][px] = s2;
  __syncthreads();
  if (tid < 32) {
    float ts = 0.f, ts2 = 0.f;
    #pragma unroll
    for (int g = 0; g < 8; ++g) { ts += rs[g][tid]; ts2 += rq[g][tid]; }
    float u = ts * (1.f / CDIM);
    float var = ts2 * (1.f / CDIM) - u * u;
    float rv = rsqrtf(var + 1e-6f);
    us[tid] = u; vs[tid] = rv;
    if (STATS && p0 + tid < NPIX) {
      ust[(size_t)b * NPIX + p0 + tid] = u;
      rstp[(size_t)b * NPIX + p0 + tid] = rv;
    }
  }
  __syncthreads();
  if (valid) {
    float u = us[px], rv = vs[px];
    const float* aw = ad + (size_t)b * 1024;
    const float* ab = aw + CDIM;
    ushort* ob = out + ((size_t)(b * NPIX + p)) * CDIM + cg * 64;
    for (int cb = 0; cb < 64; cb += 8) {
      int c = cg * 64 + cb;
      float vv[8];
      #pragma unroll
      for (int q = 0; q < 8; ++q) {
        float v = xb[(size_t)(c + q) * NPIX + p];
        vv[q] = w[c + q] * (1.f + aw[c + q]) * ((v - u) * rv) + (bias[c + q] + ab[c + q]);
      }
      uint4 o = {pack2bf(vv[0], vv[1]), pack2bf(vv[2], vv[3]),
                 pack2bf(vv[4], vv[5]), pack2bf(vv[6], vv[7])};
      *(uint4*)(ob + cb) = o;
    }
  }
}

// ---------------------------------------------------------------------------
// weight convert fp32 -> bf16 with stacking: d[r*ds + cc], zero outside.
struct CvtDesc {
  const float* s[11];
  ushort* d[11];
  int rows[11], sk[11], dk[11], ds[11], rr[11];
};
__global__ __launch_bounds__(256) void cvt_w_k(CvtDesc D) {
  int seg = blockIdx.y;
  int sk = D.sk[seg], dk = D.dk[seg], ds = D.ds[seg], rr = D.rr[seg];
  int total = D.rows[seg] * dk;
  const float* s = D.s[seg];
  ushort* d = D.d[seg];
  for (int i = blockIdx.x * 256 + threadIdx.x; i < total; i += gridDim.x * 256) {
    int r = i / dk, cc = i - r * dk;
    d[(size_t)r * ds + cc] = (cc < sk && r < rr) ? f2bf(s[(size_t)r * sk + cc]) : (ushort)0;
  }
}

// ---------------------------------------------------------------------------
__global__ __launch_bounds__(256) void sprpb_k(const float* __restrict__ sp,
                                               const float* __restrict__ rpb,
                                               ushort* __restrict__ out) {
  const int q = blockIdx.x, h = blockIdx.y;
  const int i1 = q / 28, j1 = q - i1 * 28;
  const float* src = sp + ((size_t)h * NPIX + q) * NPIX;
  ushort* dst = out + ((size_t)h * NPIX + q) * NPIX;
  for (int m = threadIdx.x; m < NPIX; m += 256) {
    int i2 = m / 28, j2 = m - i2 * 28;
    float rv = rpb[(size_t)((i1 - i2 + 27) * 55 + (j1 - j2 + 27)) * NHEAD + h];
    dst[m] = f2bf(src[m] + rv);
  }
}

__global__ __launch_bounds__(256) void fpcvt_k(const float* __restrict__ fp,
                                               ushort* __restrict__ out) {
  size_t i = (size_t)blockIdx.x * 256 + threadIdx.x;
  float4 v = *((const float4*)fp + i);
  ushort4 o;
  o.x = f2bf(v.x); o.y = f2bf(v.y); o.z = f2bf(v.z); o.w = f2bf(v.w);
  *((ushort4*)out + i) = o;
}

// ---------------------------------------------------------------------------
__global__ __launch_bounds__(512) void biaseff_k(const float* __restrict__ rbuf,
                                                 const float* __restrict__ b0,
                                                 const float* __restrict__ b1,
                                                 const float* __restrict__ b2,
                                                 const float* __restrict__ a0,
                                                 const float* __restrict__ a1,
                                                 const float* __restrict__ a2,
                                                 float* __restrict__ be,
                                                 float* __restrict__ e1bcat) {
  int b = blockIdx.x;
  if (b < 16) {
    int n = threadIdx.x;
    be[b * 512 + n] = rbuf[b * 3] * b0[n] + rbuf[b * 3 + 1] * b1[n] + rbuf[b * 3 + 2] * b2[n];
  } else {
    for (int i = threadIdx.x; i < 2112; i += 512) {
      int e = i / 704, r = i - e * 704;
      e1bcat[i] = (r < 682) ? (e == 0 ? a0 : e == 1 ? a1 : a2)[r] : 0.f;
    }
  }
}

// ---------------------------------------------------------------------------
// Universal MFMA GEMM, batch-flattened M (=12544), XCD-aware 1D grid.
// ORIENT 0: out pm bf16; EPI 0/1 relu/2 gelu/3 sigmoid*inplace/5 gelu*router
// ORIENT 1: out ch f32; EPI 4 resid+sc*(acc+bias[n]); EPI 5 resid+acc+bias2d.
// POOL: epilogue accumulates per-channel sums into pool_out via atomics.
// DUALBF: epilogue also writes bf16 pixel-major copy to pm_out.
template <int ORIENT, int EPI, int POOL, int DUALBF>
__global__ __launch_bounds__(256) void mgemm_k(const ushort* __restrict__ X,
                                               const ushort* __restrict__ Wt,
                                               const float* __restrict__ bias,
                                               const float* __restrict__ resid,
                                               const float* __restrict__ scales,
                                               void* __restrict__ OutV,
                                               float* __restrict__ pool_out,
                                               ushort* __restrict__ pm_out,
                                               int Ks, int Nreal, int Nstore) {
  const int bid = blockIdx.x;
  const int xcd = bid & 7;
  const int i = bid >> 3;
  const int mt_local = i % 14;
  const int nt = i / 14;
  const int m0 = (xcd * 14 + mt_local) * 112;
  const int n0 = nt * 128;
  const int bb = m0 / NPIX;
  const int t = threadIdx.x;
  const int w = t >> 6, lane = t & 63, c = lane & 15, g = lane >> 4;
  __shared__ ushort Xs[7168];
  __shared__ ushort Ws[8192];
  f32x4 acc[7][2];
  #pragma unroll
  for (int mi = 0; mi < 7; ++mi)
    #pragma unroll
    for (int ni = 0; ni < 2; ++ni) acc[mi][ni] = (f32x4){0.f, 0.f, 0.f, 0.f};

  for (int k0 = 0; k0 < Ks; k0 += 64) {
    for (int ii = t; ii < 896; ii += 256) {
      int m = ii >> 3, kg = ii & 7;
      uint4 v = *(const uint4*)(X + (size_t)(m0 + m) * Ks + k0 + kg * 8);
      *(uint4*)&Xs[m * 64 + ((kg ^ (m & 7)) << 3)] = v;
    }
    for (int ii = t; ii < 1024; ii += 256) {
      int n = ii >> 3, kg = ii & 7;
      uint4 v = {0u, 0u, 0u, 0u};
      if (n0 + n < Nreal) v = *(const uint4*)(Wt + (size_t)(n0 + n) * Ks + k0 + kg * 8);
      *(uint4*)&Ws[n * 64 + ((kg ^ (n & 7)) << 3)] = v;
    }
    __syncthreads();
    #pragma unroll
    for (int kc = 0; kc < 2; ++kc) {
      bf16x8 xf[7], wf[2];
      #pragma unroll
      for (int mi = 0; mi < 7; ++mi) {
        int m = mi * 16 + c;
        xf[mi] = *(const bf16x8*)&Xs[m * 64 + (((kc * 4 + g) ^ (m & 7)) << 3)];
      }
      #pragma unroll
      for (int ni = 0; ni < 2; ++ni) {
        int n = w * 32 + ni * 16 + c;
        wf[ni] = *(const bf16x8*)&Ws[n * 64 + (((kc * 4 + g) ^ (n & 7)) << 3)];
      }
      #pragma unroll
      for (int mi = 0; mi < 7; ++mi)
        #pragma unroll
        for (int ni = 0; ni < 2; ++ni)
          acc[mi][ni] = (ORIENT == 0)
            ? __builtin_amdgcn_mfma_f32_16x16x32_bf16(wf[ni], xf[mi], acc[mi][ni], 0, 0, 0)
            : __builtin_amdgcn_mfma_f32_16x16x32_bf16(xf[mi], wf[ni], acc[mi][ni], 0, 0, 0);
    }
    __syncthreads();
  }

  if (ORIENT == 0) {
    ushort* Ob = (ushort*)OutV;
    const int nbq = n0 + w * 32;
    float bi[2][4];
    #pragma unroll
    for (int ni = 0; ni < 2; ++ni)
      #pragma unroll
      for (int j = 0; j < 4; ++j) {
        int n = nbq + ni * 16 + g * 4 + j;
        bi[ni][j] = (n < Nreal) ? bias[n] : 0.f;
      }
    #pragma unroll
    for (int mi = 0; mi < 7; ++mi) {
      int m = m0 + mi * 16 + c;
      #pragma unroll
      for (int ni = 0; ni < 2; ++ni) {
        int nb = nbq + ni * 16 + g * 4;
        if (nb >= Nstore) continue;
        float v[4];
        #pragma unroll
        for (int j = 0; j < 4; ++j) v[j] = acc[mi][ni][j] + bi[ni][j];
        if (EPI == 1) {
          #pragma unroll
          for (int j = 0; j < 4; ++j) v[j] = fmaxf(v[j], 0.f);
        } else if (EPI == 2) {
          #pragma unroll
          for (int j = 0; j < 4; ++j)
            v[j] = 0.5f * v[j] * (1.f + erff(v[j] * 0.70710678118654752f));
        } else if (EPI == 3) {
          uint2 cm = *(const uint2*)&Ob[(size_t)m * Nstore + nb];
          float cf[4];
          unpack4bf(cm, cf);
          #pragma unroll
          for (int j = 0; j < 4; ++j)
            v[j] = (1.f / (1.f + __expf(-v[j]))) * cf[j];
        } else if (EPI == 5) {
          int e = nb / 704; e = (e > 2) ? 2 : e;
          float sc = scales[bb * 3 + e];
          #pragma unroll
          for (int j = 0; j < 4; ++j)
            v[j] = 0.5f * v[j] * (1.f + erff(v[j] * 0.70710678118654752f)) * sc;
        }
        uint2 o = {pack2bf(v[0], v[1]), pack2bf(v[2], v[3])};
        *(uint2*)&Ob[(size_t)m * Nstore + nb] = o;
      }
    }
  } else {
    const int prow = m0 - bb * NPIX;
    float* Ob = (float*)OutV + (size_t)bb * CDIM * NPIX;
    const float* Rb = resid + (size_t)bb * CDIM * NPIX;
    float sc = (EPI == 4 && scales) ? scales[bb * 3] : 1.f;
    #pragma unroll
    for (int ni = 0; ni < 2; ++ni) {
      int n = n0 + w * 32 + ni * 16 + c;
      float bv = (EPI == 5) ? bias[(size_t)bb * CDIM + n] : bias[n];
      float cs = 0.f;
      #pragma unroll
      for (int mi = 0; mi < 7; ++mi) {
        int p = prow + mi * 16 + g * 4;
        size_t off = (size_t)n * NPIX + p;
        float4 r = *(const float4*)&Rb[off];
        f32x4 a = acc[mi][ni];
        float4 o = {r.x + sc * (a[0] + bv), r.y + sc * (a[1] + bv),
                    r.z + sc * (a[2] + bv), r.w + sc * (a[3] + bv)};
        *(float4*)&Ob[off] = o;
        if (POOL) cs += o.x + o.y + o.z + o.w;
        if (DUALBF) {
          size_t mg = (size_t)(m0 + mi * 16 + g * 4);
          pm_out[mg * CDIM + n] = f2bf(o.x);
          pm_out[(mg + 1) * CDIM + n] = f2bf(o.y);
          pm_out[(mg + 2) * CDIM + n] = f2bf(o.z);
          pm_out[(mg + 3) * CDIM + n] = f2bf(o.w);
        }
      }
      if (POOL) {
        cs += __shfl_xor(cs, 16);
        cs += __shfl_xor(cs, 32);
        if (g == 0) atomicAdd(pool_out + (size_t)bb * CDIM + n, cs);
      }
    }
  }
}

// ---------------------------------------------------------------------------
// transpose V out of qkvbf:  [b][p][1024+c] bf16 -> vbf [b][c][784] bf16
__global__ __launch_bounds__(256) void vtr_k(const ushort* __restrict__ qkvbf,
                                             ushort* __restrict__ vbf) {
  const int p0 = blockIdx.x * 64, c0 = blockIdx.y * 64, b = blockIdx.z;
  __shared__ ushort T[64][72];
  for (int idx = threadIdx.x; idx < 512; idx += 256) {
    int pl = idx >> 3, cq = idx & 7;
    int p = p0 + pl;
    uint4 v = {0u, 0u, 0u, 0u};
    if (p < NPIX)
      v = *(const uint4*)(qkvbf + (size_t)(b * NPIX + p) * C3 + 1024 + c0 + cq * 8);
    *(uint4*)&T[pl][cq * 8] = v;
  }
  __syncthreads();
  for (int idx = threadIdx.x; idx < 512; idx += 256) {
    int cl = idx >> 3, pq = idx & 7;
    if (p0 + pq * 8 < NPIX) {
      ushort tmp[8];
      #pragma unroll
      for (int i = 0; i < 8; ++i) tmp[i] = T[pq * 8 + i][cl];
      *(uint4*)(vbf + ((size_t)(b * CDIM + c0 + cl)) * NPIX + p0 + pq * 8) =
          *(const uint4*)&tmp[0];
    }
  }
}

// ---------------------------------------------------------------------------
// MFMA flash attention, register software-pipeline: per m-step, prefetch the
// NEXT step's K/V/bias tiles into regs before computing the current step.
struct KFr { bf16x8 a0, a1, b0, b1; };
struct VFr { bf16x8 v0, v1, v2, v3; };
struct BFr { uint2 sl, fl, sh, fh; };

__global__ __launch_bounds__(256) void attn_mfma_k(const ushort* __restrict__ qkvbf,
                                                   const ushort* __restrict__ vbf,
                                                   const ushort* __restrict__ sprpb,
                                                   const ushort* __restrict__ fpb,
                                                   ushort* __restrict__ obf) {
  const int bid = blockIdx.x;
  const int xcd = bid & 7;
  const int i = bid >> 3;
  const int b = xcd + 8 * (i / 56);
  const int r = i % 56;
  const int h = r & 7;
  const int qt = r >> 3;
  const int w = threadIdx.x >> 6, lane = threadIdx.x & 63;
  const int g = lane >> 4, c = lane & 15;
  const int q0 = qt * 128 + w * 32;
  if (q0 >= NPIX) return;
  const bool hasB = (q0 + 16) < NPIX;
  const int qA = q0 + c;
  const int qB = q0 + 16 + c;

  __shared__ uint BL[4][2][384];
  uint* bwA = BL[w][0];
  uint* bwB = BL[w][1];

  const ushort* qpA = qkvbf + (size_t)(b * NPIX + qA) * C3 + h * 64 + g * 8;
  const bf16x8 qfA0 = *(const bf16x8*)qpA;
  const bf16x8 qfA1 = *(const bf16x8*)(qpA + 32);
  bf16x8 qfB0 = qfA0, qfB1 = qfA1;
  if (hasB) {
    const ushort* qpB = qkvbf + (size_t)(b * NPIX + qB) * C3 + h * 64 + g * 8;
    qfB0 = *(const bf16x8*)qpB;
    qfB1 = *(const bf16x8*)(qpB + 32);
  }

  const ushort* kbase = qkvbf + (size_t)b * NPIX * C3 + 512 + h * 64 + g * 8;
  const ushort* vbase = vbf + ((size_t)b * CDIM + h * 64) * NPIX;
  const ushort* sprA = sprpb + ((size_t)h * NPIX + qA) * NPIX;
  const ushort* sprB = sprpb + ((size_t)h * NPIX + (hasB ? qB : qA)) * NPIX;
  const ushort* fpA = fpb + ((size_t)b * NPIX + qA) * NPIX;
  const ushort* fpB = fpb + ((size_t)b * NPIX + (hasB ? qB : qA)) * NPIX;

  auto load_k = [&](int m0, bool tfull) -> KFr {
    KFr k;
    const ushort* kp = kbase + (size_t)(m0 + c) * C3;
    k.a0 = *(const bf16x8*)kp;
    k.a1 = *(const bf16x8*)(kp + 32);
    const ushort* kp1 = kp + (tfull ? (size_t)16 * C3 : 0);
    k.b0 = *(const bf16x8*)kp1;
    k.b1 = *(const bf16x8*)(kp1 + 32);
    return k;
  };
  auto load_v = [&](int m0) -> VFr {
    VFr v;
    const ushort* vp = vbase + (size_t)c * NPIX + m0 + g * 8;
    v.v0 = *(const bf16x8*)(vp);
    v.v1 = *(const bf16x8*)(vp + (size_t)16 * NPIX);
    v.v2 = *(const bf16x8*)(vp + (size_t)32 * NPIX);
    v.v3 = *(const bf16x8*)(vp + (size_t)48 * NPIX);
    return v;
  };
  auto load_b = [&](const ushort* spr, const ushort* fp, int m0) -> BFr {
    BFr x;
    x.sl = *(const uint2*)(spr + m0 + g * 4);
    x.fl = *(const uint2*)(fp + m0 + g * 4);
    x.sh = *(const uint2*)(spr + m0 + 16 + g * 4);
    x.fh = *(const uint2*)(fp + m0 + 16 + g * 4);
    return x;
  };

  f32x4 oA0 = {0.f, 0.f, 0.f, 0.f}, oA1 = oA0, oA2 = oA0, oA3 = oA0;
  f32x4 oB0 = oA0, oB1 = oA0, oB2 = oA0, oB3 = oA0;
  float MA = -1e30f, LA = 0.f, MB = -1e30f, LB = 0.f;

  KFr kc = load_k(0, true);
  VFr vc = load_v(0);
  BFr bcA = load_b(sprA, fpA, 0);
  BFr bcB = bcA;
  if (hasB) bcB = load_b(sprB, fpB, 0);

  for (int ms = 0; ms < 25; ++ms) {
    const int m0 = ms * 32;
    const bool full = (ms < 24);

    // ---- prefetch next tile (regs) ----
    KFr kn; VFr vn; BFr bnA, bnB;
    if (full) {
      const int nm0 = m0 + 32;
      kn = load_k(nm0, ms + 1 < 24);
      vn = load_v(nm0);
      bnA = load_b(sprA, fpA, nm0);
      if (hasB) bnB = load_b(sprB, fpB, nm0);
    }

    // ---- chunk A ----
    f32x4 sA0 = {0.f, 0.f, 0.f, 0.f}, sA1 = sA0;
    sA0 = __builtin_amdgcn_mfma_f32_16x16x32_bf16(kc.a0, qfA0, sA0, 0, 0, 0);
    sA0 = __builtin_amdgcn_mfma_f32_16x16x32_bf16(kc.a1, qfA1, sA0, 0, 0, 0);
    if (full) {
      sA1 = __builtin_amdgcn_mfma_f32_16x16x32_bf16(kc.b0, qfA0, sA1, 0, 0, 0);
      sA1 = __builtin_amdgcn_mfma_f32_16x16x32_bf16(kc.b1, qfA1, sA1, 0, 0, 0);
    }
    {
      float vA0[4], vA1[4];
      float spv[4], fpv[4];
      unpack4bf(bcA.sl, spv);
      unpack4bf(bcA.fl, fpv);
      #pragma unroll
      for (int j = 0; j < 4; ++j) vA0[j] = fmaf(sA0[j], 0.125f, spv[j]) * fpv[j];
      if (full) {
        unpack4bf(bcA.sh, spv);
        unpack4bf(bcA.fh, fpv);
        #pragma unroll
        for (int j = 0; j < 4; ++j) vA1[j] = fmaf(sA1[j], 0.125f, spv[j]) * fpv[j];
      }
      float tm = fmaxf(fmaxf(vA0[0], vA0[1]), fmaxf(vA0[2], vA0[3]));
      if (full) tm = fmaxf(tm, fmaxf(fmaxf(vA1[0], vA1[1]), fmaxf(vA1[2], vA1[3])));
      tm = fmaxf(tm, __shfl_xor(tm, 16));
      tm = fmaxf(tm, __shfl_xor(tm, 32));
      if (__any(tm > MA)) {
        const float nM = fmaxf(MA, tm);
        const float fac = __expf(MA - nM);
        LA *= fac;
        #pragma unroll
        for (int j = 0; j < 4; ++j) { oA0[j] *= fac; oA1[j] *= fac; oA2[j] *= fac; oA3[j] *= fac; }
        MA = nM;
      }
      float p0v[4], p1v[4];
      float ps = 0.f;
      #pragma unroll
      for (int j = 0; j < 4; ++j) { p0v[j] = __expf(vA0[j] - MA); ps += p0v[j]; }
      if (full) {
        #pragma unroll
        for (int j = 0; j < 4; ++j) { p1v[j] = __expf(vA1[j] - MA); ps += p1v[j]; }
      }
      ps += __shfl_xor(ps, 16);
      ps += __shfl_xor(ps, 32);
      LA += ps;
      uint2 wlo, whi;
      wlo.x = pack2bf(p0v[0], p0v[1]);
      wlo.y = pack2bf(p0v[2], p0v[3]);
      whi.x = full ? pack2bf(p1v[0], p1v[1]) : 0u;
      whi.y = full ? pack2bf(p1v[2], p1v[3]) : 0u;
      *(uint2*)&bwA[lane * 6] = wlo;
      *(uint2*)&bwA[lane * 6 + 2] = whi;
    }

    // ---- chunk B ----
    if (hasB) {
      f32x4 sB0 = {0.f, 0.f, 0.f, 0.f}, sB1 = sB0;
      sB0 = __builtin_amdgcn_mfma_f32_16x16x32_bf16(kc.a0, qfB0, sB0, 0, 0, 0);
      sB0 = __builtin_amdgcn_mfma_f32_16x16x32_bf16(kc.a1, qfB1, sB0, 0, 0, 0);
      if (full) {
        sB1 = __builtin_amdgcn_mfma_f32_16x16x32_bf16(kc.b0, qfB0, sB1, 0, 0, 0);
        sB1 = __builtin_amdgcn_mfma_f32_16x16x32_bf16(kc.b1, qfB1, sB1, 0, 0, 0);
      }
      float vB0[4], vB1[4];
      float spv[4], fpv[4];
      unpack4bf(bcB.sl, spv);
      unpack4bf(bcB.fl, fpv);
      #pragma unroll
      for (int j = 0; j < 4; ++j) vB0[j] = fmaf(sB0[j], 0.125f, spv[j]) * fpv[j];
      if (full) {
        unpack4bf(bcB.sh, spv);
        unpack4bf(bcB.fh, fpv);
        #pragma unroll
        for (int j = 0; j < 4; ++j) vB1[j] = fmaf(sB1[j], 0.125f, spv[j]) * fpv[j];
      }
      float tm = fmaxf(fmaxf(vB0[0], vB0[1]), fmaxf(vB0[2], vB0[3]));
      if (full) tm = fmaxf(tm, fmaxf(fmaxf(vB1[0], vB1[1]), fmaxf(vB1[2], vB1[3])));
      tm = fmaxf(tm, __shfl_xor(tm, 16));
      tm = fmaxf(tm, __shfl_xor(tm, 32));
      if (__any(tm > MB)) {
        const float nM = fmaxf(MB, tm);
        const float fac = __expf(MB - nM);
        LB *= fac;
        #pragma unroll
        for (int j = 0; j < 4; ++j) { oB0[j] *= fac; oB1[j] *= fac; oB2[j] *= fac; oB3[j] *= fac; }
        MB = nM;
      }
      float p0v[4], p1v[4];
      float ps = 0.f;
      #pragma unroll
      for (int j = 0; j < 4; ++j) { p0v[j] = __expf(vB0[j] - MB); ps += p0v[j]; }
      if (full) {
        #pragma unroll
        for (int j = 0; j < 4; ++j) { p1v[j] = __expf(vB1[j] - MB); ps += p1v[j]; }
      }
      ps += __shfl_xor(ps, 16);
      ps += __shfl_xor(ps, 32);
      LB += ps;
      uint2 wlo, whi;
      wlo.x = pack2bf(p0v[0], p0v[1]);
      wlo.y = pack2bf(p0v[2], p0v[3]);
      whi.x = full ? pack2bf(p1v[0], p1v[1]) : 0u;
      whi.y = full ? pack2bf(p1v[2], p1v[3]) : 0u;
      *(uint2*)&bwB[lane * 6] = wlo;
      *(uint2*)&bwB[lane * 6 + 2] = whi;
    }

    // ---- PV for both chunks ----
    const int f = g >> 1;
    const int slo = 32 * (g & 1) + c;
    uint2 blo = *(const uint2*)&bwA[slo * 6 + f * 2];
    uint2 bhi = *(const uint2*)&bwA[(slo + 16) * 6 + f * 2];
    uint4 bba = {blo.x, blo.y, bhi.x, bhi.y};
    const bf16x8 pfA = __builtin_bit_cast(bf16x8, bba);
    oA0 = __builtin_amdgcn_mfma_f32_16x16x32_bf16(vc.v0, pfA, oA0, 0, 0, 0);
    oA1 = __builtin_amdgcn_mfma_f32_16x16x32_bf16(vc.v1, pfA, oA1, 0, 0, 0);
    oA2 = __builtin_amdgcn_mfma_f32_16x16x32_bf16(vc.v2, pfA, oA2, 0, 0, 0);
    oA3 = __builtin_amdgcn_mfma_f32_16x16x32_bf16(vc.v3, pfA, oA3, 0, 0, 0);
    if (hasB) {
      uint2 clo = *(const uint2*)&bwB[slo * 6 + f * 2];
      uint2 chi = *(const uint2*)&bwB[(slo + 16) * 6 + f * 2];
      uint4 bbb = {clo.x, clo.y, chi.x, chi.y};
      const bf16x8 pfB = __builtin_bit_cast(bf16x8, bbb);
      oB0 = __builtin_amdgcn_mfma_f32_16x16x32_bf16(vc.v0, pfB, oB0, 0, 0, 0);
      oB1 = __builtin_amdgcn_mfma_f32_16x16x32_bf16(vc.v1, pfB, oB1, 0, 0, 0);
      oB2 = __builtin_amdgcn_mfma_f32_16x16x32_bf16(vc.v2, pfB, oB2, 0, 0, 0);
      oB3 = __builtin_amdgcn_mfma_f32_16x16x32_bf16(vc.v3, pfB, oB3, 0, 0, 0);
    }

    if (full) { kc = kn; vc = vn; bcA = bnA; if (hasB) bcB = bnB; }
  }

  {
    const float invL = 1.f / LA;
    ushort* dst = obf + (size_t)(b * NPIX + qA) * CDIM + h * 64 + g * 4;
    f32x4 ot[4] = {oA0, oA1, oA2, oA3};
    #pragma unroll
    for (int t2 = 0; t2 < 4; ++t2) {
      uint2 o = {pack2bf(ot[t2][0] * invL, ot[t2][1] * invL),
                 pack2bf(ot[t2][2] * invL, ot[t2][3] * invL)};
      *(uint2*)(dst + t2 * 16) = o;
    }
  }
  if (hasB) {
    const float invL = 1.f / LB;
    ushort* dst = obf + (size_t)(b * NPIX + qB) * CDIM + h * 64 + g * 4;
    f32x4 ot[4] = {oB0, oB1, oB2, oB3};
    #pragma unroll
    for (int t2 = 0; t2 < 4; ++t2) {
      uint2 o = {pack2bf(ot[t2][0] * invL, ot[t2][1] * invL),
                 pack2bf(ot[t2][2] * invL, ot[t2][3] * invL)};
      *(uint2*)(dst + t2 * 16) = o;
    }
  }
}

// ---------------------------------------------------------------------------
// Sliding-window fused LN2 + depthwise conv (3x3/5x5/7x7) -> cat pm bf16.
__device__ __forceinline__ float bf2f_s(ushort u) { return bf2f(u); }

template <int R>
__device__ __forceinline__ void conv_pass(const ushort* __restrict__ plane_ci,
                                          const float* __restrict__ wl_ci,
                                          float bv, int slot,
                                          ushort (*__restrict__ outb)[16], int ci) {
  constexpr int K = 2 * R + 1;
  float wreg[K * K];
  #pragma unroll
  for (int i = 0; i < K * K; ++i) wreg[i] = wl_ci[i];
  #pragma unroll
  for (int r7 = 0; r7 < 7; ++r7) {
    const int run = slot + r7 * 16;
    const int y = run >> 2, x0 = (run & 3) * 7;
    float acc[7];
    #pragma unroll
    for (int i = 0; i < 7; ++i) acc[i] = bv;
    #pragma unroll
    for (int dy = 0; dy < K; ++dy) {
      const ushort* rp = plane_ci + (y + 3 - R + dy) * 34 + (x0 + 3 - R);
      float win[7 + 2 * R];
      #pragma unroll
      for (int k = 0; k < 7 + 2 * R; ++k) win[k] = bf2f_s(rp[k]);
      #pragma unroll
      for (int i = 0; i < 7; ++i)
        #pragma unroll
        for (int k = 0; k < K; ++k)
          acc[i] = fmaf(win[i + k], wreg[dy * K + k], acc[i]);
    }
    #pragma unroll
    for (int i = 0; i < 7; ++i) outb[y * 28 + x0 + i][ci] = f2bf(acc[i]);
  }
}

__global__ __launch_bounds__(256) void dwln_k(const float* __restrict__ x2,
    const float* __restrict__ ust, const float* __restrict__ rst,
    const float* __restrict__ ad, const float* __restrict__ n2w,
    const float* __restrict__ n2b,
    const float* __restrict__ ew, const float* __restrict__ eb,
    const float* __restrict__ nw, const float* __restrict__ nb,
    const float* __restrict__ mw, const float* __restrict__ mb,
    ushort* __restrict__ cat) {
  const int cg = blockIdx.x, b = blockIdx.y;
  const int c0 = cg * 16;
  const int t = threadIdx.x;
  const int ci = t & 15, slot = t >> 4;

  __shared__ ushort plane[16][1156];
  __shared__ ushort outb[784][16];
  __shared__ float Wl[16 * 49];
  __shared__ float LWs[16], LBs[16];

  {
    uint* pz = (uint*)&plane[0][0];
    for (int i = t; i < 16 * 1156 / 2; i += 256) pz[i] = 0u;
  }
  if (t < 16) {
    int cc = c0 + t;
    float aw = ad[b * 1024 + cc], ab = ad[b * 1024 + 512 + cc];
    LWs[t] = n2w[cc] * (1.f + aw);
    LBs[t] = n2b[cc] + ab;
  }
  __syncthreads();

  {
    float uu[4], rr[4];
    #pragma unroll
    for (int j = 0; j < 4; ++j) {
      int p = t + j * 256;
      if (p < NPIX) {
        uu[j] = ust[(size_t)b * NPIX + p];
        rr[j] = rst[(size_t)b * NPIX + p];
      }
    }
    for (int cc = 0; cc < 16; ++cc) {
      const float* xp = x2 + ((size_t)(b * CDIM + c0 + cc)) * NPIX;
      float lw = LWs[cc], lb = LBs[cc];
      #pragma unroll
      for (int j = 0; j < 4; ++j) {
        int p = t + j * 256;
        if (p < NPIX) {
          int y = p / 28, xx2 = p - y * 28;
          plane[cc][(y + 3) * 34 + xx2 + 3] = f2bf(lw * (xp[p] - uu[j]) * rr[j] + lb);
        }
      }
    }
  }
  __syncthreads();

  #pragma unroll 1
  for (int cv = 0; cv < 3; ++cv) {
    const float* gw = (cv == 0) ? ew : (cv == 1) ? nw : mw;
    const float* gb = (cv == 0) ? eb : (cv == 1) ? nb : mb;
    const int K2 = (cv == 0) ? 9 : (cv == 1) ? 25 : 49;
    for (int i = t; i < 16 * K2; i += 256) {
      int cc = i / K2, k = i - cc * K2;
      Wl[cc * K2 + k] = gw[(size_t)(c0 + cc) * K2 + k];
    }
    __syncthreads();
    float bv = gb[c0 + ci];
    if (cv == 0)      conv_pass<1>(&plane[ci][0], &Wl[ci * 9],  bv, slot, outb, ci);
    else if (cv == 1) conv_pass<2>(&plane[ci][0], &Wl[ci * 25], bv, slot, outb, ci);
    else              conv_pass<3>(&plane[ci][0], &Wl[ci * 49], bv, slot, outb, ci);
    __syncthreads();
    for (int idx = t; idx < NPIX * 2; idx += 256) {
      int p = idx >> 1, half = idx & 1;
      uint4 v = *(const uint4*)&outb[p][half * 8];
      *(uint4*)(cat + ((size_t)(b * NPIX + p)) * C3 + cv * 512 + c0 + half * 8) = v;
    }
    __syncthreads();
  }
}

// ---------------------------------------------------------------------------
__global__ __launch_bounds__(64) void router_k(const float* __restrict__ pooled,
                                               const float* __restrict__ rw,
                                               const float* __restrict__ rb,
                                               float* __restrict__ r) {
  int b = blockIdx.x, lane = threadIdx.x;
  float a0 = 0.f, a1 = 0.f, a2 = 0.f;
  for (int k = lane; k < CDIM; k += 64) {
    float p = pooled[b * CDIM + k] * (1.f / NPIX);
    a0 += rw[k] * p;
    a1 += rw[CDIM + k] * p;
    a2 += rw[2 * CDIM + k] * p;
  }
  #pragma unroll
  for (int off = 32; off; off >>= 1) {
    a0 += __shfl_down(a0, off);
    a1 += __shfl_down(a1, off);
    a2 += __shfl_down(a2, off);
  }
  if (lane == 0) {
    float l0 = a0 + rb[0], l1 = a1 + rb[1], l2 = a2 + rb[2];
    float mx = fmaxf(l0, fmaxf(l1, l2));
    float e0 = __expf(l0 - mx), e1 = __expf(l1 - mx), e2 = __expf(l2 - mx);
    float inv = 1.f / (e0 + e1 + e2);
    r[b * 3 + 0] = e0 * inv;
    r[b * 3 + 1] = e1 * inv;
    r[b * 3 + 2] = e2 * inv;
  }
}

// ---------------------------------------------------------------------------
extern "C" void kernel_launch(void* const* d_in, const int* in_sizes, int n_in,
                              void* d_out, int out_size, void* d_ws, size_t ws_size,
                              hipStream_t stream) {
  (void)in_sizes; (void)n_in; (void)out_size; (void)ws_size;
  const float* x         = (const float*)d_in[0];
  const float* fpri      = (const float*)d_in[1];
  const float* n1_w      = (const float*)d_in[2];
  const float* n1_b      = (const float*)d_in[3];
  const float* n1_a1w    = (const float*)d_in[4];
  const float* n1_a1b    = (const float*)d_in[5];
  const float* n1_a2w    = (const float*)d_in[6];
  const float* n1_a2b    = (const float*)d_in[7];
  const float* n2_w      = (const float*)d_in[8];
  const float* n2_b      = (const float*)d_in[9];
  const float* n2_a1w    = (const float*)d_in[10];
  const float* n2_a1b    = (const float*)d_in[11];
  const float* n2_a2w    = (const float*)d_in[12];
  const float* n2_a2b    = (const float*)d_in[13];
  const float* qkv_w     = (const float*)d_in[14];
  const float* qkv_b     = (const float*)d_in[15];
  const float* rpb_table = (const float*)d_in[16];
  const float* sprior    = (const float*)d_in[17];
  const float* proj_w    = (const float*)d_in[18];
  const float* proj_b    = (const float*)d_in[19];
  const float* eye_w     = (const float*)d_in[20];
  const float* eye_b     = (const float*)d_in[21];
  const float* nose_w    = (const float*)d_in[22];
  const float* nose_b    = (const float*)d_in[23];
  const float* mouth_w   = (const float*)d_in[24];
  const float* mouth_b   = (const float*)d_in[25];
  const float* fusion_w  = (const float*)d_in[26];
  const float* fusion_b  = (const float*)d_in[27];
  const float* gate1_w   = (const float*)d_in[28];
  const float* gate1_b   = (const float*)d_in[29];
  const float* gate2_w   = (const float*)d_in[30];
  const float* gate2_b   = (const float*)d_in[31];
  const float* e1w[3] = {(const float*)d_in[32], (const float*)d_in[36], (const float*)d_in[40]};
  const float* e1b[3] = {(const float*)d_in[33], (const float*)d_in[37], (const float*)d_in[41]};
  const float* e2w[3] = {(const float*)d_in[34], (const float*)d_in[38], (const float*)d_in[42]};
  const float* e2b[3] = {(const float*)d_in[35], (const float*)d_in[39], (const float*)d_in[43]};
  const float* router_w  = (const float*)d_in[44];
  const float* router_b  = (const float*)d_in[45];

  float* ws    = (float*)d_ws;
  ushort* xpm  = (ushort*)(ws + OFF_XPM);   // xa / xn2 -> x3bf
  ushort* wb   = (ushort*)(ws + OFF_W);
  ushort* r2u  = (ushort*)(ws + OFF_R2);    // qkvbf -> catpm -> he
  ushort* vbf  = (ushort*)(ws + OFF_VBF);
  ushort* obf  = (ushort*)(ws + OFF_OBF);   // attn O -> g1bf
  float* x2    = ws + OFF_X2;
  float* x3    = ws + OFF_X3;
  float* pld   = ws + OFF_PL;
  float* adb   = ws + OFF_AD;
  float* rbuf  = ws + OFF_RB;
  float* ust   = ws + OFF_US;
  float* rst   = ws + OFF_RS;
  float* outp  = (float*)d_out;

  ushort* qkvw  = wb + WOFF_QKV;
  ushort* projw = wb + WOFF_PROJ;
  ushort* g1w   = wb + WOFF_G1;
  ushort* g2w   = wb + WOFF_G2;
  ushort* fusw  = wb + WOFF_FUS;
  ushort* e1cat = wb + WOFF_E1;             // [2112][512]
  ushort* e2cat = (ushort*)(ws + OFF_E2C);  // [512][2112]
  float* be     = adb;                      // [16][512]
  float* e1bcat = adb + 8192;               // [2112]

  ushort* fpbf   = (ushort*)x2;
  ushort* sprpbf = (ushort*)x3;

  // --- weight conversion + expert stacking (704-aligned) ---
  CvtDesc D;
  auto seg = [&](int s2, const float* src, ushort* dst, int rows, int sk, int dk,
                 int ds, int rr) {
    D.s[s2] = src; D.d[s2] = dst; D.rows[s2] = rows; D.sk[s2] = sk;
    D.dk[s2] = dk; D.ds[s2] = ds; D.rr[s2] = rr;
  };
  seg(0, qkv_w,    qkvw,  1536, 512,  512,  512,  1536);
  seg(1, proj_w,   projw, 512,  512,  512,  512,  512);
  seg(2, gate1_w,  g1w,   128,  512,  512,  512,  128);
  seg(3, gate2_w,  g2w,   1536, 128,  128,  128,  1536);
  seg(4, fusion_w, fusw,  512,  1536, 1536, 1536, 512);
  for (int e = 0; e < 3; ++e) {
    seg(5 + e, e1w[e], e1cat + (size_t)e * 704 * 512, 704, 512, 512, 512, 682);
    seg(8 + e, e2w[e], e2cat + (size_t)e * 704,       512, 682, 704, 2112, 512);
  }
  cvt_w_k<<<dim3(512, 11), 256, 0, stream>>>(D);

  // --- attention bias prep ---
  sprpb_k<<<dim3(NPIX, NHEAD), 256, 0, stream>>>(sprior, rpb_table, sprpbf);
  fpcvt_k<<<9604, 256, 0, stream>>>(fpri, fpbf);

  // --- LN1 ---
  pool_mean_k<<<dim3(CDIM, 16), 64, 0, stream>>>(x, pld);
  adapt_mlp_k<<<16, 256, 0, stream>>>(pld, n1_a1w, n1_a1b, n1_a2w, n1_a2b, adb);
  ln_pm_k<0><<<dim3(25, 16), 256, 0, stream>>>(x, n1_w, n1_b, adb, xpm, nullptr, nullptr);

  // --- attention ---
  mgemm_k<0, 0, 0, 0><<<1344, 256, 0, stream>>>(xpm, qkvw, qkv_b, nullptr, nullptr,
                                                r2u, nullptr, nullptr, 512, 1536, 1536);
  vtr_k<<<dim3(13, 8, 16), 256, 0, stream>>>(r2u, vbf);
  attn_mfma_k<<<896, 256, 0, stream>>>(r2u, vbf, sprpbf, fpbf, obf);
  hipMemsetAsync(pld, 0, 16 * CDIM * sizeof(float), stream);
  mgemm_k<1, 4, 1, 0><<<448, 256, 0, stream>>>(obf, projw, proj_b, x, nullptr,
                                               x2, pld, nullptr, 512, 512, 512);

  // --- LN2 + token mixer ---
  adapt_mlp_k<<<16, 256, 0, stream>>>(pld, n2_a1w, n2_a1b, n2_a2w, n2_a2b, adb);
  ln_pm_k<1><<<dim3(25, 16), 256, 0, stream>>>(x2, n2_w, n2_b, adb, xpm, ust, rst);
  dwln_k<<<dim3(32, 16), 256, 0, stream>>>(x2, ust, rst, adb, n2_w, n2_b,
                                           eye_w, eye_b, nose_w, nose_b, mouth_w, mouth_b,
                                           r2u);
  mgemm_k<0, 1, 0, 0><<<112, 256, 0, stream>>>(xpm, g1w, gate1_b, nullptr, nullptr,
                                               obf, nullptr, nullptr, 512, 128, 128);
  mgemm_k<0, 3, 0, 0><<<1344, 256, 0, stream>>>(obf, g2w, gate2_b, nullptr, nullptr,
                                                r2u, nullptr, nullptr, 128, 1536, 1536);
  hipMemsetAsync(pld, 0, 16 * CDIM * sizeof(float), stream);
  mgemm_k<1, 4, 1, 1><<<448, 256, 0, stream>>>(r2u, fusw, fusion_b, x2, nullptr,
                                               x3, pld, xpm, 1536, 512, 512);

  // --- MoE (fused: 2 stacked GEMMs; x3bf already in xpm via DUALBF) ---
  router_k<<<16, 64, 0, stream>>>(pld, router_w, router_b, rbuf);
  biaseff_k<<<17, 512, 0, stream>>>(rbuf, e2b[0], e2b[1], e2b[2],
                                    e1b[0], e1b[1], e1b[2], be, e1bcat);
  mgemm_k<0, 5, 0, 0><<<1904, 256, 0, stream>>>(xpm, e1cat, e1bcat, nullptr, rbuf,
                                                r2u, nullptr, nullptr, 512, 2112, 2112);
  mgemm_k<1, 5, 0, 0><<<448, 256, 0, stream>>>(r2u, e2cat, be, x3, nullptr,
                                               outp, nullptr, nullptr, 2112, 512, 512);
}

// Round 9
// 724.081 us; speedup vs baseline: 4.0889x; 1.0879x over previous
//
#include <hip/hip_runtime.h>
#include <math.h>

// ---------------------------------------------------------------------------
// EfficientFaceTransformer forward — round 9: BN-templated GEMM; BN=64 for the
// N=512 (grid-starved) GEMMs -> 2x block parallelism on proj/fusion/e2/g1.
// ---------------------------------------------------------------------------

#define NPIX 784
#define CDIM 512
#define NHEAD 8
#define C3 1536

typedef unsigned int uint;
typedef unsigned short ushort;
typedef float f32x4 __attribute__((ext_vector_type(4)));
typedef __bf16 bf16x8 __attribute__((ext_vector_type(8)));
typedef __bf16 bf16x2 __attribute__((ext_vector_type(2)));

// ---- workspace float offsets ----------------------------------------------
#define OFF_XPM ((size_t)0)          // pm bf16 act (xa / xn2 / x3bf)
#define OFF_W   ((size_t)3211264)    // bf16 weights
#define OFF_R2  ((size_t)5324288)    // qkvbf -> catpm -> he
#define OFF_VBF ((size_t)14958080)   // vbf (attn V)
#define OFF_OBF ((size_t)18169344)   // obf -> g1bf
#define OFF_X2  ((size_t)21380608)   // fp_bf (attn) -> x2 f32 ch-major
#define OFF_X3  ((size_t)27803136)   // sprpb_bf (attn) -> x3 f32 ch-major
#define OFF_PL  ((size_t)34225664)
#define OFF_AD  ((size_t)34233856)
#define OFF_RB  ((size_t)34250240)
#define OFF_US  ((size_t)34250288)
#define OFF_RS  ((size_t)34262832)
#define OFF_E2C ((size_t)34275392)   // e2cat bf16 [512][2112]

// weight sub-offsets (ushort units)
#define WOFF_QKV 0
#define WOFF_PROJ 786432
#define WOFF_G1  1048576
#define WOFF_G2  1114112
#define WOFF_FUS 1310720
#define WOFF_E1  2097152   /* e1cat [2112][512] stacked, 704-aligned */

__device__ __forceinline__ ushort f2bf(float f) {
  __bf16 h = (__bf16)f;
  return __builtin_bit_cast(ushort, h);
}
__device__ __forceinline__ unsigned pack2bf(float lo, float hi) {
  bf16x2 v = {(__bf16)lo, (__bf16)hi};
  return __builtin_bit_cast(unsigned, v);
}
__device__ __forceinline__ float bf2f(ushort u) {
  unsigned x = ((unsigned)u) << 16;
  return __builtin_bit_cast(float, x);
}
__device__ __forceinline__ void unpack4bf(uint2 v, float* o) {
  o[0] = bf2f((ushort)(v.x & 0xffffu)); o[1] = bf2f((ushort)(v.x >> 16));
  o[2] = bf2f((ushort)(v.y & 0xffffu)); o[3] = bf2f((ushort)(v.y >> 16));
}

// ---------------------------------------------------------------------------
// pooled[b,c] = SUM_p x[b,c,p]  (consumers apply 1/784)
__global__ __launch_bounds__(64) void pool_mean_k(const float* __restrict__ x,
                                                  float* __restrict__ pooled) {
  int c = blockIdx.x, b = blockIdx.y;
  const float* row = x + ((size_t)b * CDIM + c) * NPIX;
  float s = 0.f;
  for (int i = threadIdx.x; i < NPIX; i += 64) s += row[i];
  #pragma unroll
  for (int off = 32; off; off >>= 1) s += __shfl_down(s, off);
  if (threadIdx.x == 0) pooled[b * CDIM + c] = s;
}

// ---------------------------------------------------------------------------
__global__ __launch_bounds__(256) void adapt_mlp_k(const float* __restrict__ pooled,
                                                   const float* __restrict__ a1w,
                                                   const float* __restrict__ a1b,
                                                   const float* __restrict__ a2w,
                                                   const float* __restrict__ a2b,
                                                   float* __restrict__ ad) {
  int b = blockIdx.x, tid = threadIdx.x;
  __shared__ float pl[CDIM];
  __shared__ float hh[128];
  for (int i = tid; i < CDIM; i += 256)
    pl[i] = pooled[b * CDIM + i] * (1.f / NPIX);
  __syncthreads();
  if (tid < 128) {
    const float* w = a1w + (size_t)tid * CDIM;
    float a = a1b[tid];
    for (int k = 0; k < CDIM; ++k) a += w[k] * pl[k];
    hh[tid] = fmaxf(a, 0.f);
  }
  __syncthreads();
  for (int o = tid; o < 1024; o += 256) {
    const float* w = a2w + (size_t)o * 128;
    float a = a2b[o];
    for (int k = 0; k < 128; ++k) a += w[k] * hh[k];
    ad[b * 1024 + o] = a;
  }
}

// ---------------------------------------------------------------------------
// adaptive LN: read f32 ch-major, write bf16 pixel-major [b][p][512].
template <int STATS>
__global__ __launch_bounds__(256) void ln_pm_k(const float* __restrict__ x,
                                               const float* __restrict__ w,
                                               const float* __restrict__ bias,
                                               const float* __restrict__ ad,
                                               ushort* __restrict__ out,
                                               float* __restrict__ ust,
                                               float* __restrict__ rstp) {
  int b = blockIdx.y;
  int p0 = blockIdx.x * 32;
  int tid = threadIdx.x;
  int px = tid & 31, cg = tid >> 5;
  int p = p0 + px;
  bool valid = p < NPIX;
  const float* xb = x + (size_t)b * CDIM * NPIX;
  float s = 0.f, s2 = 0.f;
  if (valid) {
    for (int c = cg * 64; c < cg * 64 + 64; ++c) {
      float v = xb[(size_t)c * NPIX + p];
      s += v; s2 += v * v;
    }
  }
  __shared__ float rs[8][32], rq[8][32], us[32], vs[32];
  rs[cg][px] = s; rq[cg][px] = s2;
  __syncthreads();
  if (tid < 32) {
    float ts = 0.f, ts2 = 0.f;
    #pragma unroll
    for (int g = 0; g < 8; ++g) { ts += rs[g][tid]; ts2 += rq[g][tid]; }
    float u = ts * (1.f / CDIM);
    float var = ts2 * (1.f / CDIM) - u * u;
    float rv = rsqrtf(var + 1e-6f);
    us[tid] = u; vs[tid] = rv;
    if (STATS && p0 + tid < NPIX) {
      ust[(size_t)b * NPIX + p0 + tid] = u;
      rstp[(size_t)b * NPIX + p0 + tid] = rv;
    }
  }
  __syncthreads();
  if (valid) {
    float u = us[px], rv = vs[px];
    const float* aw = ad + (size_t)b * 1024;
    const float* ab = aw + CDIM;
    ushort* ob = out + ((size_t)(b * NPIX + p)) * CDIM + cg * 64;
    for (int cb = 0; cb < 64; cb += 8) {
      int c = cg * 64 + cb;
      float vv[8];
      #pragma unroll
      for (int q = 0; q < 8; ++q) {
        float v = xb[(size_t)(c + q) * NPIX + p];
        vv[q] = w[c + q] * (1.f + aw[c + q]) * ((v - u) * rv) + (bias[c + q] + ab[c + q]);
      }
      uint4 o = {pack2bf(vv[0], vv[1]), pack2bf(vv[2], vv[3]),
                 pack2bf(vv[4], vv[5]), pack2bf(vv[6], vv[7])};
      *(uint4*)(ob + cb) = o;
    }
  }
}

// ---------------------------------------------------------------------------
// weight convert fp32 -> bf16 with stacking: d[r*ds + cc], zero outside.
struct CvtDesc {
  const float* s[11];
  ushort* d[11];
  int rows[11], sk[11], dk[11], ds[11], rr[11];
};
__global__ __launch_bounds__(256) void cvt_w_k(CvtDesc D) {
  int seg = blockIdx.y;
  int sk = D.sk[seg], dk = D.dk[seg], ds = D.ds[seg], rr = D.rr[seg];
  int total = D.rows[seg] * dk;
  const float* s = D.s[seg];
  ushort* d = D.d[seg];
  for (int i = blockIdx.x * 256 + threadIdx.x; i < total; i += gridDim.x * 256) {
    int r = i / dk, cc = i - r * dk;
    d[(size_t)r * ds + cc] = (cc < sk && r < rr) ? f2bf(s[(size_t)r * sk + cc]) : (ushort)0;
  }
}

// ---------------------------------------------------------------------------
__global__ __launch_bounds__(256) void sprpb_k(const float* __restrict__ sp,
                                               const float* __restrict__ rpb,
                                               ushort* __restrict__ out) {
  const int q = blockIdx.x, h = blockIdx.y;
  const int i1 = q / 28, j1 = q - i1 * 28;
  const float* src = sp + ((size_t)h * NPIX + q) * NPIX;
  ushort* dst = out + ((size_t)h * NPIX + q) * NPIX;
  for (int m = threadIdx.x; m < NPIX; m += 256) {
    int i2 = m / 28, j2 = m - i2 * 28;
    float rv = rpb[(size_t)((i1 - i2 + 27) * 55 + (j1 - j2 + 27)) * NHEAD + h];
    dst[m] = f2bf(src[m] + rv);
  }
}

__global__ __launch_bounds__(256) void fpcvt_k(const float* __restrict__ fp,
                                               ushort* __restrict__ out) {
  size_t i = (size_t)blockIdx.x * 256 + threadIdx.x;
  float4 v = *((const float4*)fp + i);
  ushort4 o;
  o.x = f2bf(v.x); o.y = f2bf(v.y); o.z = f2bf(v.z); o.w = f2bf(v.w);
  *((ushort4*)out + i) = o;
}

// ---------------------------------------------------------------------------
__global__ __launch_bounds__(512) void biaseff_k(const float* __restrict__ rbuf,
                                                 const float* __restrict__ b0,
                                                 const float* __restrict__ b1,
                                                 const float* __restrict__ b2,
                                                 const float* __restrict__ a0,
                                                 const float* __restrict__ a1,
                                                 const float* __restrict__ a2,
                                                 float* __restrict__ be,
                                                 float* __restrict__ e1bcat) {
  int b = blockIdx.x;
  if (b < 16) {
    int n = threadIdx.x;
    be[b * 512 + n] = rbuf[b * 3] * b0[n] + rbuf[b * 3 + 1] * b1[n] + rbuf[b * 3 + 2] * b2[n];
  } else {
    for (int i = threadIdx.x; i < 2112; i += 512) {
      int e = i / 704, r = i - e * 704;
      e1bcat[i] = (r < 682) ? (e == 0 ? a0 : e == 1 ? a1 : a2)[r] : 0.f;
    }
  }
}

// ---------------------------------------------------------------------------
// Universal MFMA GEMM, batch-flattened M (=12544), XCD-aware 1D grid.
// grid = 8 * 14 * NT where NT = ceil(N / BN); xcd = bid&7 owns 14 m-tiles.
// BN: n-tile width (128 or 64). BN=64 doubles block parallelism for small-N.
// ORIENT 0: out pm bf16; EPI 0/1 relu/2 gelu/3 sigmoid*inplace/5 gelu*router
// ORIENT 1: out ch f32; EPI 4 resid+sc*(acc+bias[n]); EPI 5 resid+acc+bias2d.
// POOL: per-channel sums -> pool_out (atomics). DUALBF: also write pm bf16.
template <int ORIENT, int EPI, int POOL, int DUALBF, int BN>
__global__ __launch_bounds__(256) void mgemm_k(const ushort* __restrict__ X,
                                               const ushort* __restrict__ Wt,
                                               const float* __restrict__ bias,
                                               const float* __restrict__ resid,
                                               const float* __restrict__ scales,
                                               void* __restrict__ OutV,
                                               float* __restrict__ pool_out,
                                               ushort* __restrict__ pm_out,
                                               int Ks, int Nreal, int Nstore) {
  constexpr int NFRAG = BN / 64;   // n-fragments per wave (16 cols each)
  const int bid = blockIdx.x;
  const int xcd = bid & 7;
  const int i = bid >> 3;
  const int mt_local = i % 14;
  const int nt = i / 14;
  const int m0 = (xcd * 14 + mt_local) * 112;
  const int n0 = nt * BN;
  const int bb = m0 / NPIX;
  const int t = threadIdx.x;
  const int w = t >> 6, lane = t & 63, c = lane & 15, g = lane >> 4;
  __shared__ ushort Xs[7168];
  __shared__ ushort Ws[BN * 64];
  f32x4 acc[7][NFRAG];
  #pragma unroll
  for (int mi = 0; mi < 7; ++mi)
    #pragma unroll
    for (int ni = 0; ni < NFRAG; ++ni) acc[mi][ni] = (f32x4){0.f, 0.f, 0.f, 0.f};

  for (int k0 = 0; k0 < Ks; k0 += 64) {
    for (int ii = t; ii < 896; ii += 256) {
      int m = ii >> 3, kg = ii & 7;
      uint4 v = *(const uint4*)(X + (size_t)(m0 + m) * Ks + k0 + kg * 8);
      *(uint4*)&Xs[m * 64 + ((kg ^ (m & 7)) << 3)] = v;
    }
    for (int ii = t; ii < BN * 8; ii += 256) {
      int n = ii >> 3, kg = ii & 7;
      uint4 v = {0u, 0u, 0u, 0u};
      if (n0 + n < Nreal) v = *(const uint4*)(Wt + (size_t)(n0 + n) * Ks + k0 + kg * 8);
      *(uint4*)&Ws[n * 64 + ((kg ^ (n & 7)) << 3)] = v;
    }
    __syncthreads();
    #pragma unroll
    for (int kc = 0; kc < 2; ++kc) {
      bf16x8 xf[7], wf[NFRAG];
      #pragma unroll
      for (int mi = 0; mi < 7; ++mi) {
        int m = mi * 16 + c;
        xf[mi] = *(const bf16x8*)&Xs[m * 64 + (((kc * 4 + g) ^ (m & 7)) << 3)];
      }
      #pragma unroll
      for (int ni = 0; ni < NFRAG; ++ni) {
        int n = w * (16 * NFRAG) + ni * 16 + c;
        wf[ni] = *(const bf16x8*)&Ws[n * 64 + (((kc * 4 + g) ^ (n & 7)) << 3)];
      }
      #pragma unroll
      for (int mi = 0; mi < 7; ++mi)
        #pragma unroll
        for (int ni = 0; ni < NFRAG; ++ni)
          acc[mi][ni] = (ORIENT == 0)
            ? __builtin_amdgcn_mfma_f32_16x16x32_bf16(wf[ni], xf[mi], acc[mi][ni], 0, 0, 0)
            : __builtin_amdgcn_mfma_f32_16x16x32_bf16(xf[mi], wf[ni], acc[mi][ni], 0, 0, 0);
    }
    __syncthreads();
  }

  if (ORIENT == 0) {
    ushort* Ob = (ushort*)OutV;
    const int nbq = n0 + w * (16 * NFRAG);
    float bi[NFRAG][4];
    #pragma unroll
    for (int ni = 0; ni < NFRAG; ++ni)
      #pragma unroll
      for (int j = 0; j < 4; ++j) {
        int n = nbq + ni * 16 + g * 4 + j;
        bi[ni][j] = (n < Nreal) ? bias[n] : 0.f;
      }
    #pragma unroll
    for (int mi = 0; mi < 7; ++mi) {
      int m = m0 + mi * 16 + c;
      #pragma unroll
      for (int ni = 0; ni < NFRAG; ++ni) {
        int nb = nbq + ni * 16 + g * 4;
        if (nb >= Nstore) continue;
        float v[4];
        #pragma unroll
        for (int j = 0; j < 4; ++j) v[j] = acc[mi][ni][j] + bi[ni][j];
        if (EPI == 1) {
          #pragma unroll
          for (int j = 0; j < 4; ++j) v[j] = fmaxf(v[j], 0.f);
        } else if (EPI == 2) {
          #pragma unroll
          for (int j = 0; j < 4; ++j)
            v[j] = 0.5f * v[j] * (1.f + erff(v[j] * 0.70710678118654752f));
        } else if (EPI == 3) {
          uint2 cm = *(const uint2*)&Ob[(size_t)m * Nstore + nb];
          float cf[4];
          unpack4bf(cm, cf);
          #pragma unroll
          for (int j = 0; j < 4; ++j)
            v[j] = (1.f / (1.f + __expf(-v[j]))) * cf[j];
        } else if (EPI == 5) {
          int e = nb / 704; e = (e > 2) ? 2 : e;
          float sc = scales[bb * 3 + e];
          #pragma unroll
          for (int j = 0; j < 4; ++j)
            v[j] = 0.5f * v[j] * (1.f + erff(v[j] * 0.70710678118654752f)) * sc;
        }
        uint2 o = {pack2bf(v[0], v[1]), pack2bf(v[2], v[3])};
        *(uint2*)&Ob[(size_t)m * Nstore + nb] = o;
      }
    }
  } else {
    const int prow = m0 - bb * NPIX;
    float* Ob = (float*)OutV + (size_t)bb * CDIM * NPIX;
    const float* Rb = resid + (size_t)bb * CDIM * NPIX;
    float sc = (EPI == 4 && scales) ? scales[bb * 3] : 1.f;
    #pragma unroll
    for (int ni = 0; ni < NFRAG; ++ni) {
      int n = n0 + w * (16 * NFRAG) + ni * 16 + c;
      float bv = (EPI == 5) ? bias[(size_t)bb * CDIM + n] : bias[n];
      float cs = 0.f;
      #pragma unroll
      for (int mi = 0; mi < 7; ++mi) {
        int p = prow + mi * 16 + g * 4;
        size_t off = (size_t)n * NPIX + p;
        float4 r = *(const float4*)&Rb[off];
        f32x4 a = acc[mi][ni];
        float4 o = {r.x + sc * (a[0] + bv), r.y + sc * (a[1] + bv),
                    r.z + sc * (a[2] + bv), r.w + sc * (a[3] + bv)};
        *(float4*)&Ob[off] = o;
        if (POOL) cs += o.x + o.y + o.z + o.w;
        if (DUALBF) {
          size_t mg = (size_t)(m0 + mi * 16 + g * 4);
          pm_out[mg * CDIM + n] = f2bf(o.x);
          pm_out[(mg + 1) * CDIM + n] = f2bf(o.y);
          pm_out[(mg + 2) * CDIM + n] = f2bf(o.z);
          pm_out[(mg + 3) * CDIM + n] = f2bf(o.w);
        }
      }
      if (POOL) {
        cs += __shfl_xor(cs, 16);
        cs += __shfl_xor(cs, 32);
        if (g == 0) atomicAdd(pool_out + (size_t)bb * CDIM + n, cs);
      }
    }
  }
}

// ---------------------------------------------------------------------------
// transpose V out of qkvbf:  [b][p][1024+c] bf16 -> vbf [b][c][784] bf16
__global__ __launch_bounds__(256) void vtr_k(const ushort* __restrict__ qkvbf,
                                             ushort* __restrict__ vbf) {
  const int p0 = blockIdx.x * 64, c0 = blockIdx.y * 64, b = blockIdx.z;
  __shared__ ushort T[64][72];
  for (int idx = threadIdx.x; idx < 512; idx += 256) {
    int pl = idx >> 3, cq = idx & 7;
    int p = p0 + pl;
    uint4 v = {0u, 0u, 0u, 0u};
    if (p < NPIX)
      v = *(const uint4*)(qkvbf + (size_t)(b * NPIX + p) * C3 + 1024 + c0 + cq * 8);
    *(uint4*)&T[pl][cq * 8] = v;
  }
  __syncthreads();
  for (int idx = threadIdx.x; idx < 512; idx += 256) {
    int cl = idx >> 3, pq = idx & 7;
    if (p0 + pq * 8 < NPIX) {
      ushort tmp[8];
      #pragma unroll
      for (int i = 0; i < 8; ++i) tmp[i] = T[pq * 8 + i][cl];
      *(uint4*)(vbf + ((size_t)(b * CDIM + c0 + cl)) * NPIX + p0 + pq * 8) =
          *(const uint4*)&tmp[0];
    }
  }
}

// ---------------------------------------------------------------------------
// MFMA flash attention, register software-pipeline (round-8 structure).
struct KFr { bf16x8 a0, a1, b0, b1; };
struct VFr { bf16x8 v0, v1, v2, v3; };
struct BFr { uint2 sl, fl, sh, fh; };

__global__ __launch_bounds__(256) void attn_mfma_k(const ushort* __restrict__ qkvbf,
                                                   const ushort* __restrict__ vbf,
                                                   const ushort* __restrict__ sprpb,
                                                   const ushort* __restrict__ fpb,
                                                   ushort* __restrict__ obf) {
  const int bid = blockIdx.x;
  const int xcd = bid & 7;
  const int i = bid >> 3;
  const int b = xcd + 8 * (i / 56);
  const int r = i % 56;
  const int h = r & 7;
  const int qt = r >> 3;
  const int w = threadIdx.x >> 6, lane = threadIdx.x & 63;
  const int g = lane >> 4, c = lane & 15;
  const int q0 = qt * 128 + w * 32;
  if (q0 >= NPIX) return;
  const bool hasB = (q0 + 16) < NPIX;
  const int qA = q0 + c;
  const int qB = q0 + 16 + c;

  __shared__ uint BL[4][2][384];
  uint* bwA = BL[w][0];
  uint* bwB = BL[w][1];

  const ushort* qpA = qkvbf + (size_t)(b * NPIX + qA) * C3 + h * 64 + g * 8;
  const bf16x8 qfA0 = *(const bf16x8*)qpA;
  const bf16x8 qfA1 = *(const bf16x8*)(qpA + 32);
  bf16x8 qfB0 = qfA0, qfB1 = qfA1;
  if (hasB) {
    const ushort* qpB = qkvbf + (size_t)(b * NPIX + qB) * C3 + h * 64 + g * 8;
    qfB0 = *(const bf16x8*)qpB;
    qfB1 = *(const bf16x8*)(qpB + 32);
  }

  const ushort* kbase = qkvbf + (size_t)b * NPIX * C3 + 512 + h * 64 + g * 8;
  const ushort* vbase = vbf + ((size_t)b * CDIM + h * 64) * NPIX;
  const ushort* sprA = sprpb + ((size_t)h * NPIX + qA) * NPIX;
  const ushort* sprB = sprpb + ((size_t)h * NPIX + (hasB ? qB : qA)) * NPIX;
  const ushort* fpA = fpb + ((size_t)b * NPIX + qA) * NPIX;
  const ushort* fpB = fpb + ((size_t)b * NPIX + (hasB ? qB : qA)) * NPIX;

  auto load_k = [&](int m0, bool tfull) -> KFr {
    KFr k;
    const ushort* kp = kbase + (size_t)(m0 + c) * C3;
    k.a0 = *(const bf16x8*)kp;
    k.a1 = *(const bf16x8*)(kp + 32);
    const ushort* kp1 = kp + (tfull ? (size_t)16 * C3 : 0);
    k.b0 = *(const bf16x8*)kp1;
    k.b1 = *(const bf16x8*)(kp1 + 32);
    return k;
  };
  auto load_v = [&](int m0) -> VFr {
    VFr v;
    const ushort* vp = vbase + (size_t)c * NPIX + m0 + g * 8;
    v.v0 = *(const bf16x8*)(vp);
    v.v1 = *(const bf16x8*)(vp + (size_t)16 * NPIX);
    v.v2 = *(const bf16x8*)(vp + (size_t)32 * NPIX);
    v.v3 = *(const bf16x8*)(vp + (size_t)48 * NPIX);
    return v;
  };
  auto load_b = [&](const ushort* spr, const ushort* fp, int m0) -> BFr {
    BFr x;
    x.sl = *(const uint2*)(spr + m0 + g * 4);
    x.fl = *(const uint2*)(fp + m0 + g * 4);
    x.sh = *(const uint2*)(spr + m0 + 16 + g * 4);
    x.fh = *(const uint2*)(fp + m0 + 16 + g * 4);
    return x;
  };

  f32x4 oA0 = {0.f, 0.f, 0.f, 0.f}, oA1 = oA0, oA2 = oA0, oA3 = oA0;
  f32x4 oB0 = oA0, oB1 = oA0, oB2 = oA0, oB3 = oA0;
  float MA = -1e30f, LA = 0.f, MB = -1e30f, LB = 0.f;

  KFr kc = load_k(0, true);
  VFr vc = load_v(0);
  BFr bcA = load_b(sprA, fpA, 0);
  BFr bcB = bcA;
  if (hasB) bcB = load_b(sprB, fpB, 0);

  for (int ms = 0; ms < 25; ++ms) {
    const int m0 = ms * 32;
    const bool full = (ms < 24);

    KFr kn; VFr vn; BFr bnA, bnB;
    if (full) {
      const int nm0 = m0 + 32;
      kn = load_k(nm0, ms + 1 < 24);
      vn = load_v(nm0);
      bnA = load_b(sprA, fpA, nm0);
      if (hasB) bnB = load_b(sprB, fpB, nm0);
    }

    // ---- chunk A ----
    f32x4 sA0 = {0.f, 0.f, 0.f, 0.f}, sA1 = sA0;
    sA0 = __builtin_amdgcn_mfma_f32_16x16x32_bf16(kc.a0, qfA0, sA0, 0, 0, 0);
    sA0 = __builtin_amdgcn_mfma_f32_16x16x32_bf16(kc.a1, qfA1, sA0, 0, 0, 0);
    if (full) {
      sA1 = __builtin_amdgcn_mfma_f32_16x16x32_bf16(kc.b0, qfA0, sA1, 0, 0, 0);
      sA1 = __builtin_amdgcn_mfma_f32_16x16x32_bf16(kc.b1, qfA1, sA1, 0, 0, 0);
    }
    {
      float vA0[4], vA1[4];
      float spv[4], fpv[4];
      unpack4bf(bcA.sl, spv);
      unpack4bf(bcA.fl, fpv);
      #pragma unroll
      for (int j = 0; j < 4; ++j) vA0[j] = fmaf(sA0[j], 0.125f, spv[j]) * fpv[j];
      if (full) {
        unpack4bf(bcA.sh, spv);
        unpack4bf(bcA.fh, fpv);
        #pragma unroll
        for (int j = 0; j < 4; ++j) vA1[j] = fmaf(sA1[j], 0.125f, spv[j]) * fpv[j];
      }
      float tm = fmaxf(fmaxf(vA0[0], vA0[1]), fmaxf(vA0[2], vA0[3]));
      if (full) tm = fmaxf(tm, fmaxf(fmaxf(vA1[0], vA1[1]), fmaxf(vA1[2], vA1[3])));
      tm = fmaxf(tm, __shfl_xor(tm, 16));
      tm = fmaxf(tm, __shfl_xor(tm, 32));
      if (__any(tm > MA)) {
        const float nM = fmaxf(MA, tm);
        const float fac = __expf(MA - nM);
        LA *= fac;
        #pragma unroll
        for (int j = 0; j < 4; ++j) { oA0[j] *= fac; oA1[j] *= fac; oA2[j] *= fac; oA3[j] *= fac; }
        MA = nM;
      }
      float p0v[4], p1v[4];
      float ps = 0.f;
      #pragma unroll
      for (int j = 0; j < 4; ++j) { p0v[j] = __expf(vA0[j] - MA); ps += p0v[j]; }
      if (full) {
        #pragma unroll
        for (int j = 0; j < 4; ++j) { p1v[j] = __expf(vA1[j] - MA); ps += p1v[j]; }
      }
      ps += __shfl_xor(ps, 16);
      ps += __shfl_xor(ps, 32);
      LA += ps;
      uint2 wlo, whi;
      wlo.x = pack2bf(p0v[0], p0v[1]);
      wlo.y = pack2bf(p0v[2], p0v[3]);
      whi.x = full ? pack2bf(p1v[0], p1v[1]) : 0u;
      whi.y = full ? pack2bf(p1v[2], p1v[3]) : 0u;
      *(uint2*)&bwA[lane * 6] = wlo;
      *(uint2*)&bwA[lane * 6 + 2] = whi;
    }

    // ---- chunk B ----
    if (hasB) {
      f32x4 sB0 = {0.f, 0.f, 0.f, 0.f}, sB1 = sB0;
      sB0 = __builtin_amdgcn_mfma_f32_16x16x32_bf16(kc.a0, qfB0, sB0, 0, 0, 0);
      sB0 = __builtin_amdgcn_mfma_f32_16x16x32_bf16(kc.a1, qfB1, sB0, 0, 0, 0);
      if (full) {
        sB1 = __builtin_amdgcn_mfma_f32_16x16x32_bf16(kc.b0, qfB0, sB1, 0, 0, 0);
        sB1 = __builtin_amdgcn_mfma_f32_16x16x32_bf16(kc.b1, qfB1, sB1, 0, 0, 0);
      }
      float vB0[4], vB1[4];
      float spv[4], fpv[4];
      unpack4bf(bcB.sl, spv);
      unpack4bf(bcB.fl, fpv);
      #pragma unroll
      for (int j = 0; j < 4; ++j) vB0[j] = fmaf(sB0[j], 0.125f, spv[j]) * fpv[j];
      if (full) {
        unpack4bf(bcB.sh, spv);
        unpack4bf(bcB.fh, fpv);
        #pragma unroll
        for (int j = 0; j < 4; ++j) vB1[j] = fmaf(sB1[j], 0.125f, spv[j]) * fpv[j];
      }
      float tm = fmaxf(fmaxf(vB0[0], vB0[1]), fmaxf(vB0[2], vB0[3]));
      if (full) tm = fmaxf(tm, fmaxf(fmaxf(vB1[0], vB1[1]), fmaxf(vB1[2], vB1[3])));
      tm = fmaxf(tm, __shfl_xor(tm, 16));
      tm = fmaxf(tm, __shfl_xor(tm, 32));
      if (__any(tm > MB)) {
        const float nM = fmaxf(MB, tm);
        const float fac = __expf(MB - nM);
        LB *= fac;
        #pragma unroll
        for (int j = 0; j < 4; ++j) { oB0[j] *= fac; oB1[j] *= fac; oB2[j] *= fac; oB3[j] *= fac; }
        MB = nM;
      }
      float p0v[4], p1v[4];
      float ps = 0.f;
      #pragma unroll
      for (int j = 0; j < 4; ++j) { p0v[j] = __expf(vB0[j] - MB); ps += p0v[j]; }
      if (full) {
        #pragma unroll
        for (int j = 0; j < 4; ++j) { p1v[j] = __expf(vB1[j] - MB); ps += p1v[j]; }
      }
      ps += __shfl_xor(ps, 16);
      ps += __shfl_xor(ps, 32);
      LB += ps;
      uint2 wlo, whi;
      wlo.x = pack2bf(p0v[0], p0v[1]);
      wlo.y = pack2bf(p0v[2], p0v[3]);
      whi.x = full ? pack2bf(p1v[0], p1v[1]) : 0u;
      whi.y = full ? pack2bf(p1v[2], p1v[3]) : 0u;
      *(uint2*)&bwB[lane * 6] = wlo;
      *(uint2*)&bwB[lane * 6 + 2] = whi;
    }

    // ---- PV for both chunks ----
    const int f = g >> 1;
    const int slo = 32 * (g & 1) + c;
    uint2 blo = *(const uint2*)&bwA[slo * 6 + f * 2];
    uint2 bhi = *(const uint2*)&bwA[(slo + 16) * 6 + f * 2];
    uint4 bba = {blo.x, blo.y, bhi.x, bhi.y};
    const bf16x8 pfA = __builtin_bit_cast(bf16x8, bba);
    oA0 = __builtin_amdgcn_mfma_f32_16x16x32_bf16(vc.v0, pfA, oA0, 0, 0, 0);
    oA1 = __builtin_amdgcn_mfma_f32_16x16x32_bf16(vc.v1, pfA, oA1, 0, 0, 0);
    oA2 = __builtin_amdgcn_mfma_f32_16x16x32_bf16(vc.v2, pfA, oA2, 0, 0, 0);
    oA3 = __builtin_amdgcn_mfma_f32_16x16x32_bf16(vc.v3, pfA, oA3, 0, 0, 0);
    if (hasB) {
      uint2 clo = *(const uint2*)&bwB[slo * 6 + f * 2];
      uint2 chi = *(const uint2*)&bwB[(slo + 16) * 6 + f * 2];
      uint4 bbb = {clo.x, clo.y, chi.x, chi.y};
      const bf16x8 pfB = __builtin_bit_cast(bf16x8, bbb);
      oB0 = __builtin_amdgcn_mfma_f32_16x16x32_bf16(vc.v0, pfB, oB0, 0, 0, 0);
      oB1 = __builtin_amdgcn_mfma_f32_16x16x32_bf16(vc.v1, pfB, oB1, 0, 0, 0);
      oB2 = __builtin_amdgcn_mfma_f32_16x16x32_bf16(vc.v2, pfB, oB2, 0, 0, 0);
      oB3 = __builtin_amdgcn_mfma_f32_16x16x32_bf16(vc.v3, pfB, oB3, 0, 0, 0);
    }

    if (full) { kc = kn; vc = vn; bcA = bnA; if (hasB) bcB = bnB; }
  }

  {
    const float invL = 1.f / LA;
    ushort* dst = obf + (size_t)(b * NPIX + qA) * CDIM + h * 64 + g * 4;
    f32x4 ot[4] = {oA0, oA1, oA2, oA3};
    #pragma unroll
    for (int t2 = 0; t2 < 4; ++t2) {
      uint2 o = {pack2bf(ot[t2][0] * invL, ot[t2][1] * invL),
                 pack2bf(ot[t2][2] * invL, ot[t2][3] * invL)};
      *(uint2*)(dst + t2 * 16) = o;
    }
  }
  if (hasB) {
    const float invL = 1.f / LB;
    ushort* dst = obf + (size_t)(b * NPIX + qB) * CDIM + h * 64 + g * 4;
    f32x4 ot[4] = {oB0, oB1, oB2, oB3};
    #pragma unroll
    for (int t2 = 0; t2 < 4; ++t2) {
      uint2 o = {pack2bf(ot[t2][0] * invL, ot[t2][1] * invL),
                 pack2bf(ot[t2][2] * invL, ot[t2][3] * invL)};
      *(uint2*)(dst + t2 * 16) = o;
    }
  }
}

// ---------------------------------------------------------------------------
// Sliding-window fused LN2 + depthwise conv (3x3/5x5/7x7) -> cat pm bf16.
__device__ __forceinline__ float bf2f_s(ushort u) { return bf2f(u); }

template <int R>
__device__ __forceinline__ void conv_pass(const ushort* __restrict__ plane_ci,
                                          const float* __restrict__ wl_ci,
                                          float bv, int slot,
                                          ushort (*__restrict__ outb)[16], int ci) {
  constexpr int K = 2 * R + 1;
  float wreg[K * K];
  #pragma unroll
  for (int i = 0; i < K * K; ++i) wreg[i] = wl_ci[i];
  #pragma unroll
  for (int r7 = 0; r7 < 7; ++r7) {
    const int run = slot + r7 * 16;
    const int y = run >> 2, x0 = (run & 3) * 7;
    float acc[7];
    #pragma unroll
    for (int i = 0; i < 7; ++i) acc[i] = bv;
    #pragma unroll
    for (int dy = 0; dy < K; ++dy) {
      const ushort* rp = plane_ci + (y + 3 - R + dy) * 34 + (x0 + 3 - R);
      float win[7 + 2 * R];
      #pragma unroll
      for (int k = 0; k < 7 + 2 * R; ++k) win[k] = bf2f_s(rp[k]);
      #pragma unroll
      for (int i = 0; i < 7; ++i)
        #pragma unroll
        for (int k = 0; k < K; ++k)
          acc[i] = fmaf(win[i + k], wreg[dy * K + k], acc[i]);
    }
    #pragma unroll
    for (int i = 0; i < 7; ++i) outb[y * 28 + x0 + i][ci] = f2bf(acc[i]);
  }
}

__global__ __launch_bounds__(256) void dwln_k(const float* __restrict__ x2,
    const float* __restrict__ ust, const float* __restrict__ rst,
    const float* __restrict__ ad, const float* __restrict__ n2w,
    const float* __restrict__ n2b,
    const float* __restrict__ ew, const float* __restrict__ eb,
    const float* __restrict__ nw, const float* __restrict__ nb,
    const float* __restrict__ mw, const float* __restrict__ mb,
    ushort* __restrict__ cat) {
  const int cg = blockIdx.x, b = blockIdx.y;
  const int c0 = cg * 16;
  const int t = threadIdx.x;
  const int ci = t & 15, slot = t >> 4;

  __shared__ ushort plane[16][1156];
  __shared__ ushort outb[784][16];
  __shared__ float Wl[16 * 49];
  __shared__ float LWs[16], LBs[16];

  {
    uint* pz = (uint*)&plane[0][0];
    for (int i = t; i < 16 * 1156 / 2; i += 256) pz[i] = 0u;
  }
  if (t < 16) {
    int cc = c0 + t;
    float aw = ad[b * 1024 + cc], ab = ad[b * 1024 + 512 + cc];
    LWs[t] = n2w[cc] * (1.f + aw);
    LBs[t] = n2b[cc] + ab;
  }
  __syncthreads();

  {
    float uu[4], rr[4];
    #pragma unroll
    for (int j = 0; j < 4; ++j) {
      int p = t + j * 256;
      if (p < NPIX) {
        uu[j] = ust[(size_t)b * NPIX + p];
        rr[j] = rst[(size_t)b * NPIX + p];
      }
    }
    for (int cc = 0; cc < 16; ++cc) {
      const float* xp = x2 + ((size_t)(b * CDIM + c0 + cc)) * NPIX;
      float lw = LWs[cc], lb = LBs[cc];
      #pragma unroll
      for (int j = 0; j < 4; ++j) {
        int p = t + j * 256;
        if (p < NPIX) {
          int y = p / 28, xx2 = p - y * 28;
          plane[cc][(y + 3) * 34 + xx2 + 3] = f2bf(lw * (xp[p] - uu[j]) * rr[j] + lb);
        }
      }
    }
  }
  __syncthreads();

  #pragma unroll 1
  for (int cv = 0; cv < 3; ++cv) {
    const float* gw = (cv == 0) ? ew : (cv == 1) ? nw : mw;
    const float* gb = (cv == 0) ? eb : (cv == 1) ? nb : mb;
    const int K2 = (cv == 0) ? 9 : (cv == 1) ? 25 : 49;
    for (int i = t; i < 16 * K2; i += 256) {
      int cc = i / K2, k = i - cc * K2;
      Wl[cc * K2 + k] = gw[(size_t)(c0 + cc) * K2 + k];
    }
    __syncthreads();
    float bv = gb[c0 + ci];
    if (cv == 0)      conv_pass<1>(&plane[ci][0], &Wl[ci * 9],  bv, slot, outb, ci);
    else if (cv == 1) conv_pass<2>(&plane[ci][0], &Wl[ci * 25], bv, slot, outb, ci);
    else              conv_pass<3>(&plane[ci][0], &Wl[ci * 49], bv, slot, outb, ci);
    __syncthreads();
    for (int idx = t; idx < NPIX * 2; idx += 256) {
      int p = idx >> 1, half = idx & 1;
      uint4 v = *(const uint4*)&outb[p][half * 8];
      *(uint4*)(cat + ((size_t)(b * NPIX + p)) * C3 + cv * 512 + c0 + half * 8) = v;
    }
    __syncthreads();
  }
}

// ---------------------------------------------------------------------------
__global__ __launch_bounds__(64) void router_k(const float* __restrict__ pooled,
                                               const float* __restrict__ rw,
                                               const float* __restrict__ rb,
                                               float* __restrict__ r) {
  int b = blockIdx.x, lane = threadIdx.x;
  float a0 = 0.f, a1 = 0.f, a2 = 0.f;
  for (int k = lane; k < CDIM; k += 64) {
    float p = pooled[b * CDIM + k] * (1.f / NPIX);
    a0 += rw[k] * p;
    a1 += rw[CDIM + k] * p;
    a2 += rw[2 * CDIM + k] * p;
  }
  #pragma unroll
  for (int off = 32; off; off >>= 1) {
    a0 += __shfl_down(a0, off);
    a1 += __shfl_down(a1, off);
    a2 += __shfl_down(a2, off);
  }
  if (lane == 0) {
    float l0 = a0 + rb[0], l1 = a1 + rb[1], l2 = a2 + rb[2];
    float mx = fmaxf(l0, fmaxf(l1, l2));
    float e0 = __expf(l0 - mx), e1 = __expf(l1 - mx), e2 = __expf(l2 - mx);
    float inv = 1.f / (e0 + e1 + e2);
    r[b * 3 + 0] = e0 * inv;
    r[b * 3 + 1] = e1 * inv;
    r[b * 3 + 2] = e2 * inv;
  }
}

// ---------------------------------------------------------------------------
extern "C" void kernel_launch(void* const* d_in, const int* in_sizes, int n_in,
                              void* d_out, int out_size, void* d_ws, size_t ws_size,
                              hipStream_t stream) {
  (void)in_sizes; (void)n_in; (void)out_size; (void)ws_size;
  const float* x         = (const float*)d_in[0];
  const float* fpri      = (const float*)d_in[1];
  const float* n1_w      = (const float*)d_in[2];
  const float* n1_b      = (const float*)d_in[3];
  const float* n1_a1w    = (const float*)d_in[4];
  const float* n1_a1b    = (const float*)d_in[5];
  const float* n1_a2w    = (const float*)d_in[6];
  const float* n1_a2b    = (const float*)d_in[7];
  const float* n2_w      = (const float*)d_in[8];
  const float* n2_b      = (const float*)d_in[9];
  const float* n2_a1w    = (const float*)d_in[10];
  const float* n2_a1b    = (const float*)d_in[11];
  const float* n2_a2w    = (const float*)d_in[12];
  const float* n2_a2b    = (const float*)d_in[13];
  const float* qkv_w     = (const float*)d_in[14];
  const float* qkv_b     = (const float*)d_in[15];
  const float* rpb_table = (const float*)d_in[16];
  const float* sprior    = (const float*)d_in[17];
  const float* proj_w    = (const float*)d_in[18];
  const float* proj_b    = (const float*)d_in[19];
  const float* eye_w     = (const float*)d_in[20];
  const float* eye_b     = (const float*)d_in[21];
  const float* nose_w    = (const float*)d_in[22];
  const float* nose_b    = (const float*)d_in[23];
  const float* mouth_w   = (const float*)d_in[24];
  const float* mouth_b   = (const float*)d_in[25];
  const float* fusion_w  = (const float*)d_in[26];
  const float* fusion_b  = (const float*)d_in[27];
  const float* gate1_w   = (const float*)d_in[28];
  const float* gate1_b   = (const float*)d_in[29];
  const float* gate2_w   = (const float*)d_in[30];
  const float* gate2_b   = (const float*)d_in[31];
  const float* e1w[3] = {(const float*)d_in[32], (const float*)d_in[36], (const float*)d_in[40]};
  const float* e1b[3] = {(const float*)d_in[33], (const float*)d_in[37], (const float*)d_in[41]};
  const float* e2w[3] = {(const float*)d_in[34], (const float*)d_in[38], (const float*)d_in[42]};
  const float* e2b[3] = {(const float*)d_in[35], (const float*)d_in[39], (const float*)d_in[43]};
  const float* router_w  = (const float*)d_in[44];
  const float* router_b  = (const float*)d_in[45];

  float* ws    = (float*)d_ws;
  ushort* xpm  = (ushort*)(ws + OFF_XPM);   // xa / xn2 -> x3bf
  ushort* wb   = (ushort*)(ws + OFF_W);
  ushort* r2u  = (ushort*)(ws + OFF_R2);    // qkvbf -> catpm -> he
  ushort* vbf  = (ushort*)(ws + OFF_VBF);
  ushort* obf  = (ushort*)(ws + OFF_OBF);   // attn O -> g1bf
  float* x2    = ws + OFF_X2;
  float* x3    = ws + OFF_X3;
  float* pld   = ws + OFF_PL;
  float* adb   = ws + OFF_AD;
  float* rbuf  = ws + OFF_RB;
  float* ust   = ws + OFF_US;
  float* rst   = ws + OFF_RS;
  float* outp  = (float*)d_out;

  ushort* qkvw  = wb + WOFF_QKV;
  ushort* projw = wb + WOFF_PROJ;
  ushort* g1w   = wb + WOFF_G1;
  ushort* g2w   = wb + WOFF_G2;
  ushort* fusw  = wb + WOFF_FUS;
  ushort* e1cat = wb + WOFF_E1;             // [2112][512]
  ushort* e2cat = (ushort*)(ws + OFF_E2C);  // [512][2112]
  float* be     = adb;                      // [16][512]
  float* e1bcat = adb + 8192;               // [2112]

  ushort* fpbf   = (ushort*)x2;
  ushort* sprpbf = (ushort*)x3;

  // --- weight conversion + expert stacking (704-aligned) ---
  CvtDesc D;
  auto seg = [&](int s2, const float* src, ushort* dst, int rows, int sk, int dk,
                 int ds, int rr) {
    D.s[s2] = src; D.d[s2] = dst; D.rows[s2] = rows; D.sk[s2] = sk;
    D.dk[s2] = dk; D.ds[s2] = ds; D.rr[s2] = rr;
  };
  seg(0, qkv_w,    qkvw,  1536, 512,  512,  512,  1536);
  seg(1, proj_w,   projw, 512,  512,  512,  512,  512);
  seg(2, gate1_w,  g1w,   128,  512,  512,  512,  128);
  seg(3, gate2_w,  g2w,   1536, 128,  128,  128,  1536);
  seg(4, fusion_w, fusw,  512,  1536, 1536, 1536, 512);
  for (int e = 0; e < 3; ++e) {
    seg(5 + e, e1w[e], e1cat + (size_t)e * 704 * 512, 704, 512, 512, 512, 682);
    seg(8 + e, e2w[e], e2cat + (size_t)e * 704,       512, 682, 704, 2112, 512);
  }
  cvt_w_k<<<dim3(512, 11), 256, 0, stream>>>(D);

  // --- attention bias prep ---
  sprpb_k<<<dim3(NPIX, NHEAD), 256, 0, stream>>>(sprior, rpb_table, sprpbf);
  fpcvt_k<<<9604, 256, 0, stream>>>(fpri, fpbf);

  // --- LN1 ---
  pool_mean_k<<<dim3(CDIM, 16), 64, 0, stream>>>(x, pld);
  adapt_mlp_k<<<16, 256, 0, stream>>>(pld, n1_a1w, n1_a1b, n1_a2w, n1_a2b, adb);
  ln_pm_k<0><<<dim3(25, 16), 256, 0, stream>>>(x, n1_w, n1_b, adb, xpm, nullptr, nullptr);

  // --- attention ---
  mgemm_k<0, 0, 0, 0, 128><<<1344, 256, 0, stream>>>(xpm, qkvw, qkv_b, nullptr, nullptr,
                                                     r2u, nullptr, nullptr, 512, 1536, 1536);
  vtr_k<<<dim3(13, 8, 16), 256, 0, stream>>>(r2u, vbf);
  attn_mfma_k<<<896, 256, 0, stream>>>(r2u, vbf, sprpbf, fpbf, obf);
  hipMemsetAsync(pld, 0, 16 * CDIM * sizeof(float), stream);
  mgemm_k<1, 4, 1, 0, 64><<<896, 256, 0, stream>>>(obf, projw, proj_b, x, nullptr,
                                                   x2, pld, nullptr, 512, 512, 512);

  // --- LN2 + token mixer ---
  adapt_mlp_k<<<16, 256, 0, stream>>>(pld, n2_a1w, n2_a1b, n2_a2w, n2_a2b, adb);
  ln_pm_k<1><<<dim3(25, 16), 256, 0, stream>>>(x2, n2_w, n2_b, adb, xpm, ust, rst);
  dwln_k<<<dim3(32, 16), 256, 0, stream>>>(x2, ust, rst, adb, n2_w, n2_b,
                                           eye_w, eye_b, nose_w, nose_b, mouth_w, mouth_b,
                                           r2u);
  mgemm_k<0, 1, 0, 0, 64><<<224, 256, 0, stream>>>(xpm, g1w, gate1_b, nullptr, nullptr,
                                                   obf, nullptr, nullptr, 512, 128, 128);
  mgemm_k<0, 3, 0, 0, 128><<<1344, 256, 0, stream>>>(obf, g2w, gate2_b, nullptr, nullptr,
                                                     r2u, nullptr, nullptr, 128, 1536, 1536);
  hipMemsetAsync(pld, 0, 16 * CDIM * sizeof(float), stream);
  mgemm_k<1, 4, 1, 1, 64><<<896, 256, 0, stream>>>(r2u, fusw, fusion_b, x2, nullptr,
                                                   x3, pld, xpm, 1536, 512, 512);

  // --- MoE (fused: 2 stacked GEMMs; x3bf already in xpm via DUALBF) ---
  router_k<<<16, 64, 0, stream>>>(pld, router_w, router_b, rbuf);
  biaseff_k<<<17, 512, 0, stream>>>(rbuf, e2b[0], e2b[1], e2b[2],
                                    e1b[0], e1b[1], e1b[2], be, e1bcat);
  mgemm_k<0, 5, 0, 0, 128><<<1904, 256, 0, stream>>>(xpm, e1cat, e1bcat, nullptr, rbuf,
                                                     r2u, nullptr, nullptr, 512, 2112, 2112);
  mgemm_k<1, 5, 0, 0, 64><<<896, 256, 0, stream>>>(r2u, e2cat, be, x3, nullptr,
                                                   outp, nullptr, nullptr, 2112, 512, 512);
}